// Round 3
// baseline (2480.583 us; speedup 1.0000x reference)
//
#include <hip/hip_runtime.h>
#include <hip/hip_bf16.h>
#include <math.h>

// ---------------- problem constants ----------------
#define L_SEQ   4096
#define DMODEL  1024
#define DINNER  2048
#define NHEADS  32
#define HEADDIM 64
#define DSTATE  128
#define NCHUNK  32
#define CHUNKL  128
#define CONVDIM 2560
#define DPROJ   4672   // 2*DINNER + 2*(2*DSTATE) + 2*NHEADS

typedef __hip_bfloat16 bf16;
__device__ __forceinline__ float b2f(bf16 x) { return __bfloat162float(x); }
__device__ __forceinline__ bf16 f2b(float x) { return __float2bfloat16(x); }
__device__ __forceinline__ float to_f(float x) { return x; }
__device__ __forceinline__ float to_f(bf16 x) { return b2f(x); }

// zxbcdt column layout: [0,2048) = z ; [2048,4608) = xBC ; [4608,4672) = dt raw
// xBC_conv channel layout: [0,2048) = x ; fw B = [2048,2176) C = [2176,2304)
//                          bw B = [2304,2432) C = [2432,2560)  (bw streams time-flipped)

// ---------------- GEMM: C[m,n] = sum_k A[m,k]*B[n,k] (+bias[n]), f32 acc ----------------
#define BM 64
#define BN 64
#define BKK 16
template <typename TA, typename TB, typename TC>
__global__ __launch_bounds__(256) void gemm_abt(
    const TA* __restrict__ A, int lda,
    const TB* __restrict__ B, int ldb,
    TC* __restrict__ C, int ldc,
    int M, int N, int K,
    const float* __restrict__ bias) {
  __shared__ float As[BKK][BM + 4];
  __shared__ float Bs[BKK][BN + 4];
  int tid = threadIdx.x;
  int bm = blockIdx.y * BM;
  int bn = blockIdx.x * BN;
  int tx = tid % 16, ty = tid / 16;
  int lr = tid / 16;   // row within pass
  int lc = tid % 16;   // k within tile
  float acc[4][4] = {};
  for (int k0 = 0; k0 < K; k0 += BKK) {
#pragma unroll
    for (int i = 0; i < 4; i++) {
      int row = lr + i * 16;
      int gr = bm + row;
      float v = 0.f;
      if (gr < M) v = to_f(A[(size_t)gr * lda + k0 + lc]);
      As[lc][row] = v;
    }
#pragma unroll
    for (int i = 0; i < 4; i++) {
      int row = lr + i * 16;
      int gr = bn + row;
      float v = 0.f;
      if (gr < N) v = to_f(B[(size_t)gr * ldb + k0 + lc]);
      Bs[lc][row] = v;
    }
    __syncthreads();
#pragma unroll
    for (int k = 0; k < BKK; k++) {
      float a0[4], b0[4];
#pragma unroll
      for (int i = 0; i < 4; i++) a0[i] = As[k][ty * 4 + i];
#pragma unroll
      for (int j = 0; j < 4; j++) b0[j] = Bs[k][tx * 4 + j];
#pragma unroll
      for (int i = 0; i < 4; i++)
#pragma unroll
        for (int j = 0; j < 4; j++) acc[i][j] += a0[i] * b0[j];
    }
    __syncthreads();
  }
#pragma unroll
  for (int i = 0; i < 4; i++) {
    int gr = bm + ty * 4 + i;
    if (gr >= M) continue;
#pragma unroll
    for (int j = 0; j < 4; j++) {
      int gc = bn + tx * 4 + j;
      if (gc < N) {
        float v = acc[i][j] + (bias ? bias[gc] : 0.f);
        if constexpr (sizeof(TC) == 2) C[(size_t)gr * ldc + gc] = f2b(v);
        else                           C[(size_t)gr * ldc + gc] = v;
      }
    }
  }
}

// ---------------- conv (depthwise causal, k=4) + SiLU ----------------
__global__ __launch_bounds__(256) void conv_silu_kernel(
    const bf16* __restrict__ zx, const float* __restrict__ conv_w,
    const float* __restrict__ conv_b, bf16* __restrict__ xbc) {
  int idx = blockIdx.x * 256 + threadIdx.x;   // L_SEQ*CONVDIM
  if (idx >= L_SEQ * CONVDIM) return;
  int ch = idx % CONVDIM;
  int t = idx / CONVDIM;
  const bf16* col = zx + DINNER + ch;         // xBC region
  float w0 = conv_w[ch * 4 + 0], w1 = conv_w[ch * 4 + 1];
  float w2 = conv_w[ch * 4 + 2], w3 = conv_w[ch * 4 + 3];
  float acc = conv_b[ch];
  if (t >= 3) acc += w0 * b2f(col[(size_t)(t - 3) * DPROJ]);
  if (t >= 2) acc += w1 * b2f(col[(size_t)(t - 2) * DPROJ]);
  if (t >= 1) acc += w2 * b2f(col[(size_t)(t - 1) * DPROJ]);
  acc += w3 * b2f(col[(size_t)t * DPROJ]);
  xbc[idx] = f2b(acc / (1.f + expf(-acc)));
}

// ---------------- dt: split fw/bw (bw time-flipped), softplus(dt + bias) ----------------
__global__ __launch_bounds__(256) void dt_kernel(
    const bf16* __restrict__ zx, const float* __restrict__ dt_bias,
    float* __restrict__ dt2) {
  int idx = blockIdx.x * 256 + threadIdx.x;   // 2*L_SEQ*NHEADS
  if (idx >= 2 * L_SEQ * NHEADS) return;
  int h = idx % NHEADS;
  int t = (idx / NHEADS) % L_SEQ;
  int b = idx / (NHEADS * L_SEQ);
  float v;
  if (b == 0) v = b2f(zx[(size_t)t * DPROJ + 4608 + h]);
  else        v = b2f(zx[(size_t)(L_SEQ - 1 - t) * DPROJ + 4608 + NHEADS + h]);
  v += dt_bias[h];
  dt2[idx] = (v > 20.f) ? v : log1pf(expf(v));
}

// ---------------- G[b,c,l,s] = sum_n C[l,n]*B[s,n]  (lower triangle only) ----------------
__global__ __launch_bounds__(256) void gmat_kernel(
    const bf16* __restrict__ xbc, float* __restrict__ G) {
  __shared__ float Bs[CHUNKL][DSTATE + 1];
  __shared__ float Cs[CHUNKL][DSTATE + 1];
  int bc = blockIdx.x;            // b*32 + c
  int b = bc / NCHUNK, c = bc % NCHUNK;
  int tid = threadIdx.x;
  int bofs = b ? 2304 : 2048;
  int cofs = b ? 2432 : 2176;
  for (int o = tid; o < CHUNKL * DSTATE; o += 256) {
    int n = o % DSTATE, s = o / DSTATE;
    int t = b ? (L_SEQ - 1 - (c * CHUNKL + s)) : (c * CHUNKL + s);
    const bf16* row = xbc + (size_t)t * CONVDIM;
    Bs[s][n] = b2f(row[bofs + n]);
    Cs[s][n] = b2f(row[cofs + n]);
  }
  __syncthreads();
  float* Gb = G + (size_t)bc * CHUNKL * CHUNKL;
  for (int o = tid; o < CHUNKL * CHUNKL; o += 256) {
    int s = o % CHUNKL, l = o / CHUNKL;
    float acc = 0.f;
    if (s <= l) {
#pragma unroll 8
      for (int n = 0; n < DSTATE; n++) acc += Cs[l][n] * Bs[s][n];
    }
    Gb[o] = acc;
  }
}

// ---------------- per-(b,c,h): Y_diag and chunk states ----------------
__global__ __launch_bounds__(256) void chunk_kernel(
    const bf16* __restrict__ xbc, const float* __restrict__ dt2,
    const float* __restrict__ A_log, const float* __restrict__ G,
    float* __restrict__ Y, float* __restrict__ states,
    float* __restrict__ csum) {
  int gid = blockIdx.x;           // (b*32+c)*32 + h
  int h = gid % NHEADS;
  int bc = gid / NHEADS;
  int c = bc % NCHUNK, b = bc / NCHUNK;
  int tid = threadIdx.x;
  __shared__ float xdt[CHUNKL][HEADDIM];     // 32 KB
  __shared__ float W[CHUNKL][CHUNKL];        // 64 KB
  __shared__ float acs[CHUNKL];
  __shared__ float dtl[CHUNKL];
  if (tid < CHUNKL)
    dtl[tid] = dt2[((size_t)b * L_SEQ + c * CHUNKL + tid) * NHEADS + h];
  __syncthreads();
  if (tid == 0) {
    float Ah = -expf(A_log[h]);
    float s = 0.f;
    for (int l = 0; l < CHUNKL; l++) { s += Ah * dtl[l]; acs[l] = s; }
    csum[gid] = s;
  }
  __syncthreads();
  // xdt[s][p] = x[s,p] * dt[s]
  for (int o = tid; o < CHUNKL * HEADDIM; o += 256) {
    int p = o % HEADDIM, s = o / HEADDIM;
    int t = b ? (L_SEQ - 1 - (c * CHUNKL + s)) : (c * CHUNKL + s);
    xdt[s][p] = b2f(xbc[(size_t)t * CONVDIM + h * HEADDIM + p]) * dtl[s];
  }
  // W[l][s] = G * exp(acs[l]-acs[s]) for s<=l
  const float* Gb = G + (size_t)bc * CHUNKL * CHUNKL;
  for (int o = tid; o < CHUNKL * CHUNKL; o += 256) {
    int s = o % CHUNKL, l = o / CHUNKL;
    W[l][s] = (s <= l) ? Gb[o] * expf(acs[l] - acs[s]) : 0.f;
  }
  __syncthreads();
  // Y_diag = W @ xdt
  {
    int p = tid % HEADDIM;
    int lg = tid / HEADDIM;       // 0..3
    for (int i = 0; i < 32; i++) {
      int l = lg * 32 + i;
      float acc = 0.f;
      for (int s = 0; s <= l; s++) acc += W[l][s] * xdt[s][p];
      Y[((size_t)b * L_SEQ + c * CHUNKL + l) * DINNER + h * HEADDIM + p] = acc;
    }
  }
  __syncthreads();
  if (tid < CHUNKL) dtl[tid] = expf(acs[CHUNKL - 1] - acs[tid]);  // decay_states
  __syncthreads();
  // states[p][n] = sum_l B[l][n]*decay[l]*xdt[l][p]
  {
    int n = tid % DSTATE;
    int pg = tid / DSTATE;        // 0..1
    int bofs = b ? 2304 : 2048;
    float acc2[32];
#pragma unroll
    for (int i = 0; i < 32; i++) acc2[i] = 0.f;
    for (int l = 0; l < CHUNKL; l++) {
      int t = b ? (L_SEQ - 1 - (c * CHUNKL + l)) : (c * CHUNKL + l);
      float w = b2f(xbc[(size_t)t * CONVDIM + bofs + n]) * dtl[l];
#pragma unroll
      for (int i = 0; i < 32; i++) acc2[i] += w * xdt[l][pg * 32 + i];
    }
    float* st = states + (size_t)gid * (HEADDIM * DSTATE);
#pragma unroll
    for (int i = 0; i < 32; i++) st[(pg * 32 + i) * DSTATE + n] = acc2[i];
  }
}

// ---------------- inter-chunk scan (in place: states -> state_in) ----------------
__global__ __launch_bounds__(256) void scan_kernel(
    float* __restrict__ states, const float* __restrict__ csum) {
  int idx = blockIdx.x * 256 + threadIdx.x;  // 2*NHEADS*HEADDIM*DSTATE
  int n = idx % DSTATE;
  int p = (idx / DSTATE) % HEADDIM;
  int h = (idx / (DSTATE * HEADDIM)) % NHEADS;
  int b = idx / (DSTATE * HEADDIM * NHEADS);
  float S = 0.f;
  for (int c = 0; c < NCHUNK; c++) {
    int gid = (b * NCHUNK + c) * NHEADS + h;
    size_t off = (size_t)gid * (HEADDIM * DSTATE) + p * DSTATE + n;
    float tmp = states[off];
    states[off] = S;
    S = expf(csum[gid]) * S + tmp;
  }
}

// ---------------- Y_off + D*x, accumulate into Y ----------------
__global__ __launch_bounds__(256) void yoff_kernel(
    const bf16* __restrict__ xbc, const float* __restrict__ dt2,
    const float* __restrict__ A_log, const float* __restrict__ states,
    const float* __restrict__ Dp, float* __restrict__ Y) {
  int gid = blockIdx.x;
  int h = gid % NHEADS;
  int bc = gid / NHEADS;
  int c = bc % NCHUNK, b = bc / NCHUNK;
  int tid = threadIdx.x;
  __shared__ float S[HEADDIM][DSTATE + 1];   // ~33 KB
  __shared__ float acs[CHUNKL];
  __shared__ float dtl[CHUNKL];
  if (tid < CHUNKL)
    dtl[tid] = dt2[((size_t)b * L_SEQ + c * CHUNKL + tid) * NHEADS + h];
  __syncthreads();
  if (tid == 0) {
    float Ah = -expf(A_log[h]);
    float s = 0.f;
    for (int l = 0; l < CHUNKL; l++) { s += Ah * dtl[l]; acs[l] = s; }
  }
  const float* st = states + (size_t)gid * (HEADDIM * DSTATE);
  for (int o = tid; o < HEADDIM * DSTATE; o += 256) {
    int n = o % DSTATE, p = o / DSTATE;
    S[p][n] = st[o];
  }
  __syncthreads();
  int cofs = b ? 2432 : 2176;
  int p = tid % HEADDIM;
  int lg = tid / HEADDIM;
  float Dh = Dp[h];
  for (int i = 0; i < 32; i++) {
    int l = lg * 32 + i;
    int t = b ? (L_SEQ - 1 - (c * CHUNKL + l)) : (c * CHUNKL + l);
    const bf16* crow = xbc + (size_t)t * CONVDIM + cofs;
    float acc = 0.f;
#pragma unroll 8
    for (int n = 0; n < DSTATE; n++) acc += b2f(crow[n]) * S[p][n];
    float eA = expf(acs[l]);
    size_t yi = ((size_t)b * L_SEQ + c * CHUNKL + l) * DINNER + h * HEADDIM + p;
    float xv = b2f(xbc[(size_t)t * CONVDIM + h * HEADDIM + p]);
    Y[yi] = Y[yi] + eA * acc + xv * Dh;
  }
}

// ---------------- combine: shift, flip, +x*fd, gate, RMSNorm ----------------
__global__ __launch_bounds__(256) void combine_kernel(
    const float* __restrict__ Y, const bf16* __restrict__ xbc,
    const bf16* __restrict__ zx, const float* __restrict__ fd,
    const float* __restrict__ norm_w, bf16* __restrict__ yn) {
  int t = blockIdx.x;
  int tid = threadIdx.x;
  float yg[8];
  float ss = 0.f;
#pragma unroll
  for (int i = 0; i < 8; i++) {
    int j = tid + i * 256;
    float yfw = (t >= 1) ? Y[(size_t)(t - 1) * DINNER + j] : 0.f;
    float ybw = (t <= L_SEQ - 2)
                    ? Y[((size_t)L_SEQ + (L_SEQ - 2 - t)) * DINNER + j] : 0.f;
    float xog = b2f(xbc[(size_t)t * CONVDIM + j]);
    float fdv = fd[t * NHEADS + (j >> 6)];
    float z = b2f(zx[(size_t)t * DPROJ + j]);
    float y = yfw + ybw + xog * fdv;
    float g = y * (z / (1.f + expf(-z)));
    yg[i] = g;
    ss += g * g;
  }
#pragma unroll
  for (int off = 32; off > 0; off >>= 1) ss += __shfl_down(ss, off);
  __shared__ float red[4];
  if ((tid & 63) == 0) red[tid >> 6] = ss;
  __syncthreads();
  float tot = red[0] + red[1] + red[2] + red[3];
  float scale = rsqrtf(tot / (float)DINNER + 1e-5f);
#pragma unroll
  for (int i = 0; i < 8; i++) {
    int j = tid + i * 256;
    yn[(size_t)t * DINNER + j] = f2b(yg[i] * scale * norm_w[j]);
  }
}

// ---------------- launch ----------------
extern "C" void kernel_launch(void* const* d_in, const int* in_sizes, int n_in,
                              void* d_out, int out_size, void* d_ws, size_t ws_size,
                              hipStream_t stream) {
  const float* u         = (const float*)d_in[0];
  const float* in_proj_w = (const float*)d_in[1];
  const float* conv_w    = (const float*)d_in[2];
  const float* conv_b    = (const float*)d_in[3];
  const float* dt_bias   = (const float*)d_in[4];
  const float* A_log     = (const float*)d_in[5];
  const float* Dp        = (const float*)d_in[6];
  const float* fc_D_w    = (const float*)d_in[7];
  const float* norm_w    = (const float*)d_in[8];
  const float* out_proj_w= (const float*)d_in[9];
  float* out = (float*)d_out;

  char* base = (char*)d_ws;
  bf16*  zx  = (bf16*)base;  base += (size_t)L_SEQ * DPROJ * 2;                    // 38.3 MB
  bf16*  xbc = (bf16*)base;  base += (size_t)L_SEQ * CONVDIM * 2;                  // 21.0 MB
  float* dt2 = (float*)base; base += (size_t)2 * L_SEQ * NHEADS * 4;               //  1.0 MB
  float* G   = (float*)base; base += (size_t)2 * NCHUNK * CHUNKL * CHUNKL * 4;     //  4.2 MB
  float* Yb  = (float*)base; base += (size_t)2 * L_SEQ * DINNER * 4;               // 67.1 MB
  float* st  = (float*)base; base += (size_t)2 * NCHUNK * NHEADS * HEADDIM * DSTATE * 4; // 67.1 MB
  float* cs  = (float*)base; base += (size_t)2 * NCHUNK * NHEADS * 4;              //  8 KB
  // yn/fd alias the states region (dead after yoff_kernel)
  bf16*  yn  = (bf16*)st;                                                          // 16.8 MB
  float* fd  = (float*)((char*)st + 33554432);                                     //  0.5 MB

  // 1. in_proj: zx = u @ in_proj_w^T
  gemm_abt<float, float, bf16><<<dim3(DPROJ / 64, L_SEQ / 64), 256, 0, stream>>>(
      u, DMODEL, in_proj_w, DMODEL, zx, DPROJ, L_SEQ, DPROJ, DMODEL, nullptr);
  // 2. conv + silu
  conv_silu_kernel<<<(L_SEQ * CONVDIM + 255) / 256, 256, 0, stream>>>(
      zx, conv_w, conv_b, xbc);
  // 2b. dt
  dt_kernel<<<(2 * L_SEQ * NHEADS + 255) / 256, 256, 0, stream>>>(
      zx, dt_bias, dt2);
  // 3a. G = C B^T per (b,c)
  gmat_kernel<<<2 * NCHUNK, 256, 0, stream>>>(xbc, G);
  // 3b. intra-chunk
  chunk_kernel<<<2 * NCHUNK * NHEADS, 256, 0, stream>>>(
      xbc, dt2, A_log, G, Yb, st, cs);
  // 3c. inter-chunk scan
  scan_kernel<<<(2 * NHEADS * HEADDIM * DSTATE) / 256, 256, 0, stream>>>(st, cs);
  // 3d. Y_off + D*x
  yoff_kernel<<<2 * NCHUNK * NHEADS, 256, 0, stream>>>(
      xbc, dt2, A_log, st, Dp, Yb);
  // 4. fd = x_og @ fc_D_w^T + D
  gemm_abt<bf16, float, float><<<dim3(1, L_SEQ / 64), 256, 0, stream>>>(
      xbc, CONVDIM, fc_D_w, DINNER, fd, NHEADS, L_SEQ, NHEADS, DINNER, Dp);
  // 5. combine + gate + RMSNorm
  combine_kernel<<<L_SEQ, 256, 0, stream>>>(Yb, xbc, zx, fd, norm_w, yn);
  // 6. out_proj
  gemm_abt<bf16, float, float><<<dim3(DMODEL / 64, L_SEQ / 64), 256, 0, stream>>>(
      yn, DINNER, out_proj_w, DINNER, out, DMODEL, L_SEQ, DMODEL, DINNER, nullptr);
}

// Round 4
// 1637.325 us; speedup vs baseline: 1.5150x; 1.5150x over previous
//
#include <hip/hip_runtime.h>
#include <hip/hip_bf16.h>
#include <math.h>

// ---------------- problem constants ----------------
#define L_SEQ   4096
#define DMODEL  1024
#define DINNER  2048
#define NHEADS  32
#define HEADDIM 64
#define DSTATE  128
#define NCHUNK  32
#define CHUNKL  128
#define CONVDIM 2560
#define DPROJ   4672   // 2*DINNER + 2*(2*DSTATE) + 2*NHEADS
#define NPAD1   4736   // DPROJ padded to multiple of 128 for MFMA gemm

typedef __hip_bfloat16 bf16;
__device__ __forceinline__ float b2f(bf16 x) { return __bfloat162float(x); }
__device__ __forceinline__ bf16 f2b(float x) { return __float2bfloat16(x); }
__device__ __forceinline__ float to_f(float x) { return x; }
__device__ __forceinline__ float to_f(bf16 x) { return b2f(x); }

typedef __attribute__((ext_vector_type(8))) short bf16x8v;
typedef __attribute__((ext_vector_type(4))) float f32x4v;

// zxbcdt column layout: [0,2048) = z ; [2048,4608) = xBC ; [4608,4672) = dt raw
// xBC_conv channel layout: [0,2048) = x ; fw B = [2048,2176) C = [2176,2304)
//                          bw B = [2304,2432) C = [2432,2560)  (bw streams time-flipped)

// ---------------- f32 -> bf16 cast (dst beyond n_src zero-filled) ----------------
__global__ __launch_bounds__(256) void cast_kernel(
    const float* __restrict__ src, bf16* __restrict__ dst, int n_src, int n_tot) {
  int i = blockIdx.x * 256 + threadIdx.x;
  if (i < n_tot) dst[i] = (i < n_src) ? f2b(src[i]) : f2b(0.f);
}

// ---------------- MFMA GEMM: C[m,n] = sum_k A[m,k]*B[n,k], bf16 in, f32 acc ----------------
// 128x128 tile, BK=32, 256 threads = 4 waves in 2x2, each wave 64x64 (4x4 MFMA tiles).
// A: M x K bf16 row-major (M % 128 == 0). B: Npad x K bf16 row-major (Npad = gridDim.x*128,
// rows [N, Npad) must be readable -> caller pads). Store guarded by col < N.
template <typename TC>
__global__ __launch_bounds__(256) void gemm_mfma(
    const bf16* __restrict__ A, int lda,
    const bf16* __restrict__ B, int ldb,
    TC* __restrict__ C, int ldc,
    int N, int K) {
  __shared__ short As[128][32];
  __shared__ short Bs[128][32];
  int tid = threadIdx.x;
  int lane = tid & 63;
  int w = tid >> 6;            // wave 0..3
  int wr = w >> 1, wc = w & 1; // 2x2 wave grid
  int bm = blockIdx.y * 128;
  int bn = blockIdx.x * 128;
  f32x4v acc[4][4];
#pragma unroll
  for (int i = 0; i < 4; i++)
#pragma unroll
    for (int j = 0; j < 4; j++) acc[i][j] = (f32x4v){0.f, 0.f, 0.f, 0.f};

  // staging: per wave 16 rows per instruction; lane i -> row (i>>2), k-chunk (i&3)*8 elems
  const bf16* Ab = A + (size_t)(bm + w * 32 + (lane >> 2)) * lda + (lane & 3) * 8;
  const bf16* Bb = B + (size_t)(bn + w * 32 + (lane >> 2)) * ldb + (lane & 3) * 8;

  for (int k0 = 0; k0 < K; k0 += 32) {
    __builtin_amdgcn_global_load_lds(
        (const __attribute__((address_space(1))) void*)(Ab + k0),
        (__attribute__((address_space(3))) void*)&As[w * 32][0], 16, 0, 0);
    __builtin_amdgcn_global_load_lds(
        (const __attribute__((address_space(1))) void*)(Ab + (size_t)16 * lda + k0),
        (__attribute__((address_space(3))) void*)&As[w * 32 + 16][0], 16, 0, 0);
    __builtin_amdgcn_global_load_lds(
        (const __attribute__((address_space(1))) void*)(Bb + k0),
        (__attribute__((address_space(3))) void*)&Bs[w * 32][0], 16, 0, 0);
    __builtin_amdgcn_global_load_lds(
        (const __attribute__((address_space(1))) void*)(Bb + (size_t)16 * ldb + k0),
        (__attribute__((address_space(3))) void*)&Bs[w * 32 + 16][0], 16, 0, 0);
    __syncthreads();
    bf16x8v af[4], bv[4];
#pragma unroll
    for (int i = 0; i < 4; i++)
      af[i] = *(const bf16x8v*)&As[wr * 64 + i * 16 + (lane & 15)][(lane >> 4) * 8];
#pragma unroll
    for (int j = 0; j < 4; j++)
      bv[j] = *(const bf16x8v*)&Bs[wc * 64 + j * 16 + (lane & 15)][(lane >> 4) * 8];
#pragma unroll
    for (int i = 0; i < 4; i++)
#pragma unroll
      for (int j = 0; j < 4; j++)
        acc[i][j] = __builtin_amdgcn_mfma_f32_16x16x32_bf16(af[i], bv[j], acc[i][j], 0, 0, 0);
    __syncthreads();
  }
  // C/D layout: col = lane&15, row = quad*4 + reg  [m89/m91 verified]
  int quad = lane >> 4;
  int cn = lane & 15;
#pragma unroll
  for (int i = 0; i < 4; i++) {
#pragma unroll
    for (int j = 0; j < 4; j++) {
      int col = bn + wc * 64 + j * 16 + cn;
      if (col < N) {
#pragma unroll
        for (int r = 0; r < 4; r++) {
          int row = bm + wr * 64 + i * 16 + quad * 4 + r;
          float v = acc[i][j][r];
          if constexpr (sizeof(TC) == 2) C[(size_t)row * ldc + col] = f2b(v);
          else                           C[(size_t)row * ldc + col] = v;
        }
      }
    }
  }
}

// ---------------- VALU GEMM (kept for tiny fc_D): C[m,n] = sum_k A[m,k]*B[n,k] ----------------
#define BM 64
#define BN 64
#define BKK 16
template <typename TA, typename TB, typename TC>
__global__ __launch_bounds__(256) void gemm_abt(
    const TA* __restrict__ A, int lda,
    const TB* __restrict__ B, int ldb,
    TC* __restrict__ C, int ldc,
    int M, int N, int K,
    const float* __restrict__ bias) {
  __shared__ float As[BKK][BM + 4];
  __shared__ float Bs[BKK][BN + 4];
  int tid = threadIdx.x;
  int bm = blockIdx.y * BM;
  int bn = blockIdx.x * BN;
  int tx = tid % 16, ty = tid / 16;
  int lr = tid / 16;
  int lc = tid % 16;
  float acc[4][4] = {};
  for (int k0 = 0; k0 < K; k0 += BKK) {
#pragma unroll
    for (int i = 0; i < 4; i++) {
      int row = lr + i * 16;
      int gr = bm + row;
      float v = 0.f;
      if (gr < M) v = to_f(A[(size_t)gr * lda + k0 + lc]);
      As[lc][row] = v;
    }
#pragma unroll
    for (int i = 0; i < 4; i++) {
      int row = lr + i * 16;
      int gr = bn + row;
      float v = 0.f;
      if (gr < N) v = to_f(B[(size_t)gr * ldb + k0 + lc]);
      Bs[lc][row] = v;
    }
    __syncthreads();
#pragma unroll
    for (int k = 0; k < BKK; k++) {
      float a0[4], b0[4];
#pragma unroll
      for (int i = 0; i < 4; i++) a0[i] = As[k][ty * 4 + i];
#pragma unroll
      for (int j = 0; j < 4; j++) b0[j] = Bs[k][tx * 4 + j];
#pragma unroll
      for (int i = 0; i < 4; i++)
#pragma unroll
        for (int j = 0; j < 4; j++) acc[i][j] += a0[i] * b0[j];
    }
    __syncthreads();
  }
#pragma unroll
  for (int i = 0; i < 4; i++) {
    int gr = bm + ty * 4 + i;
    if (gr >= M) continue;
#pragma unroll
    for (int j = 0; j < 4; j++) {
      int gc = bn + tx * 4 + j;
      if (gc < N) {
        float v = acc[i][j] + (bias ? bias[gc] : 0.f);
        if constexpr (sizeof(TC) == 2) C[(size_t)gr * ldc + gc] = f2b(v);
        else                           C[(size_t)gr * ldc + gc] = v;
      }
    }
  }
}

// ---------------- conv (depthwise causal, k=4) + SiLU ----------------
__global__ __launch_bounds__(256) void conv_silu_kernel(
    const bf16* __restrict__ zx, const float* __restrict__ conv_w,
    const float* __restrict__ conv_b, bf16* __restrict__ xbc) {
  int idx = blockIdx.x * 256 + threadIdx.x;   // L_SEQ*CONVDIM
  if (idx >= L_SEQ * CONVDIM) return;
  int ch = idx % CONVDIM;
  int t = idx / CONVDIM;
  const bf16* col = zx + DINNER + ch;         // xBC region
  float w0 = conv_w[ch * 4 + 0], w1 = conv_w[ch * 4 + 1];
  float w2 = conv_w[ch * 4 + 2], w3 = conv_w[ch * 4 + 3];
  float acc = conv_b[ch];
  if (t >= 3) acc += w0 * b2f(col[(size_t)(t - 3) * DPROJ]);
  if (t >= 2) acc += w1 * b2f(col[(size_t)(t - 2) * DPROJ]);
  if (t >= 1) acc += w2 * b2f(col[(size_t)(t - 1) * DPROJ]);
  acc += w3 * b2f(col[(size_t)t * DPROJ]);
  xbc[idx] = f2b(acc / (1.f + expf(-acc)));
}

// ---------------- dt: split fw/bw (bw time-flipped), softplus(dt + bias) ----------------
__global__ __launch_bounds__(256) void dt_kernel(
    const bf16* __restrict__ zx, const float* __restrict__ dt_bias,
    float* __restrict__ dt2) {
  int idx = blockIdx.x * 256 + threadIdx.x;   // 2*L_SEQ*NHEADS
  if (idx >= 2 * L_SEQ * NHEADS) return;
  int h = idx % NHEADS;
  int t = (idx / NHEADS) % L_SEQ;
  int b = idx / (NHEADS * L_SEQ);
  float v;
  if (b == 0) v = b2f(zx[(size_t)t * DPROJ + 4608 + h]);
  else        v = b2f(zx[(size_t)(L_SEQ - 1 - t) * DPROJ + 4608 + NHEADS + h]);
  v += dt_bias[h];
  dt2[idx] = (v > 20.f) ? v : log1pf(expf(v));
}

// ---------------- G[b,c,l,s] = sum_n C[l,n]*B[s,n]  (lower triangle only) ----------------
__global__ __launch_bounds__(256) void gmat_kernel(
    const bf16* __restrict__ xbc, float* __restrict__ G) {
  __shared__ float Bs[CHUNKL][DSTATE + 1];
  __shared__ float Cs[CHUNKL][DSTATE + 1];
  int bc = blockIdx.x;            // b*32 + c
  int b = bc / NCHUNK, c = bc % NCHUNK;
  int tid = threadIdx.x;
  int bofs = b ? 2304 : 2048;
  int cofs = b ? 2432 : 2176;
  for (int o = tid; o < CHUNKL * DSTATE; o += 256) {
    int n = o % DSTATE, s = o / DSTATE;
    int t = b ? (L_SEQ - 1 - (c * CHUNKL + s)) : (c * CHUNKL + s);
    const bf16* row = xbc + (size_t)t * CONVDIM;
    Bs[s][n] = b2f(row[bofs + n]);
    Cs[s][n] = b2f(row[cofs + n]);
  }
  __syncthreads();
  float* Gb = G + (size_t)bc * CHUNKL * CHUNKL;
  for (int o = tid; o < CHUNKL * CHUNKL; o += 256) {
    int s = o % CHUNKL, l = o / CHUNKL;
    float acc = 0.f;
    if (s <= l) {
#pragma unroll 8
      for (int n = 0; n < DSTATE; n++) acc += Cs[l][n] * Bs[s][n];
    }
    Gb[o] = acc;
  }
}

// ---------------- per-(b,c,h): Y_diag and chunk states ----------------
__global__ __launch_bounds__(256) void chunk_kernel(
    const bf16* __restrict__ xbc, const float* __restrict__ dt2,
    const float* __restrict__ A_log, const float* __restrict__ G,
    float* __restrict__ Y, float* __restrict__ states,
    float* __restrict__ csum) {
  int gid = blockIdx.x;           // (b*32+c)*32 + h
  int h = gid % NHEADS;
  int bc = gid / NHEADS;
  int c = bc % NCHUNK, b = bc / NCHUNK;
  int tid = threadIdx.x;
  __shared__ float xdt[CHUNKL][HEADDIM];     // 32 KB
  __shared__ float W[CHUNKL][CHUNKL];        // 64 KB
  __shared__ float acs[CHUNKL];
  __shared__ float dtl[CHUNKL];
  if (tid < CHUNKL)
    dtl[tid] = dt2[((size_t)b * L_SEQ + c * CHUNKL + tid) * NHEADS + h];
  __syncthreads();
  if (tid == 0) {
    float Ah = -expf(A_log[h]);
    float s = 0.f;
    for (int l = 0; l < CHUNKL; l++) { s += Ah * dtl[l]; acs[l] = s; }
    csum[gid] = s;
  }
  __syncthreads();
  for (int o = tid; o < CHUNKL * HEADDIM; o += 256) {
    int p = o % HEADDIM, s = o / HEADDIM;
    int t = b ? (L_SEQ - 1 - (c * CHUNKL + s)) : (c * CHUNKL + s);
    xdt[s][p] = b2f(xbc[(size_t)t * CONVDIM + h * HEADDIM + p]) * dtl[s];
  }
  const float* Gb = G + (size_t)bc * CHUNKL * CHUNKL;
  for (int o = tid; o < CHUNKL * CHUNKL; o += 256) {
    int s = o % CHUNKL, l = o / CHUNKL;
    W[l][s] = (s <= l) ? Gb[o] * expf(acs[l] - acs[s]) : 0.f;
  }
  __syncthreads();
  {
    int p = tid % HEADDIM;
    int lg = tid / HEADDIM;
    for (int i = 0; i < 32; i++) {
      int l = lg * 32 + i;
      float acc = 0.f;
      for (int s = 0; s <= l; s++) acc += W[l][s] * xdt[s][p];
      Y[((size_t)b * L_SEQ + c * CHUNKL + l) * DINNER + h * HEADDIM + p] = acc;
    }
  }
  __syncthreads();
  if (tid < CHUNKL) dtl[tid] = expf(acs[CHUNKL - 1] - acs[tid]);  // decay_states
  __syncthreads();
  {
    int n = tid % DSTATE;
    int pg = tid / DSTATE;
    int bofs = b ? 2304 : 2048;
    float acc2[32];
#pragma unroll
    for (int i = 0; i < 32; i++) acc2[i] = 0.f;
    for (int l = 0; l < CHUNKL; l++) {
      int t = b ? (L_SEQ - 1 - (c * CHUNKL + l)) : (c * CHUNKL + l);
      float w = b2f(xbc[(size_t)t * CONVDIM + bofs + n]) * dtl[l];
#pragma unroll
      for (int i = 0; i < 32; i++) acc2[i] += w * xdt[l][pg * 32 + i];
    }
    float* st = states + (size_t)gid * (HEADDIM * DSTATE);
#pragma unroll
    for (int i = 0; i < 32; i++) st[(pg * 32 + i) * DSTATE + n] = acc2[i];
  }
}

// ---------------- inter-chunk scan (in place: states -> state_in) ----------------
__global__ __launch_bounds__(256) void scan_kernel(
    float* __restrict__ states, const float* __restrict__ csum) {
  int idx = blockIdx.x * 256 + threadIdx.x;  // 2*NHEADS*HEADDIM*DSTATE
  int n = idx % DSTATE;
  int p = (idx / DSTATE) % HEADDIM;
  int h = (idx / (DSTATE * HEADDIM)) % NHEADS;
  int b = idx / (DSTATE * HEADDIM * NHEADS);
  float S = 0.f;
  for (int c = 0; c < NCHUNK; c++) {
    int gid = (b * NCHUNK + c) * NHEADS + h;
    size_t off = (size_t)gid * (HEADDIM * DSTATE) + p * DSTATE + n;
    float tmp = states[off];
    states[off] = S;
    S = expf(csum[gid]) * S + tmp;
  }
}

// ---------------- Y_off + D*x, accumulate into Y ----------------
__global__ __launch_bounds__(256) void yoff_kernel(
    const bf16* __restrict__ xbc, const float* __restrict__ dt2,
    const float* __restrict__ A_log, const float* __restrict__ states,
    const float* __restrict__ Dp, float* __restrict__ Y) {
  int gid = blockIdx.x;
  int h = gid % NHEADS;
  int bc = gid / NHEADS;
  int c = bc % NCHUNK, b = bc / NCHUNK;
  int tid = threadIdx.x;
  __shared__ float S[HEADDIM][DSTATE + 1];
  __shared__ float acs[CHUNKL];
  __shared__ float dtl[CHUNKL];
  if (tid < CHUNKL)
    dtl[tid] = dt2[((size_t)b * L_SEQ + c * CHUNKL + tid) * NHEADS + h];
  __syncthreads();
  if (tid == 0) {
    float Ah = -expf(A_log[h]);
    float s = 0.f;
    for (int l = 0; l < CHUNKL; l++) { s += Ah * dtl[l]; acs[l] = s; }
  }
  const float* st = states + (size_t)gid * (HEADDIM * DSTATE);
  for (int o = tid; o < HEADDIM * DSTATE; o += 256) {
    int n = o % DSTATE, p = o / DSTATE;
    S[p][n] = st[o];
  }
  __syncthreads();
  int cofs = b ? 2432 : 2176;
  int p = tid % HEADDIM;
  int lg = tid / HEADDIM;
  float Dh = Dp[h];
  for (int i = 0; i < 32; i++) {
    int l = lg * 32 + i;
    int t = b ? (L_SEQ - 1 - (c * CHUNKL + l)) : (c * CHUNKL + l);
    const bf16* crow = xbc + (size_t)t * CONVDIM + cofs;
    float acc = 0.f;
#pragma unroll 8
    for (int n = 0; n < DSTATE; n++) acc += b2f(crow[n]) * S[p][n];
    float eA = expf(acs[l]);
    size_t yi = ((size_t)b * L_SEQ + c * CHUNKL + l) * DINNER + h * HEADDIM + p;
    float xv = b2f(xbc[(size_t)t * CONVDIM + h * HEADDIM + p]);
    Y[yi] = Y[yi] + eA * acc + xv * Dh;
  }
}

// ---------------- combine: shift, flip, +x*fd, gate, RMSNorm ----------------
__global__ __launch_bounds__(256) void combine_kernel(
    const float* __restrict__ Y, const bf16* __restrict__ xbc,
    const bf16* __restrict__ zx, const float* __restrict__ fd,
    const float* __restrict__ norm_w, bf16* __restrict__ yn) {
  int t = blockIdx.x;
  int tid = threadIdx.x;
  float yg[8];
  float ss = 0.f;
#pragma unroll
  for (int i = 0; i < 8; i++) {
    int j = tid + i * 256;
    float yfw = (t >= 1) ? Y[(size_t)(t - 1) * DINNER + j] : 0.f;
    float ybw = (t <= L_SEQ - 2)
                    ? Y[((size_t)L_SEQ + (L_SEQ - 2 - t)) * DINNER + j] : 0.f;
    float xog = b2f(xbc[(size_t)t * CONVDIM + j]);
    float fdv = fd[t * NHEADS + (j >> 6)];
    float z = b2f(zx[(size_t)t * DPROJ + j]);
    float y = yfw + ybw + xog * fdv;
    float g = y * (z / (1.f + expf(-z)));
    yg[i] = g;
    ss += g * g;
  }
#pragma unroll
  for (int off = 32; off > 0; off >>= 1) ss += __shfl_down(ss, off);
  __shared__ float red[4];
  if ((tid & 63) == 0) red[tid >> 6] = ss;
  __syncthreads();
  float tot = red[0] + red[1] + red[2] + red[3];
  float scale = rsqrtf(tot / (float)DINNER + 1e-5f);
#pragma unroll
  for (int i = 0; i < 8; i++) {
    int j = tid + i * 256;
    yn[(size_t)t * DINNER + j] = f2b(yg[i] * scale * norm_w[j]);
  }
}

// ---------------- launch ----------------
extern "C" void kernel_launch(void* const* d_in, const int* in_sizes, int n_in,
                              void* d_out, int out_size, void* d_ws, size_t ws_size,
                              hipStream_t stream) {
  const float* u         = (const float*)d_in[0];
  const float* in_proj_w = (const float*)d_in[1];
  const float* conv_w    = (const float*)d_in[2];
  const float* conv_b    = (const float*)d_in[3];
  const float* dt_bias   = (const float*)d_in[4];
  const float* A_log     = (const float*)d_in[5];
  const float* Dp        = (const float*)d_in[6];
  const float* fc_D_w    = (const float*)d_in[7];
  const float* norm_w    = (const float*)d_in[8];
  const float* out_proj_w= (const float*)d_in[9];
  float* out = (float*)d_out;

  char* base = (char*)d_ws;
  bf16*  zx  = (bf16*)base;  base += (size_t)L_SEQ * DPROJ * 2;                    // 38.3 MB
  bf16*  xbc = (bf16*)base;  base += (size_t)L_SEQ * CONVDIM * 2;                  // 21.0 MB
  float* dt2 = (float*)base; base += (size_t)2 * L_SEQ * NHEADS * 4;               //  1.0 MB
  float* G   = (float*)base; base += (size_t)2 * NCHUNK * CHUNKL * CHUNKL * 4;     //  4.2 MB
  float* Yb  = (float*)base; base += (size_t)2 * L_SEQ * DINNER * 4;               // 67.1 MB
  float* st  = (float*)base; base += (size_t)2 * NCHUNK * NHEADS * HEADDIM * DSTATE * 4; // 67.1 MB
  float* cs  = (float*)base; base += (size_t)2 * NCHUNK * NHEADS * 4;              //  8 KB
  // aliases into dead regions:
  bf16*  u_bf   = (bf16*)Yb;                          // 8.4 MB   (Yb live only after chunk_kernel)
  bf16*  w1p_bf = (bf16*)((char*)Yb + 9437184);       // 9.7 MB   (padded in_proj_w)
  bf16*  w2_bf  = (bf16*)G;                           // 4.0 MB   (G dead after chunk_kernel)
  bf16*  yn     = (bf16*)st;                          // 16.8 MB  (st dead after yoff_kernel)
  float* fd     = (float*)((char*)st + 33554432);     //  0.5 MB

  // 0. casts for MFMA gemm1
  cast_kernel<<<(L_SEQ * DMODEL + 255) / 256, 256, 0, stream>>>(
      u, u_bf, L_SEQ * DMODEL, L_SEQ * DMODEL);
  cast_kernel<<<(NPAD1 * DMODEL + 255) / 256, 256, 0, stream>>>(
      in_proj_w, w1p_bf, DPROJ * DMODEL, NPAD1 * DMODEL);
  // 1. in_proj: zx = u @ in_proj_w^T  (MFMA)
  gemm_mfma<bf16><<<dim3(NPAD1 / 128, L_SEQ / 128), 256, 0, stream>>>(
      u_bf, DMODEL, w1p_bf, DMODEL, zx, DPROJ, DPROJ, DMODEL);
  // 2. conv + silu
  conv_silu_kernel<<<(L_SEQ * CONVDIM + 255) / 256, 256, 0, stream>>>(
      zx, conv_w, conv_b, xbc);
  // 2b. dt
  dt_kernel<<<(2 * L_SEQ * NHEADS + 255) / 256, 256, 0, stream>>>(
      zx, dt_bias, dt2);
  // 3a. G = C B^T per (b,c)
  gmat_kernel<<<2 * NCHUNK, 256, 0, stream>>>(xbc, G);
  // 3b. intra-chunk
  chunk_kernel<<<2 * NCHUNK * NHEADS, 256, 0, stream>>>(
      xbc, dt2, A_log, G, Yb, st, cs);
  // 3c. inter-chunk scan
  scan_kernel<<<(2 * NHEADS * HEADDIM * DSTATE) / 256, 256, 0, stream>>>(st, cs);
  // 3d. Y_off + D*x
  yoff_kernel<<<2 * NCHUNK * NHEADS, 256, 0, stream>>>(
      xbc, dt2, A_log, st, Dp, Yb);
  // 4a. cast out_proj_w (into dead G region)
  cast_kernel<<<(DMODEL * DINNER + 255) / 256, 256, 0, stream>>>(
      out_proj_w, w2_bf, DMODEL * DINNER, DMODEL * DINNER);
  // 4b. fd = x_og @ fc_D_w^T + D
  gemm_abt<bf16, float, float><<<dim3(1, L_SEQ / 64), 256, 0, stream>>>(
      xbc, CONVDIM, fc_D_w, DINNER, fd, NHEADS, L_SEQ, NHEADS, DINNER, Dp);
  // 5. combine + gate + RMSNorm
  combine_kernel<<<L_SEQ, 256, 0, stream>>>(Yb, xbc, zx, fd, norm_w, yn);
  // 6. out_proj (MFMA)
  gemm_mfma<float><<<dim3(DMODEL / 128, L_SEQ / 128), 256, 0, stream>>>(
      yn, DINNER, w2_bf, DINNER, out, DMODEL, DMODEL, DINNER);
}

// Round 5
// 1004.004 us; speedup vs baseline: 2.4707x; 1.6308x over previous
//
#include <hip/hip_runtime.h>
#include <hip/hip_bf16.h>
#include <math.h>

// ---------------- problem constants ----------------
#define L_SEQ   4096
#define DMODEL  1024
#define DINNER  2048
#define NHEADS  32
#define HEADDIM 64
#define DSTATE  128
#define NCHUNK  32
#define CHUNKL  128
#define CONVDIM 2560
#define DPROJ   4672   // 2*DINNER + 2*(2*DSTATE) + 2*NHEADS
#define NPAD1   4736   // DPROJ padded to multiple of 128 for MFMA gemm

typedef __hip_bfloat16 bf16;
__device__ __forceinline__ float b2f(bf16 x) { return __bfloat162float(x); }
__device__ __forceinline__ bf16 f2b(float x) { return __float2bfloat16(x); }
__device__ __forceinline__ float to_f(float x) { return x; }
__device__ __forceinline__ float to_f(bf16 x) { return b2f(x); }

typedef __attribute__((ext_vector_type(8))) short bf16x8v;
typedef __attribute__((ext_vector_type(4))) float f32x4v;

// zxbcdt column layout: [0,2048) = z ; [2048,4608) = xBC ; [4608,4672) = dt raw
// xBC_conv channel layout: [0,2048) = x ; fw B = [2048,2176) C = [2176,2304)
//                          bw B = [2304,2432) C = [2432,2560)  (bw streams time-flipped)

// ---------------- f32 -> bf16 cast (dst beyond n_src zero-filled) ----------------
__global__ __launch_bounds__(256) void cast_kernel(
    const float* __restrict__ src, bf16* __restrict__ dst, int n_src, int n_tot) {
  int i = blockIdx.x * 256 + threadIdx.x;
  if (i < n_tot) dst[i] = (i < n_src) ? f2b(src[i]) : f2b(0.f);
}

// ---------------- MFMA GEMM: C[m,n] = sum_k A[m,k]*B[n,k], bf16 in, f32 acc ----------------
template <typename TC>
__global__ __launch_bounds__(256) void gemm_mfma(
    const bf16* __restrict__ A, int lda,
    const bf16* __restrict__ B, int ldb,
    TC* __restrict__ C, int ldc,
    int N, int K) {
  __shared__ short As[128][32];
  __shared__ short Bs[128][32];
  int tid = threadIdx.x;
  int lane = tid & 63;
  int w = tid >> 6;            // wave 0..3
  int wr = w >> 1, wc = w & 1; // 2x2 wave grid
  int bm = blockIdx.y * 128;
  int bn = blockIdx.x * 128;
  f32x4v acc[4][4];
#pragma unroll
  for (int i = 0; i < 4; i++)
#pragma unroll
    for (int j = 0; j < 4; j++) acc[i][j] = (f32x4v){0.f, 0.f, 0.f, 0.f};

  const bf16* Ab = A + (size_t)(bm + w * 32 + (lane >> 2)) * lda + (lane & 3) * 8;
  const bf16* Bb = B + (size_t)(bn + w * 32 + (lane >> 2)) * ldb + (lane & 3) * 8;

  for (int k0 = 0; k0 < K; k0 += 32) {
    __builtin_amdgcn_global_load_lds(
        (const __attribute__((address_space(1))) void*)(Ab + k0),
        (__attribute__((address_space(3))) void*)&As[w * 32][0], 16, 0, 0);
    __builtin_amdgcn_global_load_lds(
        (const __attribute__((address_space(1))) void*)(Ab + (size_t)16 * lda + k0),
        (__attribute__((address_space(3))) void*)&As[w * 32 + 16][0], 16, 0, 0);
    __builtin_amdgcn_global_load_lds(
        (const __attribute__((address_space(1))) void*)(Bb + k0),
        (__attribute__((address_space(3))) void*)&Bs[w * 32][0], 16, 0, 0);
    __builtin_amdgcn_global_load_lds(
        (const __attribute__((address_space(1))) void*)(Bb + (size_t)16 * ldb + k0),
        (__attribute__((address_space(3))) void*)&Bs[w * 32 + 16][0], 16, 0, 0);
    __syncthreads();
    bf16x8v af[4], bv[4];
#pragma unroll
    for (int i = 0; i < 4; i++)
      af[i] = *(const bf16x8v*)&As[wr * 64 + i * 16 + (lane & 15)][(lane >> 4) * 8];
#pragma unroll
    for (int j = 0; j < 4; j++)
      bv[j] = *(const bf16x8v*)&Bs[wc * 64 + j * 16 + (lane & 15)][(lane >> 4) * 8];
#pragma unroll
    for (int i = 0; i < 4; i++)
#pragma unroll
      for (int j = 0; j < 4; j++)
        acc[i][j] = __builtin_amdgcn_mfma_f32_16x16x32_bf16(af[i], bv[j], acc[i][j], 0, 0, 0);
    __syncthreads();
  }
  int quad = lane >> 4;
  int cn = lane & 15;
#pragma unroll
  for (int i = 0; i < 4; i++) {
#pragma unroll
    for (int j = 0; j < 4; j++) {
      int col = bn + wc * 64 + j * 16 + cn;
      if (col < N) {
#pragma unroll
        for (int r = 0; r < 4; r++) {
          int row = bm + wr * 64 + i * 16 + quad * 4 + r;
          float v = acc[i][j][r];
          if constexpr (sizeof(TC) == 2) C[(size_t)row * ldc + col] = f2b(v);
          else                           C[(size_t)row * ldc + col] = v;
        }
      }
    }
  }
}

// ---------------- VALU GEMM (kept for tiny fc_D) ----------------
#define BM 64
#define BN 64
#define BKK 16
template <typename TA, typename TB, typename TC>
__global__ __launch_bounds__(256) void gemm_abt(
    const TA* __restrict__ A, int lda,
    const TB* __restrict__ B, int ldb,
    TC* __restrict__ C, int ldc,
    int M, int N, int K,
    const float* __restrict__ bias) {
  __shared__ float As[BKK][BM + 4];
  __shared__ float Bs[BKK][BN + 4];
  int tid = threadIdx.x;
  int bm = blockIdx.y * BM;
  int bn = blockIdx.x * BN;
  int tx = tid % 16, ty = tid / 16;
  int lr = tid / 16;
  int lc = tid % 16;
  float acc[4][4] = {};
  for (int k0 = 0; k0 < K; k0 += BKK) {
#pragma unroll
    for (int i = 0; i < 4; i++) {
      int row = lr + i * 16;
      int gr = bm + row;
      float v = 0.f;
      if (gr < M) v = to_f(A[(size_t)gr * lda + k0 + lc]);
      As[lc][row] = v;
    }
#pragma unroll
    for (int i = 0; i < 4; i++) {
      int row = lr + i * 16;
      int gr = bn + row;
      float v = 0.f;
      if (gr < N) v = to_f(B[(size_t)gr * ldb + k0 + lc]);
      Bs[lc][row] = v;
    }
    __syncthreads();
#pragma unroll
    for (int k = 0; k < BKK; k++) {
      float a0[4], b0[4];
#pragma unroll
      for (int i = 0; i < 4; i++) a0[i] = As[k][ty * 4 + i];
#pragma unroll
      for (int j = 0; j < 4; j++) b0[j] = Bs[k][tx * 4 + j];
#pragma unroll
      for (int i = 0; i < 4; i++)
#pragma unroll
        for (int j = 0; j < 4; j++) acc[i][j] += a0[i] * b0[j];
    }
    __syncthreads();
  }
#pragma unroll
  for (int i = 0; i < 4; i++) {
    int gr = bm + ty * 4 + i;
    if (gr >= M) continue;
#pragma unroll
    for (int j = 0; j < 4; j++) {
      int gc = bn + tx * 4 + j;
      if (gc < N) {
        float v = acc[i][j] + (bias ? bias[gc] : 0.f);
        if constexpr (sizeof(TC) == 2) C[(size_t)gr * ldc + gc] = f2b(v);
        else                           C[(size_t)gr * ldc + gc] = v;
      }
    }
  }
}

// ---------------- conv (depthwise causal, k=4) + SiLU ----------------
__global__ __launch_bounds__(256) void conv_silu_kernel(
    const bf16* __restrict__ zx, const float* __restrict__ conv_w,
    const float* __restrict__ conv_b, bf16* __restrict__ xbc) {
  int idx = blockIdx.x * 256 + threadIdx.x;   // L_SEQ*CONVDIM
  if (idx >= L_SEQ * CONVDIM) return;
  int ch = idx % CONVDIM;
  int t = idx / CONVDIM;
  const bf16* col = zx + DINNER + ch;         // xBC region
  float w0 = conv_w[ch * 4 + 0], w1 = conv_w[ch * 4 + 1];
  float w2 = conv_w[ch * 4 + 2], w3 = conv_w[ch * 4 + 3];
  float acc = conv_b[ch];
  if (t >= 3) acc += w0 * b2f(col[(size_t)(t - 3) * DPROJ]);
  if (t >= 2) acc += w1 * b2f(col[(size_t)(t - 2) * DPROJ]);
  if (t >= 1) acc += w2 * b2f(col[(size_t)(t - 1) * DPROJ]);
  acc += w3 * b2f(col[(size_t)t * DPROJ]);
  xbc[idx] = f2b(acc / (1.f + expf(-acc)));
}

// ---------------- dt: split fw/bw (bw time-flipped), softplus(dt + bias) ----------------
__global__ __launch_bounds__(256) void dt_kernel(
    const bf16* __restrict__ zx, const float* __restrict__ dt_bias,
    float* __restrict__ dt2) {
  int idx = blockIdx.x * 256 + threadIdx.x;   // 2*L_SEQ*NHEADS
  if (idx >= 2 * L_SEQ * NHEADS) return;
  int h = idx % NHEADS;
  int t = (idx / NHEADS) % L_SEQ;
  int b = idx / (NHEADS * L_SEQ);
  float v;
  if (b == 0) v = b2f(zx[(size_t)t * DPROJ + 4608 + h]);
  else        v = b2f(zx[(size_t)(L_SEQ - 1 - t) * DPROJ + 4608 + NHEADS + h]);
  v += dt_bias[h];
  dt2[idx] = (v > 20.f) ? v : log1pf(expf(v));
}

// ---------------- G[b,c,l,s] = sum_n C[l,n]*B[s,n]  (lower triangle only) ----------------
__global__ __launch_bounds__(256) void gmat_kernel(
    const bf16* __restrict__ xbc, float* __restrict__ G) {
  __shared__ float Bs[CHUNKL][DSTATE + 1];
  __shared__ float Cs[CHUNKL][DSTATE + 1];
  int bc = blockIdx.x;            // b*32 + c
  int b = bc / NCHUNK, c = bc % NCHUNK;
  int tid = threadIdx.x;
  int bofs = b ? 2304 : 2048;
  int cofs = b ? 2432 : 2176;
  for (int o = tid; o < CHUNKL * DSTATE; o += 256) {
    int n = o % DSTATE, s = o / DSTATE;
    int t = b ? (L_SEQ - 1 - (c * CHUNKL + s)) : (c * CHUNKL + s);
    const bf16* row = xbc + (size_t)t * CONVDIM;
    Bs[s][n] = b2f(row[bofs + n]);
    Cs[s][n] = b2f(row[cofs + n]);
  }
  __syncthreads();
  float* Gb = G + (size_t)bc * CHUNKL * CHUNKL;
  for (int o = tid; o < CHUNKL * CHUNKL; o += 256) {
    int s = o % CHUNKL, l = o / CHUNKL;
    float acc = 0.f;
    if (s <= l) {
#pragma unroll 8
      for (int n = 0; n < DSTATE; n++) acc += Cs[l][n] * Bs[s][n];
    }
    Gb[o] = acc;
  }
}

// ---------------- per-(b,c,h): Y_diag and chunk states (MFMA) ----------------
// LDS: WB time-shared (phase A: W[l][s] masked-decay matrix; phase B: BdT[n][l] =
// B[l][n]*decay[l]); xdtT[p][s] = x[s,p]*dt[s] serves as B-operand for Y_diag and
// A-operand for states. Row stride 136 shorts keeps b128 frag reads 16B-aligned.
__global__ __launch_bounds__(256) void chunk_kernel(
    const bf16* __restrict__ xbc, const float* __restrict__ dt2,
    const float* __restrict__ A_log, const float* __restrict__ G,
    float* __restrict__ Y, float* __restrict__ states,
    float* __restrict__ csum) {
  int gid = blockIdx.x;           // (b*32+c)*32 + h
  int h = gid % NHEADS;
  int bc = gid / NHEADS;
  int c = bc % NCHUNK, b = bc / NCHUNK;
  int tid = threadIdx.x;
  int lane = tid & 63;
  int w = tid >> 6;               // wave 0..3
  __shared__ bf16 WB[128][136];   // 34.0 KB
  __shared__ bf16 xdtT[64][136];  // 17.0 KB
  __shared__ float acs[CHUNKL];
  __shared__ float dtl[CHUNKL];
  __shared__ float decays[CHUNKL];
  if (tid < CHUNKL)
    dtl[tid] = dt2[((size_t)b * L_SEQ + c * CHUNKL + tid) * NHEADS + h];
  __syncthreads();
  if (tid == 0) {
    float Ah = -expf(A_log[h]);
    float s = 0.f;
    for (int l = 0; l < CHUNKL; l++) { s += Ah * dtl[l]; acs[l] = s; }
    csum[gid] = s;
  }
  __syncthreads();
  // stage xdtT[p][s] (coalesced global read over p), build W, build decays
  for (int o = tid; o < CHUNKL * HEADDIM; o += 256) {
    int p = o & 63, s = o >> 6;
    int t = b ? (L_SEQ - 1 - (c * CHUNKL + s)) : (c * CHUNKL + s);
    xdtT[p][s] = f2b(b2f(xbc[(size_t)t * CONVDIM + h * HEADDIM + p]) * dtl[s]);
  }
  {
    const float* Gb = G + (size_t)bc * CHUNKL * CHUNKL;
    for (int o = tid; o < CHUNKL * CHUNKL; o += 256) {
      int s = o & 127, l = o >> 7;
      float wv = (s <= l) ? Gb[o] * expf(acs[l] - acs[s]) : 0.f;
      WB[l][s] = f2b(wv);
    }
  }
  if (tid < CHUNKL) decays[tid] = expf(acs[CHUNKL - 1] - acs[tid]);
  __syncthreads();
  // Y_diag[l][p] = sum_s W[l][s]*xdt[s][p]; wave w -> l rows [32w, 32w+32)
  {
    f32x4v accY[2][4];
#pragma unroll
    for (int i = 0; i < 2; i++)
#pragma unroll
      for (int j = 0; j < 4; j++) accY[i][j] = (f32x4v){0.f, 0.f, 0.f, 0.f};
#pragma unroll
    for (int k0 = 0; k0 < 128; k0 += 32) {
      bf16x8v a0 = *(const bf16x8v*)&WB[w * 32 + (lane & 15)][(lane >> 4) * 8 + k0];
      bf16x8v a1 = *(const bf16x8v*)&WB[w * 32 + 16 + (lane & 15)][(lane >> 4) * 8 + k0];
      bf16x8v xv[4];
#pragma unroll
      for (int j = 0; j < 4; j++)
        xv[j] = *(const bf16x8v*)&xdtT[j * 16 + (lane & 15)][(lane >> 4) * 8 + k0];
#pragma unroll
      for (int j = 0; j < 4; j++) {
        accY[0][j] = __builtin_amdgcn_mfma_f32_16x16x32_bf16(a0, xv[j], accY[0][j], 0, 0, 0);
        accY[1][j] = __builtin_amdgcn_mfma_f32_16x16x32_bf16(a1, xv[j], accY[1][j], 0, 0, 0);
      }
    }
    int quad = lane >> 4, cn = lane & 15;
#pragma unroll
    for (int i = 0; i < 2; i++)
#pragma unroll
      for (int j = 0; j < 4; j++)
#pragma unroll
        for (int r = 0; r < 4; r++) {
          int l = w * 32 + i * 16 + quad * 4 + r;
          int p = j * 16 + cn;
          Y[((size_t)b * L_SEQ + c * CHUNKL + l) * DINNER + h * HEADDIM + p] = accY[i][j][r];
        }
  }
  __syncthreads();  // all Y_diag reads of WB done
  // rebuild WB as BdT[n][l] = B[l][n] * decays[l]
  {
    int bofs = b ? 2304 : 2048;
    for (int o = tid; o < CHUNKL * CHUNKL; o += 256) {
      int n = o & 127, l = o >> 7;
      int t = b ? (L_SEQ - 1 - (c * CHUNKL + l)) : (c * CHUNKL + l);
      WB[n][l] = f2b(b2f(xbc[(size_t)t * CONVDIM + bofs + n]) * decays[l]);
    }
  }
  __syncthreads();
  // states[p][n] = sum_l xdtT[p][l]*BdT[n][l]; wave w -> p-tile w (rows 16w..16w+15)
  {
    f32x4v accS[8];
#pragma unroll
    for (int j = 0; j < 8; j++) accS[j] = (f32x4v){0.f, 0.f, 0.f, 0.f};
#pragma unroll
    for (int k0 = 0; k0 < 128; k0 += 32) {
      bf16x8v av = *(const bf16x8v*)&xdtT[w * 16 + (lane & 15)][(lane >> 4) * 8 + k0];
#pragma unroll
      for (int j = 0; j < 8; j++) {
        bf16x8v bv = *(const bf16x8v*)&WB[j * 16 + (lane & 15)][(lane >> 4) * 8 + k0];
        accS[j] = __builtin_amdgcn_mfma_f32_16x16x32_bf16(av, bv, accS[j], 0, 0, 0);
      }
    }
    int quad = lane >> 4, cn = lane & 15;
    float* st = states + (size_t)gid * (HEADDIM * DSTATE);
#pragma unroll
    for (int j = 0; j < 8; j++)
#pragma unroll
      for (int r = 0; r < 4; r++) {
        int p = w * 16 + quad * 4 + r;
        int n = j * 16 + cn;
        st[p * DSTATE + n] = accS[j][r];
      }
  }
}

// ---------------- inter-chunk scan (in place: states -> state_in) ----------------
__global__ __launch_bounds__(256) void scan_kernel(
    float* __restrict__ states, const float* __restrict__ csum) {
  int idx = blockIdx.x * 256 + threadIdx.x;  // 2*NHEADS*HEADDIM*DSTATE
  int n = idx % DSTATE;
  int p = (idx / DSTATE) % HEADDIM;
  int h = (idx / (DSTATE * HEADDIM)) % NHEADS;
  int b = idx / (DSTATE * HEADDIM * NHEADS);
  float S = 0.f;
  for (int c = 0; c < NCHUNK; c++) {
    int gid = (b * NCHUNK + c) * NHEADS + h;
    size_t off = (size_t)gid * (HEADDIM * DSTATE) + p * DSTATE + n;
    float tmp = states[off];
    states[off] = S;
    S = expf(csum[gid]) * S + tmp;
  }
}

// ---------------- Y_off + D*x, accumulate into Y ----------------
__global__ __launch_bounds__(256) void yoff_kernel(
    const bf16* __restrict__ xbc, const float* __restrict__ dt2,
    const float* __restrict__ A_log, const float* __restrict__ states,
    const float* __restrict__ Dp, float* __restrict__ Y) {
  int gid = blockIdx.x;
  int h = gid % NHEADS;
  int bc = gid / NHEADS;
  int c = bc % NCHUNK, b = bc / NCHUNK;
  int tid = threadIdx.x;
  __shared__ float S[HEADDIM][DSTATE + 1];
  __shared__ float acs[CHUNKL];
  __shared__ float dtl[CHUNKL];
  if (tid < CHUNKL)
    dtl[tid] = dt2[((size_t)b * L_SEQ + c * CHUNKL + tid) * NHEADS + h];
  __syncthreads();
  if (tid == 0) {
    float Ah = -expf(A_log[h]);
    float s = 0.f;
    for (int l = 0; l < CHUNKL; l++) { s += Ah * dtl[l]; acs[l] = s; }
  }
  const float* st = states + (size_t)gid * (HEADDIM * DSTATE);
  for (int o = tid; o < HEADDIM * DSTATE; o += 256) {
    int n = o % DSTATE, p = o / DSTATE;
    S[p][n] = st[o];
  }
  __syncthreads();
  int cofs = b ? 2432 : 2176;
  int p = tid % HEADDIM;
  int lg = tid / HEADDIM;
  float Dh = Dp[h];
  for (int i = 0; i < 32; i++) {
    int l = lg * 32 + i;
    int t = b ? (L_SEQ - 1 - (c * CHUNKL + l)) : (c * CHUNKL + l);
    const bf16* crow = xbc + (size_t)t * CONVDIM + cofs;
    float acc = 0.f;
#pragma unroll 8
    for (int n = 0; n < DSTATE; n++) acc += b2f(crow[n]) * S[p][n];
    float eA = expf(acs[l]);
    size_t yi = ((size_t)b * L_SEQ + c * CHUNKL + l) * DINNER + h * HEADDIM + p;
    float xv = b2f(xbc[(size_t)t * CONVDIM + h * HEADDIM + p]);
    Y[yi] = Y[yi] + eA * acc + xv * Dh;
  }
}

// ---------------- combine: shift, flip, +x*fd, gate, RMSNorm ----------------
__global__ __launch_bounds__(256) void combine_kernel(
    const float* __restrict__ Y, const bf16* __restrict__ xbc,
    const bf16* __restrict__ zx, const float* __restrict__ fd,
    const float* __restrict__ norm_w, bf16* __restrict__ yn) {
  int t = blockIdx.x;
  int tid = threadIdx.x;
  float yg[8];
  float ss = 0.f;
#pragma unroll
  for (int i = 0; i < 8; i++) {
    int j = tid + i * 256;
    float yfw = (t >= 1) ? Y[(size_t)(t - 1) * DINNER + j] : 0.f;
    float ybw = (t <= L_SEQ - 2)
                    ? Y[((size_t)L_SEQ + (L_SEQ - 2 - t)) * DINNER + j] : 0.f;
    float xog = b2f(xbc[(size_t)t * CONVDIM + j]);
    float fdv = fd[t * NHEADS + (j >> 6)];
    float z = b2f(zx[(size_t)t * DPROJ + j]);
    float y = yfw + ybw + xog * fdv;
    float g = y * (z / (1.f + expf(-z)));
    yg[i] = g;
    ss += g * g;
  }
#pragma unroll
  for (int off = 32; off > 0; off >>= 1) ss += __shfl_down(ss, off);
  __shared__ float red[4];
  if ((tid & 63) == 0) red[tid >> 6] = ss;
  __syncthreads();
  float tot = red[0] + red[1] + red[2] + red[3];
  float scale = rsqrtf(tot / (float)DINNER + 1e-5f);
#pragma unroll
  for (int i = 0; i < 8; i++) {
    int j = tid + i * 256;
    yn[(size_t)t * DINNER + j] = f2b(yg[i] * scale * norm_w[j]);
  }
}

// ---------------- launch ----------------
extern "C" void kernel_launch(void* const* d_in, const int* in_sizes, int n_in,
                              void* d_out, int out_size, void* d_ws, size_t ws_size,
                              hipStream_t stream) {
  const float* u         = (const float*)d_in[0];
  const float* in_proj_w = (const float*)d_in[1];
  const float* conv_w    = (const float*)d_in[2];
  const float* conv_b    = (const float*)d_in[3];
  const float* dt_bias   = (const float*)d_in[4];
  const float* A_log     = (const float*)d_in[5];
  const float* Dp        = (const float*)d_in[6];
  const float* fc_D_w    = (const float*)d_in[7];
  const float* norm_w    = (const float*)d_in[8];
  const float* out_proj_w= (const float*)d_in[9];
  float* out = (float*)d_out;

  char* base = (char*)d_ws;
  bf16*  zx  = (bf16*)base;  base += (size_t)L_SEQ * DPROJ * 2;                    // 38.3 MB
  bf16*  xbc = (bf16*)base;  base += (size_t)L_SEQ * CONVDIM * 2;                  // 21.0 MB
  float* dt2 = (float*)base; base += (size_t)2 * L_SEQ * NHEADS * 4;               //  1.0 MB
  float* G   = (float*)base; base += (size_t)2 * NCHUNK * CHUNKL * CHUNKL * 4;     //  4.2 MB
  float* Yb  = (float*)base; base += (size_t)2 * L_SEQ * DINNER * 4;               // 67.1 MB
  float* st  = (float*)base; base += (size_t)2 * NCHUNK * NHEADS * HEADDIM * DSTATE * 4; // 67.1 MB
  float* cs  = (float*)base; base += (size_t)2 * NCHUNK * NHEADS * 4;              //  8 KB
  // aliases into dead regions:
  bf16*  u_bf   = (bf16*)Yb;                          // 8.4 MB   (Yb live only after chunk_kernel)
  bf16*  w1p_bf = (bf16*)((char*)Yb + 9437184);       // 9.7 MB   (padded in_proj_w)
  bf16*  w2_bf  = (bf16*)G;                           // 4.0 MB   (G dead after chunk_kernel)
  bf16*  yn     = (bf16*)st;                          // 16.8 MB  (st dead after yoff_kernel)
  float* fd     = (float*)((char*)st + 33554432);     //  0.5 MB

  // 0. casts for MFMA gemm1
  cast_kernel<<<(L_SEQ * DMODEL + 255) / 256, 256, 0, stream>>>(
      u, u_bf, L_SEQ * DMODEL, L_SEQ * DMODEL);
  cast_kernel<<<(NPAD1 * DMODEL + 255) / 256, 256, 0, stream>>>(
      in_proj_w, w1p_bf, DPROJ * DMODEL, NPAD1 * DMODEL);
  // 1. in_proj: zx = u @ in_proj_w^T  (MFMA)
  gemm_mfma<bf16><<<dim3(NPAD1 / 128, L_SEQ / 128), 256, 0, stream>>>(
      u_bf, DMODEL, w1p_bf, DMODEL, zx, DPROJ, DPROJ, DMODEL);
  // 2. conv + silu
  conv_silu_kernel<<<(L_SEQ * CONVDIM + 255) / 256, 256, 0, stream>>>(
      zx, conv_w, conv_b, xbc);
  // 2b. dt
  dt_kernel<<<(2 * L_SEQ * NHEADS + 255) / 256, 256, 0, stream>>>(
      zx, dt_bias, dt2);
  // 3a. G = C B^T per (b,c)
  gmat_kernel<<<2 * NCHUNK, 256, 0, stream>>>(xbc, G);
  // 3b. intra-chunk (MFMA)
  chunk_kernel<<<2 * NCHUNK * NHEADS, 256, 0, stream>>>(
      xbc, dt2, A_log, G, Yb, st, cs);
  // 3c. inter-chunk scan
  scan_kernel<<<(2 * NHEADS * HEADDIM * DSTATE) / 256, 256, 0, stream>>>(st, cs);
  // 3d. Y_off + D*x
  yoff_kernel<<<2 * NCHUNK * NHEADS, 256, 0, stream>>>(
      xbc, dt2, A_log, st, Dp, Yb);
  // 4a. cast out_proj_w (into dead G region)
  cast_kernel<<<(DMODEL * DINNER + 255) / 256, 256, 0, stream>>>(
      out_proj_w, w2_bf, DMODEL * DINNER, DMODEL * DINNER);
  // 4b. fd = x_og @ fc_D_w^T + D
  gemm_abt<bf16, float, float><<<dim3(1, L_SEQ / 64), 256, 0, stream>>>(
      xbc, CONVDIM, fc_D_w, DINNER, fd, NHEADS, L_SEQ, NHEADS, DINNER, Dp);
  // 5. combine + gate + RMSNorm
  combine_kernel<<<L_SEQ, 256, 0, stream>>>(Yb, xbc, zx, fd, norm_w, yn);
  // 6. out_proj (MFMA)
  gemm_mfma<float><<<dim3(DMODEL / 128, L_SEQ / 128), 256, 0, stream>>>(
      yn, DINNER, w2_bf, DINNER, out, DMODEL, DMODEL, DINNER);
}

// Round 6
// 763.924 us; speedup vs baseline: 3.2472x; 1.3143x over previous
//
#include <hip/hip_runtime.h>
#include <hip/hip_bf16.h>
#include <math.h>

// ---------------- problem constants ----------------
#define L_SEQ   4096
#define DMODEL  1024
#define DINNER  2048
#define NHEADS  32
#define HEADDIM 64
#define DSTATE  128
#define NCHUNK  32
#define CHUNKL  128
#define CONVDIM 2560
#define DPROJ   4672   // 2*DINNER + 2*(2*DSTATE) + 2*NHEADS
#define NPAD1   4736   // DPROJ padded to multiple of 128 for MFMA gemm

typedef __hip_bfloat16 bf16;
__device__ __forceinline__ float b2f(bf16 x) { return __bfloat162float(x); }
__device__ __forceinline__ bf16 f2b(float x) { return __float2bfloat16(x); }
__device__ __forceinline__ float to_f(float x) { return x; }
__device__ __forceinline__ float to_f(bf16 x) { return b2f(x); }

typedef __attribute__((ext_vector_type(8))) short bf16x8v;
typedef __attribute__((ext_vector_type(4))) float f32x4v;

// zxbcdt column layout: [0,2048) = z ; [2048,4608) = xBC ; [4608,4672) = dt raw
// xBC_conv channel layout: [0,2048) = x ; fw B = [2048,2176) C = [2176,2304)
//                          bw B = [2304,2432) C = [2432,2560)  (bw streams time-flipped)

// ---------------- f32 -> bf16 cast (dst beyond n_src zero-filled) ----------------
__global__ __launch_bounds__(256) void cast_kernel(
    const float* __restrict__ src, bf16* __restrict__ dst, int n_src, int n_tot) {
  int i = blockIdx.x * 256 + threadIdx.x;
  if (i < n_tot) dst[i] = (i < n_src) ? f2b(src[i]) : f2b(0.f);
}

// ---------------- MFMA GEMM: C[m,n] = sum_k A[m,k]*B[n,k], bf16 in, f32 acc ----------------
template <typename TC>
__global__ __launch_bounds__(256) void gemm_mfma(
    const bf16* __restrict__ A, int lda,
    const bf16* __restrict__ B, int ldb,
    TC* __restrict__ C, int ldc,
    int N, int K) {
  __shared__ short As[128][32];
  __shared__ short Bs[128][32];
  int tid = threadIdx.x;
  int lane = tid & 63;
  int w = tid >> 6;            // wave 0..3
  int wr = w >> 1, wc = w & 1; // 2x2 wave grid
  int bm = blockIdx.y * 128;
  int bn = blockIdx.x * 128;
  f32x4v acc[4][4];
#pragma unroll
  for (int i = 0; i < 4; i++)
#pragma unroll
    for (int j = 0; j < 4; j++) acc[i][j] = (f32x4v){0.f, 0.f, 0.f, 0.f};

  const bf16* Ab = A + (size_t)(bm + w * 32 + (lane >> 2)) * lda + (lane & 3) * 8;
  const bf16* Bb = B + (size_t)(bn + w * 32 + (lane >> 2)) * ldb + (lane & 3) * 8;

  for (int k0 = 0; k0 < K; k0 += 32) {
    __builtin_amdgcn_global_load_lds(
        (const __attribute__((address_space(1))) void*)(Ab + k0),
        (__attribute__((address_space(3))) void*)&As[w * 32][0], 16, 0, 0);
    __builtin_amdgcn_global_load_lds(
        (const __attribute__((address_space(1))) void*)(Ab + (size_t)16 * lda + k0),
        (__attribute__((address_space(3))) void*)&As[w * 32 + 16][0], 16, 0, 0);
    __builtin_amdgcn_global_load_lds(
        (const __attribute__((address_space(1))) void*)(Bb + k0),
        (__attribute__((address_space(3))) void*)&Bs[w * 32][0], 16, 0, 0);
    __builtin_amdgcn_global_load_lds(
        (const __attribute__((address_space(1))) void*)(Bb + (size_t)16 * ldb + k0),
        (__attribute__((address_space(3))) void*)&Bs[w * 32 + 16][0], 16, 0, 0);
    __syncthreads();
    bf16x8v af[4], bv[4];
#pragma unroll
    for (int i = 0; i < 4; i++)
      af[i] = *(const bf16x8v*)&As[wr * 64 + i * 16 + (lane & 15)][(lane >> 4) * 8];
#pragma unroll
    for (int j = 0; j < 4; j++)
      bv[j] = *(const bf16x8v*)&Bs[wc * 64 + j * 16 + (lane & 15)][(lane >> 4) * 8];
#pragma unroll
    for (int i = 0; i < 4; i++)
#pragma unroll
      for (int j = 0; j < 4; j++)
        acc[i][j] = __builtin_amdgcn_mfma_f32_16x16x32_bf16(af[i], bv[j], acc[i][j], 0, 0, 0);
    __syncthreads();
  }
  int quad = lane >> 4;
  int cn = lane & 15;
#pragma unroll
  for (int i = 0; i < 4; i++) {
#pragma unroll
    for (int j = 0; j < 4; j++) {
      int col = bn + wc * 64 + j * 16 + cn;
      if (col < N) {
#pragma unroll
        for (int r = 0; r < 4; r++) {
          int row = bm + wr * 64 + i * 16 + quad * 4 + r;
          float v = acc[i][j][r];
          if constexpr (sizeof(TC) == 2) C[(size_t)row * ldc + col] = f2b(v);
          else                           C[(size_t)row * ldc + col] = v;
        }
      }
    }
  }
}

// ---------------- VALU GEMM (kept for tiny fc_D) ----------------
#define BM 64
#define BN 64
#define BKK 16
template <typename TA, typename TB, typename TC>
__global__ __launch_bounds__(256) void gemm_abt(
    const TA* __restrict__ A, int lda,
    const TB* __restrict__ B, int ldb,
    TC* __restrict__ C, int ldc,
    int M, int N, int K,
    const float* __restrict__ bias) {
  __shared__ float As[BKK][BM + 4];
  __shared__ float Bs[BKK][BN + 4];
  int tid = threadIdx.x;
  int bm = blockIdx.y * BM;
  int bn = blockIdx.x * BN;
  int tx = tid % 16, ty = tid / 16;
  int lr = tid / 16;
  int lc = tid % 16;
  float acc[4][4] = {};
  for (int k0 = 0; k0 < K; k0 += BKK) {
#pragma unroll
    for (int i = 0; i < 4; i++) {
      int row = lr + i * 16;
      int gr = bm + row;
      float v = 0.f;
      if (gr < M) v = to_f(A[(size_t)gr * lda + k0 + lc]);
      As[lc][row] = v;
    }
#pragma unroll
    for (int i = 0; i < 4; i++) {
      int row = lr + i * 16;
      int gr = bn + row;
      float v = 0.f;
      if (gr < N) v = to_f(B[(size_t)gr * ldb + k0 + lc]);
      Bs[lc][row] = v;
    }
    __syncthreads();
#pragma unroll
    for (int k = 0; k < BKK; k++) {
      float a0[4], b0[4];
#pragma unroll
      for (int i = 0; i < 4; i++) a0[i] = As[k][ty * 4 + i];
#pragma unroll
      for (int j = 0; j < 4; j++) b0[j] = Bs[k][tx * 4 + j];
#pragma unroll
      for (int i = 0; i < 4; i++)
#pragma unroll
        for (int j = 0; j < 4; j++) acc[i][j] += a0[i] * b0[j];
    }
    __syncthreads();
  }
#pragma unroll
  for (int i = 0; i < 4; i++) {
    int gr = bm + ty * 4 + i;
    if (gr >= M) continue;
#pragma unroll
    for (int j = 0; j < 4; j++) {
      int gc = bn + tx * 4 + j;
      if (gc < N) {
        float v = acc[i][j] + (bias ? bias[gc] : 0.f);
        if constexpr (sizeof(TC) == 2) C[(size_t)gr * ldc + gc] = f2b(v);
        else                           C[(size_t)gr * ldc + gc] = v;
      }
    }
  }
}

// ---------------- conv (depthwise causal, k=4) + SiLU ----------------
__global__ __launch_bounds__(256) void conv_silu_kernel(
    const bf16* __restrict__ zx, const float* __restrict__ conv_w,
    const float* __restrict__ conv_b, bf16* __restrict__ xbc) {
  int idx = blockIdx.x * 256 + threadIdx.x;   // L_SEQ*CONVDIM
  if (idx >= L_SEQ * CONVDIM) return;
  int ch = idx % CONVDIM;
  int t = idx / CONVDIM;
  const bf16* col = zx + DINNER + ch;         // xBC region
  float w0 = conv_w[ch * 4 + 0], w1 = conv_w[ch * 4 + 1];
  float w2 = conv_w[ch * 4 + 2], w3 = conv_w[ch * 4 + 3];
  float acc = conv_b[ch];
  if (t >= 3) acc += w0 * b2f(col[(size_t)(t - 3) * DPROJ]);
  if (t >= 2) acc += w1 * b2f(col[(size_t)(t - 2) * DPROJ]);
  if (t >= 1) acc += w2 * b2f(col[(size_t)(t - 1) * DPROJ]);
  acc += w3 * b2f(col[(size_t)t * DPROJ]);
  xbc[idx] = f2b(acc / (1.f + expf(-acc)));
}

// ---------------- dt: split fw/bw (bw time-flipped), softplus(dt + bias) ----------------
__global__ __launch_bounds__(256) void dt_kernel(
    const bf16* __restrict__ zx, const float* __restrict__ dt_bias,
    float* __restrict__ dt2) {
  int idx = blockIdx.x * 256 + threadIdx.x;   // 2*L_SEQ*NHEADS
  if (idx >= 2 * L_SEQ * NHEADS) return;
  int h = idx % NHEADS;
  int t = (idx / NHEADS) % L_SEQ;
  int b = idx / (NHEADS * L_SEQ);
  float v;
  if (b == 0) v = b2f(zx[(size_t)t * DPROJ + 4608 + h]);
  else        v = b2f(zx[(size_t)(L_SEQ - 1 - t) * DPROJ + 4608 + NHEADS + h]);
  v += dt_bias[h];
  dt2[idx] = (v > 20.f) ? v : log1pf(expf(v));
}

// ---------------- G[b,c,l,s] = sum_n C[l,n]*B[s,n]  (lower triangle only) ----------------
__global__ __launch_bounds__(256) void gmat_kernel(
    const bf16* __restrict__ xbc, float* __restrict__ G) {
  __shared__ float Bs[CHUNKL][DSTATE + 1];
  __shared__ float Cs[CHUNKL][DSTATE + 1];
  int bc = blockIdx.x;            // b*32 + c
  int b = bc / NCHUNK, c = bc % NCHUNK;
  int tid = threadIdx.x;
  int bofs = b ? 2304 : 2048;
  int cofs = b ? 2432 : 2176;
  for (int o = tid; o < CHUNKL * DSTATE; o += 256) {
    int n = o % DSTATE, s = o / DSTATE;
    int t = b ? (L_SEQ - 1 - (c * CHUNKL + s)) : (c * CHUNKL + s);
    const bf16* row = xbc + (size_t)t * CONVDIM;
    Bs[s][n] = b2f(row[bofs + n]);
    Cs[s][n] = b2f(row[cofs + n]);
  }
  __syncthreads();
  float* Gb = G + (size_t)bc * CHUNKL * CHUNKL;
  for (int o = tid; o < CHUNKL * CHUNKL; o += 256) {
    int s = o % CHUNKL, l = o / CHUNKL;
    float acc = 0.f;
    if (s <= l) {
#pragma unroll 8
      for (int n = 0; n < DSTATE; n++) acc += Cs[l][n] * Bs[s][n];
    }
    Gb[o] = acc;
  }
}

// ---------------- per-(b,c,h): Y_diag and chunk states (MFMA) ----------------
__global__ __launch_bounds__(256) void chunk_kernel(
    const bf16* __restrict__ xbc, const float* __restrict__ dt2,
    const float* __restrict__ A_log, const float* __restrict__ G,
    float* __restrict__ Y, float* __restrict__ states,
    float* __restrict__ csum) {
  int gid = blockIdx.x;           // (b*32+c)*32 + h
  int h = gid % NHEADS;
  int bc = gid / NHEADS;
  int c = bc % NCHUNK, b = bc / NCHUNK;
  int tid = threadIdx.x;
  int lane = tid & 63;
  int w = tid >> 6;               // wave 0..3
  __shared__ bf16 WB[128][136];   // 34.0 KB
  __shared__ bf16 xdtT[64][136];  // 17.0 KB
  __shared__ float acs[CHUNKL];
  __shared__ float dtl[CHUNKL];
  __shared__ float decays[CHUNKL];
  if (tid < CHUNKL)
    dtl[tid] = dt2[((size_t)b * L_SEQ + c * CHUNKL + tid) * NHEADS + h];
  __syncthreads();
  if (tid == 0) {
    float Ah = -expf(A_log[h]);
    float s = 0.f;
    for (int l = 0; l < CHUNKL; l++) { s += Ah * dtl[l]; acs[l] = s; }
    csum[gid] = s;
  }
  __syncthreads();
  for (int o = tid; o < CHUNKL * HEADDIM; o += 256) {
    int p = o & 63, s = o >> 6;
    int t = b ? (L_SEQ - 1 - (c * CHUNKL + s)) : (c * CHUNKL + s);
    xdtT[p][s] = f2b(b2f(xbc[(size_t)t * CONVDIM + h * HEADDIM + p]) * dtl[s]);
  }
  {
    const float* Gb = G + (size_t)bc * CHUNKL * CHUNKL;
    for (int o = tid; o < CHUNKL * CHUNKL; o += 256) {
      int s = o & 127, l = o >> 7;
      float wv = (s <= l) ? Gb[o] * expf(acs[l] - acs[s]) : 0.f;
      WB[l][s] = f2b(wv);
    }
  }
  if (tid < CHUNKL) decays[tid] = expf(acs[CHUNKL - 1] - acs[tid]);
  __syncthreads();
  // Y_diag[l][p] = sum_s W[l][s]*xdt[s][p]; wave w -> l rows [32w, 32w+32)
  {
    f32x4v accY[2][4];
#pragma unroll
    for (int i = 0; i < 2; i++)
#pragma unroll
      for (int j = 0; j < 4; j++) accY[i][j] = (f32x4v){0.f, 0.f, 0.f, 0.f};
#pragma unroll
    for (int k0 = 0; k0 < 128; k0 += 32) {
      bf16x8v a0 = *(const bf16x8v*)&WB[w * 32 + (lane & 15)][(lane >> 4) * 8 + k0];
      bf16x8v a1 = *(const bf16x8v*)&WB[w * 32 + 16 + (lane & 15)][(lane >> 4) * 8 + k0];
      bf16x8v xv[4];
#pragma unroll
      for (int j = 0; j < 4; j++)
        xv[j] = *(const bf16x8v*)&xdtT[j * 16 + (lane & 15)][(lane >> 4) * 8 + k0];
#pragma unroll
      for (int j = 0; j < 4; j++) {
        accY[0][j] = __builtin_amdgcn_mfma_f32_16x16x32_bf16(a0, xv[j], accY[0][j], 0, 0, 0);
        accY[1][j] = __builtin_amdgcn_mfma_f32_16x16x32_bf16(a1, xv[j], accY[1][j], 0, 0, 0);
      }
    }
    int quad = lane >> 4, cn = lane & 15;
#pragma unroll
    for (int i = 0; i < 2; i++)
#pragma unroll
      for (int j = 0; j < 4; j++)
#pragma unroll
        for (int r = 0; r < 4; r++) {
          int l = w * 32 + i * 16 + quad * 4 + r;
          int p = j * 16 + cn;
          Y[((size_t)b * L_SEQ + c * CHUNKL + l) * DINNER + h * HEADDIM + p] = accY[i][j][r];
        }
  }
  __syncthreads();  // all Y_diag reads of WB done
  // rebuild WB as BdT[n][l] = B[l][n] * decays[l]
  {
    int bofs = b ? 2304 : 2048;
    for (int o = tid; o < CHUNKL * CHUNKL; o += 256) {
      int n = o & 127, l = o >> 7;
      int t = b ? (L_SEQ - 1 - (c * CHUNKL + l)) : (c * CHUNKL + l);
      WB[n][l] = f2b(b2f(xbc[(size_t)t * CONVDIM + bofs + n]) * decays[l]);
    }
  }
  __syncthreads();
  // states[p][n] = sum_l xdtT[p][l]*BdT[n][l]; wave w -> p-tile w
  {
    f32x4v accS[8];
#pragma unroll
    for (int j = 0; j < 8; j++) accS[j] = (f32x4v){0.f, 0.f, 0.f, 0.f};
#pragma unroll
    for (int k0 = 0; k0 < 128; k0 += 32) {
      bf16x8v av = *(const bf16x8v*)&xdtT[w * 16 + (lane & 15)][(lane >> 4) * 8 + k0];
#pragma unroll
      for (int j = 0; j < 8; j++) {
        bf16x8v bv = *(const bf16x8v*)&WB[j * 16 + (lane & 15)][(lane >> 4) * 8 + k0];
        accS[j] = __builtin_amdgcn_mfma_f32_16x16x32_bf16(av, bv, accS[j], 0, 0, 0);
      }
    }
    int quad = lane >> 4, cn = lane & 15;
    float* st = states + (size_t)gid * (HEADDIM * DSTATE);
#pragma unroll
    for (int j = 0; j < 8; j++)
#pragma unroll
      for (int r = 0; r < 4; r++) {
        int p = w * 16 + quad * 4 + r;
        int n = j * 16 + cn;
        st[p * DSTATE + n] = accS[j][r];
      }
  }
}

// ---------------- inter-chunk scan (in place: states -> state_in) ----------------
__global__ __launch_bounds__(256) void scan_kernel(
    float* __restrict__ states, const float* __restrict__ csum) {
  int idx = blockIdx.x * 256 + threadIdx.x;  // 2*NHEADS*HEADDIM*DSTATE
  int n = idx % DSTATE;
  int p = (idx / DSTATE) % HEADDIM;
  int h = (idx / (DSTATE * HEADDIM)) % NHEADS;
  int b = idx / (DSTATE * HEADDIM * NHEADS);
  float S = 0.f;
  for (int c = 0; c < NCHUNK; c++) {
    int gid = (b * NCHUNK + c) * NHEADS + h;
    size_t off = (size_t)gid * (HEADDIM * DSTATE) + p * DSTATE + n;
    float tmp = states[off];
    states[off] = S;
    S = expf(csum[gid]) * S + tmp;
  }
}

// ---------------- Y_off + D*x accumulate into Y (MFMA) ----------------
// Y_off[l][p] = sum_n (C[l][n]*exp(acs[l])) * St[p][n]; then Y += Y_off + x*D.
// Ce: 128x128 A-operand (decay folded in), St: 64x128 B-operand; stride 136
// keeps ds_read_b128 16B-aligned. LDS ~53.8 KB -> 3 blocks/CU.
__global__ __launch_bounds__(256) void yoff_kernel(
    const bf16* __restrict__ xbc, const float* __restrict__ dt2,
    const float* __restrict__ A_log, const float* __restrict__ states,
    const float* __restrict__ Dp, float* __restrict__ Y) {
  int gid = blockIdx.x;
  int h = gid % NHEADS;
  int bc = gid / NHEADS;
  int c = bc % NCHUNK, b = bc / NCHUNK;
  int tid = threadIdx.x;
  int lane = tid & 63;
  int w = tid >> 6;               // wave 0..3
  __shared__ bf16 Ce[128][136];   // 34.0 KB
  __shared__ bf16 St[64][136];    // 17.0 KB
  __shared__ float acs[CHUNKL];
  __shared__ float dtl[CHUNKL];
  __shared__ float eAl[CHUNKL];
  if (tid < CHUNKL)
    dtl[tid] = dt2[((size_t)b * L_SEQ + c * CHUNKL + tid) * NHEADS + h];
  __syncthreads();
  if (tid == 0) {
    float Ah = -expf(A_log[h]);
    float s = 0.f;
    for (int l = 0; l < CHUNKL; l++) { s += Ah * dtl[l]; acs[l] = s; }
  }
  __syncthreads();
  if (tid < CHUNKL) eAl[tid] = expf(acs[tid]);   // <= 1, no overflow
  __syncthreads();
  int cofs = b ? 2432 : 2176;
  for (int o = tid; o < CHUNKL * DSTATE; o += 256) {
    int n = o & 127, l = o >> 7;
    int t = b ? (L_SEQ - 1 - (c * CHUNKL + l)) : (c * CHUNKL + l);
    Ce[l][n] = f2b(b2f(xbc[(size_t)t * CONVDIM + cofs + n]) * eAl[l]);
  }
  const float* stp = states + (size_t)gid * (HEADDIM * DSTATE);
  for (int o = tid; o < HEADDIM * DSTATE; o += 256) {
    int n = o & 127, p = o >> 7;
    St[p][n] = f2b(stp[o]);
  }
  __syncthreads();
  f32x4v accY[2][4];
#pragma unroll
  for (int i = 0; i < 2; i++)
#pragma unroll
    for (int j = 0; j < 4; j++) accY[i][j] = (f32x4v){0.f, 0.f, 0.f, 0.f};
#pragma unroll
  for (int k0 = 0; k0 < 128; k0 += 32) {
    bf16x8v a0 = *(const bf16x8v*)&Ce[w * 32 + (lane & 15)][(lane >> 4) * 8 + k0];
    bf16x8v a1 = *(const bf16x8v*)&Ce[w * 32 + 16 + (lane & 15)][(lane >> 4) * 8 + k0];
    bf16x8v bv[4];
#pragma unroll
    for (int j = 0; j < 4; j++)
      bv[j] = *(const bf16x8v*)&St[j * 16 + (lane & 15)][(lane >> 4) * 8 + k0];
#pragma unroll
    for (int j = 0; j < 4; j++) {
      accY[0][j] = __builtin_amdgcn_mfma_f32_16x16x32_bf16(a0, bv[j], accY[0][j], 0, 0, 0);
      accY[1][j] = __builtin_amdgcn_mfma_f32_16x16x32_bf16(a1, bv[j], accY[1][j], 0, 0, 0);
    }
  }
  int quad = lane >> 4, cn = lane & 15;
  float Dh = Dp[h];
#pragma unroll
  for (int i = 0; i < 2; i++)
#pragma unroll
    for (int j = 0; j < 4; j++)
#pragma unroll
      for (int r = 0; r < 4; r++) {
        int l = w * 32 + i * 16 + quad * 4 + r;
        int p = j * 16 + cn;
        int t = b ? (L_SEQ - 1 - (c * CHUNKL + l)) : (c * CHUNKL + l);
        float xv = b2f(xbc[(size_t)t * CONVDIM + h * HEADDIM + p]);
        size_t yi = ((size_t)b * L_SEQ + c * CHUNKL + l) * DINNER + h * HEADDIM + p;
        Y[yi] = Y[yi] + accY[i][j][r] + xv * Dh;
      }
}

// ---------------- combine: shift, flip, +x*fd, gate, RMSNorm ----------------
__global__ __launch_bounds__(256) void combine_kernel(
    const float* __restrict__ Y, const bf16* __restrict__ xbc,
    const bf16* __restrict__ zx, const float* __restrict__ fd,
    const float* __restrict__ norm_w, bf16* __restrict__ yn) {
  int t = blockIdx.x;
  int tid = threadIdx.x;
  float yg[8];
  float ss = 0.f;
#pragma unroll
  for (int i = 0; i < 8; i++) {
    int j = tid + i * 256;
    float yfw = (t >= 1) ? Y[(size_t)(t - 1) * DINNER + j] : 0.f;
    float ybw = (t <= L_SEQ - 2)
                    ? Y[((size_t)L_SEQ + (L_SEQ - 2 - t)) * DINNER + j] : 0.f;
    float xog = b2f(xbc[(size_t)t * CONVDIM + j]);
    float fdv = fd[t * NHEADS + (j >> 6)];
    float z = b2f(zx[(size_t)t * DPROJ + j]);
    float y = yfw + ybw + xog * fdv;
    float g = y * (z / (1.f + expf(-z)));
    yg[i] = g;
    ss += g * g;
  }
#pragma unroll
  for (int off = 32; off > 0; off >>= 1) ss += __shfl_down(ss, off);
  __shared__ float red[4];
  if ((tid & 63) == 0) red[tid >> 6] = ss;
  __syncthreads();
  float tot = red[0] + red[1] + red[2] + red[3];
  float scale = rsqrtf(tot / (float)DINNER + 1e-5f);
#pragma unroll
  for (int i = 0; i < 8; i++) {
    int j = tid + i * 256;
    yn[(size_t)t * DINNER + j] = f2b(yg[i] * scale * norm_w[j]);
  }
}

// ---------------- launch ----------------
extern "C" void kernel_launch(void* const* d_in, const int* in_sizes, int n_in,
                              void* d_out, int out_size, void* d_ws, size_t ws_size,
                              hipStream_t stream) {
  const float* u         = (const float*)d_in[0];
  const float* in_proj_w = (const float*)d_in[1];
  const float* conv_w    = (const float*)d_in[2];
  const float* conv_b    = (const float*)d_in[3];
  const float* dt_bias   = (const float*)d_in[4];
  const float* A_log     = (const float*)d_in[5];
  const float* Dp        = (const float*)d_in[6];
  const float* fc_D_w    = (const float*)d_in[7];
  const float* norm_w    = (const float*)d_in[8];
  const float* out_proj_w= (const float*)d_in[9];
  float* out = (float*)d_out;

  char* base = (char*)d_ws;
  bf16*  zx  = (bf16*)base;  base += (size_t)L_SEQ * DPROJ * 2;                    // 38.3 MB
  bf16*  xbc = (bf16*)base;  base += (size_t)L_SEQ * CONVDIM * 2;                  // 21.0 MB
  float* dt2 = (float*)base; base += (size_t)2 * L_SEQ * NHEADS * 4;               //  1.0 MB
  float* G   = (float*)base; base += (size_t)2 * NCHUNK * CHUNKL * CHUNKL * 4;     //  4.2 MB
  float* Yb  = (float*)base; base += (size_t)2 * L_SEQ * DINNER * 4;               // 67.1 MB
  float* st  = (float*)base; base += (size_t)2 * NCHUNK * NHEADS * HEADDIM * DSTATE * 4; // 67.1 MB
  float* cs  = (float*)base; base += (size_t)2 * NCHUNK * NHEADS * 4;              //  8 KB
  // aliases into dead regions:
  bf16*  u_bf   = (bf16*)Yb;                          // 8.4 MB   (Yb live only after chunk_kernel)
  bf16*  w1p_bf = (bf16*)((char*)Yb + 9437184);       // 9.7 MB   (padded in_proj_w)
  bf16*  w2_bf  = (bf16*)G;                           // 4.0 MB   (G dead after chunk_kernel)
  bf16*  yn     = (bf16*)st;                          // 16.8 MB  (st dead after yoff_kernel)
  float* fd     = (float*)((char*)st + 33554432);     //  0.5 MB

  // 0. casts for MFMA gemm1
  cast_kernel<<<(L_SEQ * DMODEL + 255) / 256, 256, 0, stream>>>(
      u, u_bf, L_SEQ * DMODEL, L_SEQ * DMODEL);
  cast_kernel<<<(NPAD1 * DMODEL + 255) / 256, 256, 0, stream>>>(
      in_proj_w, w1p_bf, DPROJ * DMODEL, NPAD1 * DMODEL);
  // 1. in_proj: zx = u @ in_proj_w^T  (MFMA)
  gemm_mfma<bf16><<<dim3(NPAD1 / 128, L_SEQ / 128), 256, 0, stream>>>(
      u_bf, DMODEL, w1p_bf, DMODEL, zx, DPROJ, DPROJ, DMODEL);
  // 2. conv + silu
  conv_silu_kernel<<<(L_SEQ * CONVDIM + 255) / 256, 256, 0, stream>>>(
      zx, conv_w, conv_b, xbc);
  // 2b. dt
  dt_kernel<<<(2 * L_SEQ * NHEADS + 255) / 256, 256, 0, stream>>>(
      zx, dt_bias, dt2);
  // 3a. G = C B^T per (b,c)
  gmat_kernel<<<2 * NCHUNK, 256, 0, stream>>>(xbc, G);
  // 3b. intra-chunk (MFMA)
  chunk_kernel<<<2 * NCHUNK * NHEADS, 256, 0, stream>>>(
      xbc, dt2, A_log, G, Yb, st, cs);
  // 3c. inter-chunk scan
  scan_kernel<<<(2 * NHEADS * HEADDIM * DSTATE) / 256, 256, 0, stream>>>(st, cs);
  // 3d. Y_off + D*x (MFMA)
  yoff_kernel<<<2 * NCHUNK * NHEADS, 256, 0, stream>>>(
      xbc, dt2, A_log, st, Dp, Yb);
  // 4a. cast out_proj_w (into dead G region)
  cast_kernel<<<(DMODEL * DINNER + 255) / 256, 256, 0, stream>>>(
      out_proj_w, w2_bf, DMODEL * DINNER, DMODEL * DINNER);
  // 4b. fd = x_og @ fc_D_w^T + D
  gemm_abt<bf16, float, float><<<dim3(1, L_SEQ / 64), 256, 0, stream>>>(
      xbc, CONVDIM, fc_D_w, DINNER, fd, NHEADS, L_SEQ, NHEADS, DINNER, Dp);
  // 5. combine + gate + RMSNorm
  combine_kernel<<<L_SEQ, 256, 0, stream>>>(Yb, xbc, zx, fd, norm_w, yn);
  // 6. out_proj (MFMA)
  gemm_mfma<float><<<dim3(DMODEL / 128, L_SEQ / 128), 256, 0, stream>>>(
      yn, DINNER, w2_bf, DINNER, out, DMODEL, DMODEL, DINNER);
}

// Round 7
// 693.543 us; speedup vs baseline: 3.5767x; 1.1015x over previous
//
#include <hip/hip_runtime.h>
#include <hip/hip_bf16.h>
#include <math.h>

// ---------------- problem constants ----------------
#define L_SEQ   4096
#define DMODEL  1024
#define DINNER  2048
#define NHEADS  32
#define HEADDIM 64
#define DSTATE  128
#define NCHUNK  32
#define CHUNKL  128
#define CONVDIM 2560
#define DPROJ   4672   // 2*DINNER + 2*(2*DSTATE) + 2*NHEADS
#define NPAD1   4736   // DPROJ padded to multiple of 128 for MFMA gemm

typedef __hip_bfloat16 bf16;
__device__ __forceinline__ float b2f(bf16 x) { return __bfloat162float(x); }
__device__ __forceinline__ bf16 f2b(float x) { return __float2bfloat16(x); }
__device__ __forceinline__ float sh2f(short s) {
  return __uint_as_float(((unsigned int)(unsigned short)s) << 16);
}

typedef __attribute__((ext_vector_type(8))) short bf16x8v;
typedef __attribute__((ext_vector_type(4))) float f32x4v;

// zxbcdt column layout: [0,2048) = z ; [2048,4608) = xBC ; [4608,4672) = dt raw
// xBC_conv channel layout: [0,2048) = x ; fw B = [2048,2176) C = [2176,2304)
//                          bw B = [2304,2432) C = [2432,2560)  (bw streams time-flipped)

// ---------------- f32 -> bf16 cast (dst beyond n_src zero-filled) ----------------
__global__ __launch_bounds__(256) void cast_kernel(
    const float* __restrict__ src, bf16* __restrict__ dst, int n_src, int n_tot) {
  int i = blockIdx.x * 256 + threadIdx.x;
  if (i < n_tot) dst[i] = (i < n_src) ? f2b(src[i]) : f2b(0.f);
}

// ---------------- MFMA GEMM: C[m,n] = sum_k A[m,k]*B[n,k], bf16 in, f32 acc ----------------
template <typename TC>
__global__ __launch_bounds__(256) void gemm_mfma(
    const bf16* __restrict__ A, int lda,
    const bf16* __restrict__ B, int ldb,
    TC* __restrict__ C, int ldc,
    int N, int K) {
  __shared__ short As[128][32];
  __shared__ short Bs[128][32];
  int tid = threadIdx.x;
  int lane = tid & 63;
  int w = tid >> 6;            // wave 0..3
  int wr = w >> 1, wc = w & 1; // 2x2 wave grid
  int bm = blockIdx.y * 128;
  int bn = blockIdx.x * 128;
  f32x4v acc[4][4];
#pragma unroll
  for (int i = 0; i < 4; i++)
#pragma unroll
    for (int j = 0; j < 4; j++) acc[i][j] = (f32x4v){0.f, 0.f, 0.f, 0.f};

  const bf16* Ab = A + (size_t)(bm + w * 32 + (lane >> 2)) * lda + (lane & 3) * 8;
  const bf16* Bb = B + (size_t)(bn + w * 32 + (lane >> 2)) * ldb + (lane & 3) * 8;

  for (int k0 = 0; k0 < K; k0 += 32) {
    __builtin_amdgcn_global_load_lds(
        (const __attribute__((address_space(1))) void*)(Ab + k0),
        (__attribute__((address_space(3))) void*)&As[w * 32][0], 16, 0, 0);
    __builtin_amdgcn_global_load_lds(
        (const __attribute__((address_space(1))) void*)(Ab + (size_t)16 * lda + k0),
        (__attribute__((address_space(3))) void*)&As[w * 32 + 16][0], 16, 0, 0);
    __builtin_amdgcn_global_load_lds(
        (const __attribute__((address_space(1))) void*)(Bb + k0),
        (__attribute__((address_space(3))) void*)&Bs[w * 32][0], 16, 0, 0);
    __builtin_amdgcn_global_load_lds(
        (const __attribute__((address_space(1))) void*)(Bb + (size_t)16 * ldb + k0),
        (__attribute__((address_space(3))) void*)&Bs[w * 32 + 16][0], 16, 0, 0);
    __syncthreads();
    bf16x8v af[4], bv[4];
#pragma unroll
    for (int i = 0; i < 4; i++)
      af[i] = *(const bf16x8v*)&As[wr * 64 + i * 16 + (lane & 15)][(lane >> 4) * 8];
#pragma unroll
    for (int j = 0; j < 4; j++)
      bv[j] = *(const bf16x8v*)&Bs[wc * 64 + j * 16 + (lane & 15)][(lane >> 4) * 8];
#pragma unroll
    for (int i = 0; i < 4; i++)
#pragma unroll
      for (int j = 0; j < 4; j++)
        acc[i][j] = __builtin_amdgcn_mfma_f32_16x16x32_bf16(af[i], bv[j], acc[i][j], 0, 0, 0);
    __syncthreads();
  }
  int quad = lane >> 4;
  int cn = lane & 15;
#pragma unroll
  for (int i = 0; i < 4; i++) {
#pragma unroll
    for (int j = 0; j < 4; j++) {
      int col = bn + wc * 64 + j * 16 + cn;
      if (col < N) {
#pragma unroll
        for (int r = 0; r < 4; r++) {
          int row = bm + wr * 64 + i * 16 + quad * 4 + r;
          float v = acc[i][j][r];
          if constexpr (sizeof(TC) == 2) C[(size_t)row * ldc + col] = f2b(v);
          else                           C[(size_t)row * ldc + col] = v;
        }
      }
    }
  }
}

// ---------------- fc_D: fd[t][h] = sum_k x[t,k]*W[h,k] + D[h] ----------------
// One thread per (t,h): 512 blocks x 256 threads. Lanes with same t read the
// same x bytes (HW broadcast); W (256 KB) lives in L2 across all blocks.
__global__ __launch_bounds__(256) void fc_kernel(
    const bf16* __restrict__ xbc, const float* __restrict__ Wf,
    const float* __restrict__ Dp, float* __restrict__ fd) {
  int tid = threadIdx.x;
  int h = tid & 31;
  int t = blockIdx.x * 8 + (tid >> 5);
  const bf16* xr = xbc + (size_t)t * CONVDIM;
  const float* wr = Wf + (size_t)h * DINNER;
  float acc = 0.f;
#pragma unroll 2
  for (int k = 0; k < DINNER; k += 8) {
    bf16x8v xv = *(const bf16x8v*)(xr + k);
    float4 w0 = *(const float4*)(wr + k);
    float4 w1 = *(const float4*)(wr + k + 4);
    acc += sh2f(xv[0]) * w0.x + sh2f(xv[1]) * w0.y +
           sh2f(xv[2]) * w0.z + sh2f(xv[3]) * w0.w +
           sh2f(xv[4]) * w1.x + sh2f(xv[5]) * w1.y +
           sh2f(xv[6]) * w1.z + sh2f(xv[7]) * w1.w;
  }
  fd[t * NHEADS + h] = acc + Dp[h];
}

// ---------------- conv (depthwise causal, k=4) + SiLU ----------------
__global__ __launch_bounds__(256) void conv_silu_kernel(
    const bf16* __restrict__ zx, const float* __restrict__ conv_w,
    const float* __restrict__ conv_b, bf16* __restrict__ xbc) {
  int idx = blockIdx.x * 256 + threadIdx.x;   // L_SEQ*CONVDIM
  if (idx >= L_SEQ * CONVDIM) return;
  int ch = idx % CONVDIM;
  int t = idx / CONVDIM;
  const bf16* col = zx + DINNER + ch;         // xBC region
  float w0 = conv_w[ch * 4 + 0], w1 = conv_w[ch * 4 + 1];
  float w2 = conv_w[ch * 4 + 2], w3 = conv_w[ch * 4 + 3];
  float acc = conv_b[ch];
  if (t >= 3) acc += w0 * b2f(col[(size_t)(t - 3) * DPROJ]);
  if (t >= 2) acc += w1 * b2f(col[(size_t)(t - 2) * DPROJ]);
  if (t >= 1) acc += w2 * b2f(col[(size_t)(t - 1) * DPROJ]);
  acc += w3 * b2f(col[(size_t)t * DPROJ]);
  xbc[idx] = f2b(acc / (1.f + expf(-acc)));
}

// ---------------- dt: split fw/bw (bw time-flipped), softplus(dt + bias) ----------------
__global__ __launch_bounds__(256) void dt_kernel(
    const bf16* __restrict__ zx, const float* __restrict__ dt_bias,
    float* __restrict__ dt2) {
  int idx = blockIdx.x * 256 + threadIdx.x;   // 2*L_SEQ*NHEADS
  if (idx >= 2 * L_SEQ * NHEADS) return;
  int h = idx % NHEADS;
  int t = (idx / NHEADS) % L_SEQ;
  int b = idx / (NHEADS * L_SEQ);
  float v;
  if (b == 0) v = b2f(zx[(size_t)t * DPROJ + 4608 + h]);
  else        v = b2f(zx[(size_t)(L_SEQ - 1 - t) * DPROJ + 4608 + NHEADS + h]);
  v += dt_bias[h];
  dt2[idx] = (v > 20.f) ? v : log1pf(expf(v));
}

// ---------------- G[b,c,l,s] = sum_n C[l,n]*B[s,n]  (lower triangle only) ----------------
__global__ __launch_bounds__(256) void gmat_kernel(
    const bf16* __restrict__ xbc, float* __restrict__ G) {
  __shared__ float Bs[CHUNKL][DSTATE + 1];
  __shared__ float Cs[CHUNKL][DSTATE + 1];
  int bc = blockIdx.x;            // b*32 + c
  int b = bc / NCHUNK, c = bc % NCHUNK;
  int tid = threadIdx.x;
  int bofs = b ? 2304 : 2048;
  int cofs = b ? 2432 : 2176;
  for (int o = tid; o < CHUNKL * DSTATE; o += 256) {
    int n = o % DSTATE, s = o / DSTATE;
    int t = b ? (L_SEQ - 1 - (c * CHUNKL + s)) : (c * CHUNKL + s);
    const bf16* row = xbc + (size_t)t * CONVDIM;
    Bs[s][n] = b2f(row[bofs + n]);
    Cs[s][n] = b2f(row[cofs + n]);
  }
  __syncthreads();
  float* Gb = G + (size_t)bc * CHUNKL * CHUNKL;
  for (int o = tid; o < CHUNKL * CHUNKL; o += 256) {
    int s = o % CHUNKL, l = o / CHUNKL;
    float acc = 0.f;
    if (s <= l) {
#pragma unroll 8
      for (int n = 0; n < DSTATE; n++) acc += Cs[l][n] * Bs[s][n];
    }
    Gb[o] = acc;
  }
}

// ---------------- per-(b,c,h): Y_diag and chunk states (MFMA) ----------------
__global__ __launch_bounds__(256) void chunk_kernel(
    const bf16* __restrict__ xbc, const float* __restrict__ dt2,
    const float* __restrict__ A_log, const float* __restrict__ G,
    float* __restrict__ Y, float* __restrict__ states,
    float* __restrict__ csum) {
  int gid = blockIdx.x;           // (b*32+c)*32 + h
  int h = gid % NHEADS;
  int bc = gid / NHEADS;
  int c = bc % NCHUNK, b = bc / NCHUNK;
  int tid = threadIdx.x;
  int lane = tid & 63;
  int w = tid >> 6;               // wave 0..3
  __shared__ bf16 WB[128][136];   // 34.0 KB
  __shared__ bf16 xdtT[64][136];  // 17.0 KB
  __shared__ float acs[CHUNKL];
  __shared__ float dtl[CHUNKL];
  __shared__ float decays[CHUNKL];
  if (tid < CHUNKL)
    dtl[tid] = dt2[((size_t)b * L_SEQ + c * CHUNKL + tid) * NHEADS + h];
  __syncthreads();
  if (tid == 0) {
    float Ah = -expf(A_log[h]);
    float s = 0.f;
    for (int l = 0; l < CHUNKL; l++) { s += Ah * dtl[l]; acs[l] = s; }
    csum[gid] = s;
  }
  __syncthreads();
  for (int o = tid; o < CHUNKL * HEADDIM; o += 256) {
    int p = o & 63, s = o >> 6;
    int t = b ? (L_SEQ - 1 - (c * CHUNKL + s)) : (c * CHUNKL + s);
    xdtT[p][s] = f2b(b2f(xbc[(size_t)t * CONVDIM + h * HEADDIM + p]) * dtl[s]);
  }
  {
    const float* Gb = G + (size_t)bc * CHUNKL * CHUNKL;
    for (int o = tid; o < CHUNKL * CHUNKL; o += 256) {
      int s = o & 127, l = o >> 7;
      float wv = (s <= l) ? Gb[o] * expf(acs[l] - acs[s]) : 0.f;
      WB[l][s] = f2b(wv);
    }
  }
  if (tid < CHUNKL) decays[tid] = expf(acs[CHUNKL - 1] - acs[tid]);
  __syncthreads();
  // Y_diag[l][p] = sum_s W[l][s]*xdt[s][p]; wave w -> l rows [32w, 32w+32)
  {
    f32x4v accY[2][4];
#pragma unroll
    for (int i = 0; i < 2; i++)
#pragma unroll
      for (int j = 0; j < 4; j++) accY[i][j] = (f32x4v){0.f, 0.f, 0.f, 0.f};
#pragma unroll
    for (int k0 = 0; k0 < 128; k0 += 32) {
      bf16x8v a0 = *(const bf16x8v*)&WB[w * 32 + (lane & 15)][(lane >> 4) * 8 + k0];
      bf16x8v a1 = *(const bf16x8v*)&WB[w * 32 + 16 + (lane & 15)][(lane >> 4) * 8 + k0];
      bf16x8v xv[4];
#pragma unroll
      for (int j = 0; j < 4; j++)
        xv[j] = *(const bf16x8v*)&xdtT[j * 16 + (lane & 15)][(lane >> 4) * 8 + k0];
#pragma unroll
      for (int j = 0; j < 4; j++) {
        accY[0][j] = __builtin_amdgcn_mfma_f32_16x16x32_bf16(a0, xv[j], accY[0][j], 0, 0, 0);
        accY[1][j] = __builtin_amdgcn_mfma_f32_16x16x32_bf16(a1, xv[j], accY[1][j], 0, 0, 0);
      }
    }
    int quad = lane >> 4, cn = lane & 15;
#pragma unroll
    for (int i = 0; i < 2; i++)
#pragma unroll
      for (int j = 0; j < 4; j++)
#pragma unroll
        for (int r = 0; r < 4; r++) {
          int l = w * 32 + i * 16 + quad * 4 + r;
          int p = j * 16 + cn;
          Y[((size_t)b * L_SEQ + c * CHUNKL + l) * DINNER + h * HEADDIM + p] = accY[i][j][r];
        }
  }
  __syncthreads();  // all Y_diag reads of WB done
  // rebuild WB as BdT[n][l] = B[l][n] * decays[l]
  {
    int bofs = b ? 2304 : 2048;
    for (int o = tid; o < CHUNKL * CHUNKL; o += 256) {
      int n = o & 127, l = o >> 7;
      int t = b ? (L_SEQ - 1 - (c * CHUNKL + l)) : (c * CHUNKL + l);
      WB[n][l] = f2b(b2f(xbc[(size_t)t * CONVDIM + bofs + n]) * decays[l]);
    }
  }
  __syncthreads();
  // states[p][n] = sum_l xdtT[p][l]*BdT[n][l]; wave w -> p-tile w
  {
    f32x4v accS[8];
#pragma unroll
    for (int j = 0; j < 8; j++) accS[j] = (f32x4v){0.f, 0.f, 0.f, 0.f};
#pragma unroll
    for (int k0 = 0; k0 < 128; k0 += 32) {
      bf16x8v av = *(const bf16x8v*)&xdtT[w * 16 + (lane & 15)][(lane >> 4) * 8 + k0];
#pragma unroll
      for (int j = 0; j < 8; j++) {
        bf16x8v bv = *(const bf16x8v*)&WB[j * 16 + (lane & 15)][(lane >> 4) * 8 + k0];
        accS[j] = __builtin_amdgcn_mfma_f32_16x16x32_bf16(av, bv, accS[j], 0, 0, 0);
      }
    }
    int quad = lane >> 4, cn = lane & 15;
    float* st = states + (size_t)gid * (HEADDIM * DSTATE);
#pragma unroll
    for (int j = 0; j < 8; j++)
#pragma unroll
      for (int r = 0; r < 4; r++) {
        int p = w * 16 + quad * 4 + r;
        int n = j * 16 + cn;
        st[p * DSTATE + n] = accS[j][r];
      }
  }
}

// ---------------- inter-chunk scan (in place: states -> state_in) ----------------
__global__ __launch_bounds__(256) void scan_kernel(
    float* __restrict__ states, const float* __restrict__ csum) {
  int idx = blockIdx.x * 256 + threadIdx.x;  // 2*NHEADS*HEADDIM*DSTATE
  int n = idx % DSTATE;
  int p = (idx / DSTATE) % HEADDIM;
  int h = (idx / (DSTATE * HEADDIM)) % NHEADS;
  int b = idx / (DSTATE * HEADDIM * NHEADS);
  float S = 0.f;
  for (int c = 0; c < NCHUNK; c++) {
    int gid = (b * NCHUNK + c) * NHEADS + h;
    size_t off = (size_t)gid * (HEADDIM * DSTATE) + p * DSTATE + n;
    float tmp = states[off];
    states[off] = S;
    S = expf(csum[gid]) * S + tmp;
  }
}

// ---------------- Y_off + D*x accumulate into Y (MFMA) ----------------
__global__ __launch_bounds__(256) void yoff_kernel(
    const bf16* __restrict__ xbc, const float* __restrict__ dt2,
    const float* __restrict__ A_log, const float* __restrict__ states,
    const float* __restrict__ Dp, float* __restrict__ Y) {
  int gid = blockIdx.x;
  int h = gid % NHEADS;
  int bc = gid / NHEADS;
  int c = bc % NCHUNK, b = bc / NCHUNK;
  int tid = threadIdx.x;
  int lane = tid & 63;
  int w = tid >> 6;               // wave 0..3
  __shared__ bf16 Ce[128][136];   // 34.0 KB
  __shared__ bf16 St[64][136];    // 17.0 KB
  __shared__ float acs[CHUNKL];
  __shared__ float dtl[CHUNKL];
  __shared__ float eAl[CHUNKL];
  if (tid < CHUNKL)
    dtl[tid] = dt2[((size_t)b * L_SEQ + c * CHUNKL + tid) * NHEADS + h];
  __syncthreads();
  if (tid == 0) {
    float Ah = -expf(A_log[h]);
    float s = 0.f;
    for (int l = 0; l < CHUNKL; l++) { s += Ah * dtl[l]; acs[l] = s; }
  }
  __syncthreads();
  if (tid < CHUNKL) eAl[tid] = expf(acs[tid]);   // <= 1, no overflow
  __syncthreads();
  int cofs = b ? 2432 : 2176;
  for (int o = tid; o < CHUNKL * DSTATE; o += 256) {
    int n = o & 127, l = o >> 7;
    int t = b ? (L_SEQ - 1 - (c * CHUNKL + l)) : (c * CHUNKL + l);
    Ce[l][n] = f2b(b2f(xbc[(size_t)t * CONVDIM + cofs + n]) * eAl[l]);
  }
  const float* stp = states + (size_t)gid * (HEADDIM * DSTATE);
  for (int o = tid; o < HEADDIM * DSTATE; o += 256) {
    int n = o & 127, p = o >> 7;
    St[p][n] = f2b(stp[o]);
  }
  __syncthreads();
  f32x4v accY[2][4];
#pragma unroll
  for (int i = 0; i < 2; i++)
#pragma unroll
    for (int j = 0; j < 4; j++) accY[i][j] = (f32x4v){0.f, 0.f, 0.f, 0.f};
#pragma unroll
  for (int k0 = 0; k0 < 128; k0 += 32) {
    bf16x8v a0 = *(const bf16x8v*)&Ce[w * 32 + (lane & 15)][(lane >> 4) * 8 + k0];
    bf16x8v a1 = *(const bf16x8v*)&Ce[w * 32 + 16 + (lane & 15)][(lane >> 4) * 8 + k0];
    bf16x8v bv[4];
#pragma unroll
    for (int j = 0; j < 4; j++)
      bv[j] = *(const bf16x8v*)&St[j * 16 + (lane & 15)][(lane >> 4) * 8 + k0];
#pragma unroll
    for (int j = 0; j < 4; j++) {
      accY[0][j] = __builtin_amdgcn_mfma_f32_16x16x32_bf16(a0, bv[j], accY[0][j], 0, 0, 0);
      accY[1][j] = __builtin_amdgcn_mfma_f32_16x16x32_bf16(a1, bv[j], accY[1][j], 0, 0, 0);
    }
  }
  int quad = lane >> 4, cn = lane & 15;
  float Dh = Dp[h];
#pragma unroll
  for (int i = 0; i < 2; i++)
#pragma unroll
    for (int j = 0; j < 4; j++)
#pragma unroll
      for (int r = 0; r < 4; r++) {
        int l = w * 32 + i * 16 + quad * 4 + r;
        int p = j * 16 + cn;
        int t = b ? (L_SEQ - 1 - (c * CHUNKL + l)) : (c * CHUNKL + l);
        float xv = b2f(xbc[(size_t)t * CONVDIM + h * HEADDIM + p]);
        size_t yi = ((size_t)b * L_SEQ + c * CHUNKL + l) * DINNER + h * HEADDIM + p;
        Y[yi] = Y[yi] + accY[i][j][r] + xv * Dh;
      }
}

// ---------------- combine: shift, flip, +x*fd, gate, RMSNorm ----------------
__global__ __launch_bounds__(256) void combine_kernel(
    const float* __restrict__ Y, const bf16* __restrict__ xbc,
    const bf16* __restrict__ zx, const float* __restrict__ fd,
    const float* __restrict__ norm_w, bf16* __restrict__ yn) {
  int t = blockIdx.x;
  int tid = threadIdx.x;
  float yg[8];
  float ss = 0.f;
#pragma unroll
  for (int i = 0; i < 8; i++) {
    int j = tid + i * 256;
    float yfw = (t >= 1) ? Y[(size_t)(t - 1) * DINNER + j] : 0.f;
    float ybw = (t <= L_SEQ - 2)
                    ? Y[((size_t)L_SEQ + (L_SEQ - 2 - t)) * DINNER + j] : 0.f;
    float xog = b2f(xbc[(size_t)t * CONVDIM + j]);
    float fdv = fd[t * NHEADS + (j >> 6)];
    float z = b2f(zx[(size_t)t * DPROJ + j]);
    float y = yfw + ybw + xog * fdv;
    float g = y * (z / (1.f + expf(-z)));
    yg[i] = g;
    ss += g * g;
  }
#pragma unroll
  for (int off = 32; off > 0; off >>= 1) ss += __shfl_down(ss, off);
  __shared__ float red[4];
  if ((tid & 63) == 0) red[tid >> 6] = ss;
  __syncthreads();
  float tot = red[0] + red[1] + red[2] + red[3];
  float scale = rsqrtf(tot / (float)DINNER + 1e-5f);
#pragma unroll
  for (int i = 0; i < 8; i++) {
    int j = tid + i * 256;
    yn[(size_t)t * DINNER + j] = f2b(yg[i] * scale * norm_w[j]);
  }
}

// ---------------- launch ----------------
extern "C" void kernel_launch(void* const* d_in, const int* in_sizes, int n_in,
                              void* d_out, int out_size, void* d_ws, size_t ws_size,
                              hipStream_t stream) {
  const float* u         = (const float*)d_in[0];
  const float* in_proj_w = (const float*)d_in[1];
  const float* conv_w    = (const float*)d_in[2];
  const float* conv_b    = (const float*)d_in[3];
  const float* dt_bias   = (const float*)d_in[4];
  const float* A_log     = (const float*)d_in[5];
  const float* Dp        = (const float*)d_in[6];
  const float* fc_D_w    = (const float*)d_in[7];
  const float* norm_w    = (const float*)d_in[8];
  const float* out_proj_w= (const float*)d_in[9];
  float* out = (float*)d_out;

  char* base = (char*)d_ws;
  bf16*  zx  = (bf16*)base;  base += (size_t)L_SEQ * DPROJ * 2;                    // 38.3 MB
  bf16*  xbc = (bf16*)base;  base += (size_t)L_SEQ * CONVDIM * 2;                  // 21.0 MB
  float* dt2 = (float*)base; base += (size_t)2 * L_SEQ * NHEADS * 4;               //  1.0 MB
  float* G   = (float*)base; base += (size_t)2 * NCHUNK * CHUNKL * CHUNKL * 4;     //  4.2 MB
  float* Yb  = (float*)base; base += (size_t)2 * L_SEQ * DINNER * 4;               // 67.1 MB
  float* st  = (float*)base; base += (size_t)2 * NCHUNK * NHEADS * HEADDIM * DSTATE * 4; // 67.1 MB
  float* cs  = (float*)base; base += (size_t)2 * NCHUNK * NHEADS * 4;              //  8 KB
  // aliases into dead regions:
  bf16*  u_bf   = (bf16*)Yb;                          // 8.4 MB   (Yb live only after chunk_kernel)
  bf16*  w1p_bf = (bf16*)((char*)Yb + 9437184);       // 9.7 MB   (padded in_proj_w)
  bf16*  w2_bf  = (bf16*)G;                           // 4.0 MB   (G dead after chunk_kernel)
  bf16*  yn     = (bf16*)st;                          // 16.8 MB  (st dead after yoff_kernel)
  float* fd     = (float*)((char*)st + 33554432);     //  0.5 MB

  // 0. casts for MFMA gemm1
  cast_kernel<<<(L_SEQ * DMODEL + 255) / 256, 256, 0, stream>>>(
      u, u_bf, L_SEQ * DMODEL, L_SEQ * DMODEL);
  cast_kernel<<<(NPAD1 * DMODEL + 255) / 256, 256, 0, stream>>>(
      in_proj_w, w1p_bf, DPROJ * DMODEL, NPAD1 * DMODEL);
  // 1. in_proj: zx = u @ in_proj_w^T  (MFMA)
  gemm_mfma<bf16><<<dim3(NPAD1 / 128, L_SEQ / 128), 256, 0, stream>>>(
      u_bf, DMODEL, w1p_bf, DMODEL, zx, DPROJ, DPROJ, DMODEL);
  // 2. conv + silu
  conv_silu_kernel<<<(L_SEQ * CONVDIM + 255) / 256, 256, 0, stream>>>(
      zx, conv_w, conv_b, xbc);
  // 2b. dt
  dt_kernel<<<(2 * L_SEQ * NHEADS + 255) / 256, 256, 0, stream>>>(
      zx, dt_bias, dt2);
  // 3a. G = C B^T per (b,c)
  gmat_kernel<<<2 * NCHUNK, 256, 0, stream>>>(xbc, G);
  // 3b. intra-chunk (MFMA)
  chunk_kernel<<<2 * NCHUNK * NHEADS, 256, 0, stream>>>(
      xbc, dt2, A_log, G, Yb, st, cs);
  // 3c. inter-chunk scan
  scan_kernel<<<(2 * NHEADS * HEADDIM * DSTATE) / 256, 256, 0, stream>>>(st, cs);
  // 3d. Y_off + D*x (MFMA)
  yoff_kernel<<<2 * NCHUNK * NHEADS, 256, 0, stream>>>(
      xbc, dt2, A_log, st, Dp, Yb);
  // 4a. cast out_proj_w (into dead G region)
  cast_kernel<<<(DMODEL * DINNER + 255) / 256, 256, 0, stream>>>(
      out_proj_w, w2_bf, DMODEL * DINNER, DMODEL * DINNER);
  // 4b. fd = x_og @ fc_D_w^T + D  (dedicated skinny-GEMM kernel)
  fc_kernel<<<L_SEQ / 8, 256, 0, stream>>>(xbc, fc_D_w, Dp, fd);
  // 5. combine + gate + RMSNorm
  combine_kernel<<<L_SEQ, 256, 0, stream>>>(Yb, xbc, zx, fd, norm_w, yn);
  // 6. out_proj (MFMA)
  gemm_mfma<float><<<dim3(DMODEL / 128, L_SEQ / 128), 256, 0, stream>>>(
      yn, DINNER, w2_bf, DINNER, out, DMODEL, DMODEL, DINNER);
}

// Round 8
// 622.741 us; speedup vs baseline: 3.9833x; 1.1137x over previous
//
#include <hip/hip_runtime.h>
#include <hip/hip_bf16.h>
#include <math.h>

// ---------------- problem constants ----------------
#define L_SEQ   4096
#define DMODEL  1024
#define DINNER  2048
#define NHEADS  32
#define HEADDIM 64
#define DSTATE  128
#define NCHUNK  32
#define CHUNKL  128
#define CONVDIM 2560
#define DPROJ   4672   // 2*DINNER + 2*(2*DSTATE) + 2*NHEADS
#define NPAD1   4736   // DPROJ padded to multiple of 128 for MFMA gemm

typedef __hip_bfloat16 bf16;
__device__ __forceinline__ float b2f(bf16 x) { return __bfloat162float(x); }
__device__ __forceinline__ bf16 f2b(float x) { return __float2bfloat16(x); }
__device__ __forceinline__ float sh2f(short s) {
  return __uint_as_float(((unsigned int)(unsigned short)s) << 16);
}

typedef __attribute__((ext_vector_type(8))) short bf16x8v;
typedef __attribute__((ext_vector_type(4))) float f32x4v;

__device__ __forceinline__ float dot8(bf16x8v x, float4 w0, float4 w1) {
  return sh2f(x[0]) * w0.x + sh2f(x[1]) * w0.y + sh2f(x[2]) * w0.z + sh2f(x[3]) * w0.w +
         sh2f(x[4]) * w1.x + sh2f(x[5]) * w1.y + sh2f(x[6]) * w1.z + sh2f(x[7]) * w1.w;
}

// zxbcdt column layout: [0,2048) = z ; [2048,4608) = xBC ; [4608,4672) = dt raw
// xBC_conv channel layout: [0,2048) = x ; fw B = [2048,2176) C = [2176,2304)
//                          bw B = [2304,2432) C = [2432,2560)  (bw streams time-flipped)

// ---------------- f32 -> bf16 cast (dst beyond n_src zero-filled) ----------------
__global__ __launch_bounds__(256) void cast_kernel(
    const float* __restrict__ src, bf16* __restrict__ dst, int n_src, int n_tot) {
  int i = blockIdx.x * 256 + threadIdx.x;
  if (i < n_tot) dst[i] = (i < n_src) ? f2b(src[i]) : f2b(0.f);
}

// ---------------- MFMA GEMM: C[m,n] = sum_k A[m,k]*B[n,k], bf16 in, f32 acc ----------------
template <typename TC>
__global__ __launch_bounds__(256) void gemm_mfma(
    const bf16* __restrict__ A, int lda,
    const bf16* __restrict__ B, int ldb,
    TC* __restrict__ C, int ldc,
    int N, int K) {
  __shared__ short As[128][32];
  __shared__ short Bs[128][32];
  int tid = threadIdx.x;
  int lane = tid & 63;
  int w = tid >> 6;            // wave 0..3
  int wr = w >> 1, wc = w & 1; // 2x2 wave grid
  int bm = blockIdx.y * 128;
  int bn = blockIdx.x * 128;
  f32x4v acc[4][4];
#pragma unroll
  for (int i = 0; i < 4; i++)
#pragma unroll
    for (int j = 0; j < 4; j++) acc[i][j] = (f32x4v){0.f, 0.f, 0.f, 0.f};

  const bf16* Ab = A + (size_t)(bm + w * 32 + (lane >> 2)) * lda + (lane & 3) * 8;
  const bf16* Bb = B + (size_t)(bn + w * 32 + (lane >> 2)) * ldb + (lane & 3) * 8;

  for (int k0 = 0; k0 < K; k0 += 32) {
    __builtin_amdgcn_global_load_lds(
        (const __attribute__((address_space(1))) void*)(Ab + k0),
        (__attribute__((address_space(3))) void*)&As[w * 32][0], 16, 0, 0);
    __builtin_amdgcn_global_load_lds(
        (const __attribute__((address_space(1))) void*)(Ab + (size_t)16 * lda + k0),
        (__attribute__((address_space(3))) void*)&As[w * 32 + 16][0], 16, 0, 0);
    __builtin_amdgcn_global_load_lds(
        (const __attribute__((address_space(1))) void*)(Bb + k0),
        (__attribute__((address_space(3))) void*)&Bs[w * 32][0], 16, 0, 0);
    __builtin_amdgcn_global_load_lds(
        (const __attribute__((address_space(1))) void*)(Bb + (size_t)16 * ldb + k0),
        (__attribute__((address_space(3))) void*)&Bs[w * 32 + 16][0], 16, 0, 0);
    __syncthreads();
    bf16x8v af[4], bv[4];
#pragma unroll
    for (int i = 0; i < 4; i++)
      af[i] = *(const bf16x8v*)&As[wr * 64 + i * 16 + (lane & 15)][(lane >> 4) * 8];
#pragma unroll
    for (int j = 0; j < 4; j++)
      bv[j] = *(const bf16x8v*)&Bs[wc * 64 + j * 16 + (lane & 15)][(lane >> 4) * 8];
#pragma unroll
    for (int i = 0; i < 4; i++)
#pragma unroll
      for (int j = 0; j < 4; j++)
        acc[i][j] = __builtin_amdgcn_mfma_f32_16x16x32_bf16(af[i], bv[j], acc[i][j], 0, 0, 0);
    __syncthreads();
  }
  int quad = lane >> 4;
  int cn = lane & 15;
#pragma unroll
  for (int i = 0; i < 4; i++) {
#pragma unroll
    for (int j = 0; j < 4; j++) {
      int col = bn + wc * 64 + j * 16 + cn;
      if (col < N) {
#pragma unroll
        for (int r = 0; r < 4; r++) {
          int row = bm + wr * 64 + i * 16 + quad * 4 + r;
          float v = acc[i][j][r];
          if constexpr (sizeof(TC) == 2) C[(size_t)row * ldc + col] = f2b(v);
          else                           C[(size_t)row * ldc + col] = v;
        }
      }
    }
  }
}

// ---------------- fc_D: fd[t][h] = sum_k x[t,k]*W[h,k] + D[h] ----------------
// One wave per 4 t-rows. Lane = h (32) x k-half g (2). 4 independent
// accumulators per lane (ILP=4x8); x loads broadcast across same-g lanes;
// cross-half combine via shfl_down(32). 256 blocks = 1024 waves.
__global__ __launch_bounds__(256) void fc_kernel(
    const bf16* __restrict__ xbc, const float* __restrict__ Wf,
    const float* __restrict__ Dp, float* __restrict__ fd) {
  int lane = threadIdx.x & 63;
  int w = threadIdx.x >> 6;
  int t0 = (blockIdx.x * 4 + w) * 4;
  int h = lane & 31;
  int g = lane >> 5;                 // k-half: [g*1024, g*1024+1024)
  const float* wr = Wf + (size_t)h * DINNER + g * 1024;
  const bf16* xr = xbc + (size_t)t0 * CONVDIM + g * 1024;
  float a0 = 0.f, a1 = 0.f, a2 = 0.f, a3 = 0.f;
  for (int k = 0; k < 1024; k += 8) {
    float4 w0 = *(const float4*)(wr + k);
    float4 w1 = *(const float4*)(wr + k + 4);
    bf16x8v x0 = *(const bf16x8v*)(xr + k);
    bf16x8v x1 = *(const bf16x8v*)(xr + CONVDIM + k);
    bf16x8v x2 = *(const bf16x8v*)(xr + 2 * CONVDIM + k);
    bf16x8v x3 = *(const bf16x8v*)(xr + 3 * CONVDIM + k);
    a0 += dot8(x0, w0, w1);
    a1 += dot8(x1, w0, w1);
    a2 += dot8(x2, w0, w1);
    a3 += dot8(x3, w0, w1);
  }
  a0 += __shfl_down(a0, 32);
  a1 += __shfl_down(a1, 32);
  a2 += __shfl_down(a2, 32);
  a3 += __shfl_down(a3, 32);
  if (lane < 32) {
    float d = Dp[h];
    fd[(t0 + 0) * NHEADS + h] = a0 + d;
    fd[(t0 + 1) * NHEADS + h] = a1 + d;
    fd[(t0 + 2) * NHEADS + h] = a2 + d;
    fd[(t0 + 3) * NHEADS + h] = a3 + d;
  }
}

// ---------------- conv (depthwise causal, k=4) + SiLU ----------------
__global__ __launch_bounds__(256) void conv_silu_kernel(
    const bf16* __restrict__ zx, const float* __restrict__ conv_w,
    const float* __restrict__ conv_b, bf16* __restrict__ xbc) {
  int idx = blockIdx.x * 256 + threadIdx.x;   // L_SEQ*CONVDIM
  if (idx >= L_SEQ * CONVDIM) return;
  int ch = idx % CONVDIM;
  int t = idx / CONVDIM;
  const bf16* col = zx + DINNER + ch;         // xBC region
  float w0 = conv_w[ch * 4 + 0], w1 = conv_w[ch * 4 + 1];
  float w2 = conv_w[ch * 4 + 2], w3 = conv_w[ch * 4 + 3];
  float acc = conv_b[ch];
  if (t >= 3) acc += w0 * b2f(col[(size_t)(t - 3) * DPROJ]);
  if (t >= 2) acc += w1 * b2f(col[(size_t)(t - 2) * DPROJ]);
  if (t >= 1) acc += w2 * b2f(col[(size_t)(t - 1) * DPROJ]);
  acc += w3 * b2f(col[(size_t)t * DPROJ]);
  xbc[idx] = f2b(acc / (1.f + expf(-acc)));
}

// ---------------- dt: split fw/bw (bw time-flipped), softplus(dt + bias) ----------------
__global__ __launch_bounds__(256) void dt_kernel(
    const bf16* __restrict__ zx, const float* __restrict__ dt_bias,
    float* __restrict__ dt2) {
  int idx = blockIdx.x * 256 + threadIdx.x;   // 2*L_SEQ*NHEADS
  if (idx >= 2 * L_SEQ * NHEADS) return;
  int h = idx % NHEADS;
  int t = (idx / NHEADS) % L_SEQ;
  int b = idx / (NHEADS * L_SEQ);
  float v;
  if (b == 0) v = b2f(zx[(size_t)t * DPROJ + 4608 + h]);
  else        v = b2f(zx[(size_t)(L_SEQ - 1 - t) * DPROJ + 4608 + NHEADS + h]);
  v += dt_bias[h];
  dt2[idx] = (v > 20.f) ? v : log1pf(expf(v));
}

// ---------------- G[b,c,l,s] = sum_n C[l,n]*B[s,n]  (lower triangle only) ----------------
__global__ __launch_bounds__(256) void gmat_kernel(
    const bf16* __restrict__ xbc, float* __restrict__ G) {
  __shared__ float Bs[CHUNKL][DSTATE + 1];
  __shared__ float Cs[CHUNKL][DSTATE + 1];
  int bc = blockIdx.x;            // b*32 + c
  int b = bc / NCHUNK, c = bc % NCHUNK;
  int tid = threadIdx.x;
  int bofs = b ? 2304 : 2048;
  int cofs = b ? 2432 : 2176;
  for (int o = tid; o < CHUNKL * DSTATE; o += 256) {
    int n = o % DSTATE, s = o / DSTATE;
    int t = b ? (L_SEQ - 1 - (c * CHUNKL + s)) : (c * CHUNKL + s);
    const bf16* row = xbc + (size_t)t * CONVDIM;
    Bs[s][n] = b2f(row[bofs + n]);
    Cs[s][n] = b2f(row[cofs + n]);
  }
  __syncthreads();
  float* Gb = G + (size_t)bc * CHUNKL * CHUNKL;
  for (int o = tid; o < CHUNKL * CHUNKL; o += 256) {
    int s = o % CHUNKL, l = o / CHUNKL;
    float acc = 0.f;
    if (s <= l) {
#pragma unroll 8
      for (int n = 0; n < DSTATE; n++) acc += Cs[l][n] * Bs[s][n];
    }
    Gb[o] = acc;
  }
}

// ---------------- per-(b,c,h): Y_diag and chunk states (MFMA) ----------------
__global__ __launch_bounds__(256) void chunk_kernel(
    const bf16* __restrict__ xbc, const float* __restrict__ dt2,
    const float* __restrict__ A_log, const float* __restrict__ G,
    float* __restrict__ Y, float* __restrict__ states,
    float* __restrict__ csum) {
  int gid = blockIdx.x;           // (b*32+c)*32 + h
  int h = gid % NHEADS;
  int bc = gid / NHEADS;
  int c = bc % NCHUNK, b = bc / NCHUNK;
  int tid = threadIdx.x;
  int lane = tid & 63;
  int w = tid >> 6;               // wave 0..3
  __shared__ bf16 WB[128][136];   // 34.0 KB
  __shared__ bf16 xdtT[64][136];  // 17.0 KB
  __shared__ float acs[CHUNKL];
  __shared__ float dtl[CHUNKL];
  __shared__ float decays[CHUNKL];
  if (tid < CHUNKL)
    dtl[tid] = dt2[((size_t)b * L_SEQ + c * CHUNKL + tid) * NHEADS + h];
  __syncthreads();
  if (tid == 0) {
    float Ah = -expf(A_log[h]);
    float s = 0.f;
    for (int l = 0; l < CHUNKL; l++) { s += Ah * dtl[l]; acs[l] = s; }
    csum[gid] = s;
  }
  __syncthreads();
  for (int o = tid; o < CHUNKL * HEADDIM; o += 256) {
    int p = o & 63, s = o >> 6;
    int t = b ? (L_SEQ - 1 - (c * CHUNKL + s)) : (c * CHUNKL + s);
    xdtT[p][s] = f2b(b2f(xbc[(size_t)t * CONVDIM + h * HEADDIM + p]) * dtl[s]);
  }
  {
    const float* Gb = G + (size_t)bc * CHUNKL * CHUNKL;
    for (int o = tid; o < CHUNKL * CHUNKL; o += 256) {
      int s = o & 127, l = o >> 7;
      float wv = (s <= l) ? Gb[o] * expf(acs[l] - acs[s]) : 0.f;
      WB[l][s] = f2b(wv);
    }
  }
  if (tid < CHUNKL) decays[tid] = expf(acs[CHUNKL - 1] - acs[tid]);
  __syncthreads();
  // Y_diag[l][p] = sum_s W[l][s]*xdt[s][p]; wave w -> l rows [32w, 32w+32)
  {
    f32x4v accY[2][4];
#pragma unroll
    for (int i = 0; i < 2; i++)
#pragma unroll
      for (int j = 0; j < 4; j++) accY[i][j] = (f32x4v){0.f, 0.f, 0.f, 0.f};
#pragma unroll
    for (int k0 = 0; k0 < 128; k0 += 32) {
      bf16x8v a0 = *(const bf16x8v*)&WB[w * 32 + (lane & 15)][(lane >> 4) * 8 + k0];
      bf16x8v a1 = *(const bf16x8v*)&WB[w * 32 + 16 + (lane & 15)][(lane >> 4) * 8 + k0];
      bf16x8v xv[4];
#pragma unroll
      for (int j = 0; j < 4; j++)
        xv[j] = *(const bf16x8v*)&xdtT[j * 16 + (lane & 15)][(lane >> 4) * 8 + k0];
#pragma unroll
      for (int j = 0; j < 4; j++) {
        accY[0][j] = __builtin_amdgcn_mfma_f32_16x16x32_bf16(a0, xv[j], accY[0][j], 0, 0, 0);
        accY[1][j] = __builtin_amdgcn_mfma_f32_16x16x32_bf16(a1, xv[j], accY[1][j], 0, 0, 0);
      }
    }
    int quad = lane >> 4, cn = lane & 15;
#pragma unroll
    for (int i = 0; i < 2; i++)
#pragma unroll
      for (int j = 0; j < 4; j++)
#pragma unroll
        for (int r = 0; r < 4; r++) {
          int l = w * 32 + i * 16 + quad * 4 + r;
          int p = j * 16 + cn;
          Y[((size_t)b * L_SEQ + c * CHUNKL + l) * DINNER + h * HEADDIM + p] = accY[i][j][r];
        }
  }
  __syncthreads();  // all Y_diag reads of WB done
  // rebuild WB as BdT[n][l] = B[l][n] * decays[l]
  {
    int bofs = b ? 2304 : 2048;
    for (int o = tid; o < CHUNKL * CHUNKL; o += 256) {
      int n = o & 127, l = o >> 7;
      int t = b ? (L_SEQ - 1 - (c * CHUNKL + l)) : (c * CHUNKL + l);
      WB[n][l] = f2b(b2f(xbc[(size_t)t * CONVDIM + bofs + n]) * decays[l]);
    }
  }
  __syncthreads();
  // states[p][n] = sum_l xdtT[p][l]*BdT[n][l]; wave w -> p-tile w
  {
    f32x4v accS[8];
#pragma unroll
    for (int j = 0; j < 8; j++) accS[j] = (f32x4v){0.f, 0.f, 0.f, 0.f};
#pragma unroll
    for (int k0 = 0; k0 < 128; k0 += 32) {
      bf16x8v av = *(const bf16x8v*)&xdtT[w * 16 + (lane & 15)][(lane >> 4) * 8 + k0];
#pragma unroll
      for (int j = 0; j < 8; j++) {
        bf16x8v bv = *(const bf16x8v*)&WB[j * 16 + (lane & 15)][(lane >> 4) * 8 + k0];
        accS[j] = __builtin_amdgcn_mfma_f32_16x16x32_bf16(av, bv, accS[j], 0, 0, 0);
      }
    }
    int quad = lane >> 4, cn = lane & 15;
    float* st = states + (size_t)gid * (HEADDIM * DSTATE);
#pragma unroll
    for (int j = 0; j < 8; j++)
#pragma unroll
      for (int r = 0; r < 4; r++) {
        int p = w * 16 + quad * 4 + r;
        int n = j * 16 + cn;
        st[p * DSTATE + n] = accS[j][r];
      }
  }
}

// ---------------- inter-chunk scan (in place: states -> state_in) ----------------
__global__ __launch_bounds__(256) void scan_kernel(
    float* __restrict__ states, const float* __restrict__ csum) {
  int idx = blockIdx.x * 256 + threadIdx.x;  // 2*NHEADS*HEADDIM*DSTATE
  int n = idx % DSTATE;
  int p = (idx / DSTATE) % HEADDIM;
  int h = (idx / (DSTATE * HEADDIM)) % NHEADS;
  int b = idx / (DSTATE * HEADDIM * NHEADS);
  float S = 0.f;
  for (int c = 0; c < NCHUNK; c++) {
    int gid = (b * NCHUNK + c) * NHEADS + h;
    size_t off = (size_t)gid * (HEADDIM * DSTATE) + p * DSTATE + n;
    float tmp = states[off];
    states[off] = S;
    S = expf(csum[gid]) * S + tmp;
  }
}

// ---------------- Y_off + D*x accumulate into Y (MFMA) ----------------
__global__ __launch_bounds__(256) void yoff_kernel(
    const bf16* __restrict__ xbc, const float* __restrict__ dt2,
    const float* __restrict__ A_log, const float* __restrict__ states,
    const float* __restrict__ Dp, float* __restrict__ Y) {
  int gid = blockIdx.x;
  int h = gid % NHEADS;
  int bc = gid / NHEADS;
  int c = bc % NCHUNK, b = bc / NCHUNK;
  int tid = threadIdx.x;
  int lane = tid & 63;
  int w = tid >> 6;               // wave 0..3
  __shared__ bf16 Ce[128][136];   // 34.0 KB
  __shared__ bf16 St[64][136];    // 17.0 KB
  __shared__ float acs[CHUNKL];
  __shared__ float dtl[CHUNKL];
  __shared__ float eAl[CHUNKL];
  if (tid < CHUNKL)
    dtl[tid] = dt2[((size_t)b * L_SEQ + c * CHUNKL + tid) * NHEADS + h];
  __syncthreads();
  if (tid == 0) {
    float Ah = -expf(A_log[h]);
    float s = 0.f;
    for (int l = 0; l < CHUNKL; l++) { s += Ah * dtl[l]; acs[l] = s; }
  }
  __syncthreads();
  if (tid < CHUNKL) eAl[tid] = expf(acs[tid]);   // <= 1, no overflow
  __syncthreads();
  int cofs = b ? 2432 : 2176;
  for (int o = tid; o < CHUNKL * DSTATE; o += 256) {
    int n = o & 127, l = o >> 7;
    int t = b ? (L_SEQ - 1 - (c * CHUNKL + l)) : (c * CHUNKL + l);
    Ce[l][n] = f2b(b2f(xbc[(size_t)t * CONVDIM + cofs + n]) * eAl[l]);
  }
  const float* stp = states + (size_t)gid * (HEADDIM * DSTATE);
  for (int o = tid; o < HEADDIM * DSTATE; o += 256) {
    int n = o & 127, p = o >> 7;
    St[p][n] = f2b(stp[o]);
  }
  __syncthreads();
  f32x4v accY[2][4];
#pragma unroll
  for (int i = 0; i < 2; i++)
#pragma unroll
    for (int j = 0; j < 4; j++) accY[i][j] = (f32x4v){0.f, 0.f, 0.f, 0.f};
#pragma unroll
  for (int k0 = 0; k0 < 128; k0 += 32) {
    bf16x8v a0 = *(const bf16x8v*)&Ce[w * 32 + (lane & 15)][(lane >> 4) * 8 + k0];
    bf16x8v a1 = *(const bf16x8v*)&Ce[w * 32 + 16 + (lane & 15)][(lane >> 4) * 8 + k0];
    bf16x8v bv[4];
#pragma unroll
    for (int j = 0; j < 4; j++)
      bv[j] = *(const bf16x8v*)&St[j * 16 + (lane & 15)][(lane >> 4) * 8 + k0];
#pragma unroll
    for (int j = 0; j < 4; j++) {
      accY[0][j] = __builtin_amdgcn_mfma_f32_16x16x32_bf16(a0, bv[j], accY[0][j], 0, 0, 0);
      accY[1][j] = __builtin_amdgcn_mfma_f32_16x16x32_bf16(a1, bv[j], accY[1][j], 0, 0, 0);
    }
  }
  int quad = lane >> 4, cn = lane & 15;
  float Dh = Dp[h];
#pragma unroll
  for (int i = 0; i < 2; i++)
#pragma unroll
    for (int j = 0; j < 4; j++)
#pragma unroll
      for (int r = 0; r < 4; r++) {
        int l = w * 32 + i * 16 + quad * 4 + r;
        int p = j * 16 + cn;
        int t = b ? (L_SEQ - 1 - (c * CHUNKL + l)) : (c * CHUNKL + l);
        float xv = b2f(xbc[(size_t)t * CONVDIM + h * HEADDIM + p]);
        size_t yi = ((size_t)b * L_SEQ + c * CHUNKL + l) * DINNER + h * HEADDIM + p;
        Y[yi] = Y[yi] + accY[i][j][r] + xv * Dh;
      }
}

// ---------------- combine: shift, flip, +x*fd, gate, RMSNorm ----------------
__global__ __launch_bounds__(256) void combine_kernel(
    const float* __restrict__ Y, const bf16* __restrict__ xbc,
    const bf16* __restrict__ zx, const float* __restrict__ fd,
    const float* __restrict__ norm_w, bf16* __restrict__ yn) {
  int t = blockIdx.x;
  int tid = threadIdx.x;
  float yg[8];
  float ss = 0.f;
#pragma unroll
  for (int i = 0; i < 8; i++) {
    int j = tid + i * 256;
    float yfw = (t >= 1) ? Y[(size_t)(t - 1) * DINNER + j] : 0.f;
    float ybw = (t <= L_SEQ - 2)
                    ? Y[((size_t)L_SEQ + (L_SEQ - 2 - t)) * DINNER + j] : 0.f;
    float xog = b2f(xbc[(size_t)t * CONVDIM + j]);
    float fdv = fd[t * NHEADS + (j >> 6)];
    float z = b2f(zx[(size_t)t * DPROJ + j]);
    float y = yfw + ybw + xog * fdv;
    float g = y * (z / (1.f + expf(-z)));
    yg[i] = g;
    ss += g * g;
  }
#pragma unroll
  for (int off = 32; off > 0; off >>= 1) ss += __shfl_down(ss, off);
  __shared__ float red[4];
  if ((tid & 63) == 0) red[tid >> 6] = ss;
  __syncthreads();
  float tot = red[0] + red[1] + red[2] + red[3];
  float scale = rsqrtf(tot / (float)DINNER + 1e-5f);
#pragma unroll
  for (int i = 0; i < 8; i++) {
    int j = tid + i * 256;
    yn[(size_t)t * DINNER + j] = f2b(yg[i] * scale * norm_w[j]);
  }
}

// ---------------- launch ----------------
extern "C" void kernel_launch(void* const* d_in, const int* in_sizes, int n_in,
                              void* d_out, int out_size, void* d_ws, size_t ws_size,
                              hipStream_t stream) {
  const float* u         = (const float*)d_in[0];
  const float* in_proj_w = (const float*)d_in[1];
  const float* conv_w    = (const float*)d_in[2];
  const float* conv_b    = (const float*)d_in[3];
  const float* dt_bias   = (const float*)d_in[4];
  const float* A_log     = (const float*)d_in[5];
  const float* Dp        = (const float*)d_in[6];
  const float* fc_D_w    = (const float*)d_in[7];
  const float* norm_w    = (const float*)d_in[8];
  const float* out_proj_w= (const float*)d_in[9];
  float* out = (float*)d_out;

  char* base = (char*)d_ws;
  bf16*  zx  = (bf16*)base;  base += (size_t)L_SEQ * DPROJ * 2;                    // 38.3 MB
  bf16*  xbc = (bf16*)base;  base += (size_t)L_SEQ * CONVDIM * 2;                  // 21.0 MB
  float* dt2 = (float*)base; base += (size_t)2 * L_SEQ * NHEADS * 4;               //  1.0 MB
  float* G   = (float*)base; base += (size_t)2 * NCHUNK * CHUNKL * CHUNKL * 4;     //  4.2 MB
  float* Yb  = (float*)base; base += (size_t)2 * L_SEQ * DINNER * 4;               // 67.1 MB
  float* st  = (float*)base; base += (size_t)2 * NCHUNK * NHEADS * HEADDIM * DSTATE * 4; // 67.1 MB
  float* cs  = (float*)base; base += (size_t)2 * NCHUNK * NHEADS * 4;              //  8 KB
  // aliases into dead regions:
  bf16*  u_bf   = (bf16*)Yb;                          // 8.4 MB   (Yb live only after chunk_kernel)
  bf16*  w1p_bf = (bf16*)((char*)Yb + 9437184);       // 9.7 MB   (padded in_proj_w)
  bf16*  w2_bf  = (bf16*)G;                           // 4.0 MB   (G dead after chunk_kernel)
  bf16*  yn     = (bf16*)st;                          // 16.8 MB  (st dead after yoff_kernel)
  float* fd     = (float*)((char*)st + 33554432);     //  0.5 MB

  // 0. casts for MFMA gemm1
  cast_kernel<<<(L_SEQ * DMODEL + 255) / 256, 256, 0, stream>>>(
      u, u_bf, L_SEQ * DMODEL, L_SEQ * DMODEL);
  cast_kernel<<<(NPAD1 * DMODEL + 255) / 256, 256, 0, stream>>>(
      in_proj_w, w1p_bf, DPROJ * DMODEL, NPAD1 * DMODEL);
  // 1. in_proj: zx = u @ in_proj_w^T  (MFMA)
  gemm_mfma<bf16><<<dim3(NPAD1 / 128, L_SEQ / 128), 256, 0, stream>>>(
      u_bf, DMODEL, w1p_bf, DMODEL, zx, DPROJ, DPROJ, DMODEL);
  // 2. conv + silu
  conv_silu_kernel<<<(L_SEQ * CONVDIM + 255) / 256, 256, 0, stream>>>(
      zx, conv_w, conv_b, xbc);
  // 2b. dt
  dt_kernel<<<(2 * L_SEQ * NHEADS + 255) / 256, 256, 0, stream>>>(
      zx, dt_bias, dt2);
  // 3a. G = C B^T per (b,c)
  gmat_kernel<<<2 * NCHUNK, 256, 0, stream>>>(xbc, G);
  // 3b. intra-chunk (MFMA)
  chunk_kernel<<<2 * NCHUNK * NHEADS, 256, 0, stream>>>(
      xbc, dt2, A_log, G, Yb, st, cs);
  // 3c. inter-chunk scan
  scan_kernel<<<(2 * NHEADS * HEADDIM * DSTATE) / 256, 256, 0, stream>>>(st, cs);
  // 3d. Y_off + D*x (MFMA)
  yoff_kernel<<<2 * NCHUNK * NHEADS, 256, 0, stream>>>(
      xbc, dt2, A_log, st, Dp, Yb);
  // 4a. cast out_proj_w (into dead G region)
  cast_kernel<<<(DMODEL * DINNER + 255) / 256, 256, 0, stream>>>(
      out_proj_w, w2_bf, DMODEL * DINNER, DMODEL * DINNER);
  // 4b. fd = x_og @ fc_D_w^T + D  (wave-per-4t, ILP=4)
  fc_kernel<<<L_SEQ / 16, 256, 0, stream>>>(xbc, fc_D_w, Dp, fd);
  // 5. combine + gate + RMSNorm
  combine_kernel<<<L_SEQ, 256, 0, stream>>>(Yb, xbc, zx, fd, norm_w, yn);
  // 6. out_proj (MFMA)
  gemm_mfma<float><<<dim3(DMODEL / 128, L_SEQ / 128), 256, 0, stream>>>(
      yn, DINNER, w2_bf, DINNER, out, DMODEL, DMODEL, DINNER);
}

// Round 9
// 512.830 us; speedup vs baseline: 4.8370x; 1.2143x over previous
//
#include <hip/hip_runtime.h>
#include <hip/hip_bf16.h>
#include <math.h>

// ---------------- problem constants ----------------
#define L_SEQ   4096
#define DMODEL  1024
#define DINNER  2048
#define NHEADS  32
#define HEADDIM 64
#define DSTATE  128
#define NCHUNK  32
#define CHUNKL  128
#define CONVDIM 2560
#define DPROJ   4672   // 2*DINNER + 2*(2*DSTATE) + 2*NHEADS
#define NPAD1   4736   // DPROJ padded to multiple of 128 for MFMA gemm

typedef __hip_bfloat16 bf16;
__device__ __forceinline__ float b2f(bf16 x) { return __bfloat162float(x); }
__device__ __forceinline__ bf16 f2b(float x) { return __float2bfloat16(x); }
__device__ __forceinline__ float sh2f(short s) {
  return __uint_as_float(((unsigned int)(unsigned short)s) << 16);
}

typedef __attribute__((ext_vector_type(8))) short bf16x8v;
typedef __attribute__((ext_vector_type(4))) float f32x4v;

__device__ __forceinline__ float dot8(bf16x8v x, float4 w0, float4 w1) {
  return sh2f(x[0]) * w0.x + sh2f(x[1]) * w0.y + sh2f(x[2]) * w0.z + sh2f(x[3]) * w0.w +
         sh2f(x[4]) * w1.x + sh2f(x[5]) * w1.y + sh2f(x[6]) * w1.z + sh2f(x[7]) * w1.w;
}

// zxbcdt column layout: [0,2048) = z ; [2048,4608) = xBC ; [4608,4672) = dt raw
// xBC_conv channel layout: [0,2048) = x ; fw B = [2048,2176) C = [2176,2304)
//                          bw B = [2304,2432) C = [2432,2560)  (bw streams time-flipped)

// ---------------- f32 -> bf16 cast (dst beyond n_src zero-filled) ----------------
__global__ __launch_bounds__(256) void cast_kernel(
    const float* __restrict__ src, bf16* __restrict__ dst, int n_src, int n_tot) {
  int i = blockIdx.x * 256 + threadIdx.x;
  if (i < n_tot) dst[i] = (i < n_src) ? f2b(src[i]) : f2b(0.f);
}

// ---------------- MFMA GEMM: C[m,n] = sum_k A[m,k]*B[n,k], bf16 in, f32 acc ----------------
template <typename TC>
__global__ __launch_bounds__(256) void gemm_mfma(
    const bf16* __restrict__ A, int lda,
    const bf16* __restrict__ B, int ldb,
    TC* __restrict__ C, int ldc,
    int N, int K) {
  __shared__ short As[128][32];
  __shared__ short Bs[128][32];
  int tid = threadIdx.x;
  int lane = tid & 63;
  int w = tid >> 6;            // wave 0..3
  int wr = w >> 1, wc = w & 1; // 2x2 wave grid
  int bm = blockIdx.y * 128;
  int bn = blockIdx.x * 128;
  f32x4v acc[4][4];
#pragma unroll
  for (int i = 0; i < 4; i++)
#pragma unroll
    for (int j = 0; j < 4; j++) acc[i][j] = (f32x4v){0.f, 0.f, 0.f, 0.f};

  const bf16* Ab = A + (size_t)(bm + w * 32 + (lane >> 2)) * lda + (lane & 3) * 8;
  const bf16* Bb = B + (size_t)(bn + w * 32 + (lane >> 2)) * ldb + (lane & 3) * 8;

  for (int k0 = 0; k0 < K; k0 += 32) {
    __builtin_amdgcn_global_load_lds(
        (const __attribute__((address_space(1))) void*)(Ab + k0),
        (__attribute__((address_space(3))) void*)&As[w * 32][0], 16, 0, 0);
    __builtin_amdgcn_global_load_lds(
        (const __attribute__((address_space(1))) void*)(Ab + (size_t)16 * lda + k0),
        (__attribute__((address_space(3))) void*)&As[w * 32 + 16][0], 16, 0, 0);
    __builtin_amdgcn_global_load_lds(
        (const __attribute__((address_space(1))) void*)(Bb + k0),
        (__attribute__((address_space(3))) void*)&Bs[w * 32][0], 16, 0, 0);
    __builtin_amdgcn_global_load_lds(
        (const __attribute__((address_space(1))) void*)(Bb + (size_t)16 * ldb + k0),
        (__attribute__((address_space(3))) void*)&Bs[w * 32 + 16][0], 16, 0, 0);
    __syncthreads();
    bf16x8v af[4], bv[4];
#pragma unroll
    for (int i = 0; i < 4; i++)
      af[i] = *(const bf16x8v*)&As[wr * 64 + i * 16 + (lane & 15)][(lane >> 4) * 8];
#pragma unroll
    for (int j = 0; j < 4; j++)
      bv[j] = *(const bf16x8v*)&Bs[wc * 64 + j * 16 + (lane & 15)][(lane >> 4) * 8];
#pragma unroll
    for (int i = 0; i < 4; i++)
#pragma unroll
      for (int j = 0; j < 4; j++)
        acc[i][j] = __builtin_amdgcn_mfma_f32_16x16x32_bf16(af[i], bv[j], acc[i][j], 0, 0, 0);
    __syncthreads();
  }
  int quad = lane >> 4;
  int cn = lane & 15;
#pragma unroll
  for (int i = 0; i < 4; i++) {
#pragma unroll
    for (int j = 0; j < 4; j++) {
      int col = bn + wc * 64 + j * 16 + cn;
      if (col < N) {
#pragma unroll
        for (int r = 0; r < 4; r++) {
          int row = bm + wr * 64 + i * 16 + quad * 4 + r;
          float v = acc[i][j][r];
          if constexpr (sizeof(TC) == 2) C[(size_t)row * ldc + col] = f2b(v);
          else                           C[(size_t)row * ldc + col] = v;
        }
      }
    }
  }
}

// ---------------- fc_D: fd[t][h] = sum_k x[t,k]*W[h,k] + D[h] ----------------
__global__ __launch_bounds__(256) void fc_kernel(
    const bf16* __restrict__ xbc, const float* __restrict__ Wf,
    const float* __restrict__ Dp, float* __restrict__ fd) {
  int lane = threadIdx.x & 63;
  int w = threadIdx.x >> 6;
  int t0 = (blockIdx.x * 4 + w) * 4;
  int h = lane & 31;
  int g = lane >> 5;                 // k-half
  const float* wr = Wf + (size_t)h * DINNER + g * 1024;
  const bf16* xr = xbc + (size_t)t0 * CONVDIM + g * 1024;
  float a0 = 0.f, a1 = 0.f, a2 = 0.f, a3 = 0.f;
  for (int k = 0; k < 1024; k += 8) {
    float4 w0 = *(const float4*)(wr + k);
    float4 w1 = *(const float4*)(wr + k + 4);
    bf16x8v x0 = *(const bf16x8v*)(xr + k);
    bf16x8v x1 = *(const bf16x8v*)(xr + CONVDIM + k);
    bf16x8v x2 = *(const bf16x8v*)(xr + 2 * CONVDIM + k);
    bf16x8v x3 = *(const bf16x8v*)(xr + 3 * CONVDIM + k);
    a0 += dot8(x0, w0, w1);
    a1 += dot8(x1, w0, w1);
    a2 += dot8(x2, w0, w1);
    a3 += dot8(x3, w0, w1);
  }
  a0 += __shfl_down(a0, 32);
  a1 += __shfl_down(a1, 32);
  a2 += __shfl_down(a2, 32);
  a3 += __shfl_down(a3, 32);
  if (lane < 32) {
    float d = Dp[h];
    fd[(t0 + 0) * NHEADS + h] = a0 + d;
    fd[(t0 + 1) * NHEADS + h] = a1 + d;
    fd[(t0 + 2) * NHEADS + h] = a2 + d;
    fd[(t0 + 3) * NHEADS + h] = a3 + d;
  }
}

// ---------------- conv (depthwise causal, k=4) + SiLU ----------------
__global__ __launch_bounds__(256) void conv_silu_kernel(
    const bf16* __restrict__ zx, const float* __restrict__ conv_w,
    const float* __restrict__ conv_b, bf16* __restrict__ xbc) {
  int idx = blockIdx.x * 256 + threadIdx.x;   // L_SEQ*CONVDIM
  if (idx >= L_SEQ * CONVDIM) return;
  int ch = idx % CONVDIM;
  int t = idx / CONVDIM;
  const bf16* col = zx + DINNER + ch;         // xBC region
  float w0 = conv_w[ch * 4 + 0], w1 = conv_w[ch * 4 + 1];
  float w2 = conv_w[ch * 4 + 2], w3 = conv_w[ch * 4 + 3];
  float acc = conv_b[ch];
  if (t >= 3) acc += w0 * b2f(col[(size_t)(t - 3) * DPROJ]);
  if (t >= 2) acc += w1 * b2f(col[(size_t)(t - 2) * DPROJ]);
  if (t >= 1) acc += w2 * b2f(col[(size_t)(t - 1) * DPROJ]);
  acc += w3 * b2f(col[(size_t)t * DPROJ]);
  xbc[idx] = f2b(acc / (1.f + expf(-acc)));
}

// ---------------- dt: split fw/bw (bw time-flipped), softplus(dt + bias) ----------------
__global__ __launch_bounds__(256) void dt_kernel(
    const bf16* __restrict__ zx, const float* __restrict__ dt_bias,
    float* __restrict__ dt2) {
  int idx = blockIdx.x * 256 + threadIdx.x;   // 2*L_SEQ*NHEADS
  if (idx >= 2 * L_SEQ * NHEADS) return;
  int h = idx % NHEADS;
  int t = (idx / NHEADS) % L_SEQ;
  int b = idx / (NHEADS * L_SEQ);
  float v;
  if (b == 0) v = b2f(zx[(size_t)t * DPROJ + 4608 + h]);
  else        v = b2f(zx[(size_t)(L_SEQ - 1 - t) * DPROJ + 4608 + NHEADS + h]);
  v += dt_bias[h];
  dt2[idx] = (v > 20.f) ? v : log1pf(expf(v));
}

// ---------------- G[b,c,l,s] = sum_n C[l,n]*B[s,n]  (MFMA, full matrix, bf16 out) ----------------
__global__ __launch_bounds__(256) void gmat_kernel(
    const bf16* __restrict__ xbc, bf16* __restrict__ G) {
  __shared__ bf16 Cs[128][136];  // C[l][n]  34 KB
  __shared__ bf16 Bs[128][136];  // B[s][n]  34 KB
  int bc = blockIdx.x;            // b*32 + c
  int b = bc / NCHUNK, c = bc % NCHUNK;
  int tid = threadIdx.x;
  int lane = tid & 63;
  int w = tid >> 6;
  int bofs = b ? 2304 : 2048;
  int cofs = b ? 2432 : 2176;
  for (int o = tid; o < CHUNKL * DSTATE; o += 256) {
    int n = o & 127, s = o >> 7;
    int t = b ? (L_SEQ - 1 - (c * CHUNKL + s)) : (c * CHUNKL + s);
    const bf16* row = xbc + (size_t)t * CONVDIM;
    Bs[s][n] = row[bofs + n];
    Cs[s][n] = row[cofs + n];
  }
  __syncthreads();
  // G[l][s]: wave w -> l rows [32w, 32w+32); s full 128 (8 col-tiles)
  f32x4v acc[2][8];
#pragma unroll
  for (int i = 0; i < 2; i++)
#pragma unroll
    for (int j = 0; j < 8; j++) acc[i][j] = (f32x4v){0.f, 0.f, 0.f, 0.f};
#pragma unroll
  for (int k0 = 0; k0 < 128; k0 += 32) {
    bf16x8v a0 = *(const bf16x8v*)&Cs[w * 32 + (lane & 15)][(lane >> 4) * 8 + k0];
    bf16x8v a1 = *(const bf16x8v*)&Cs[w * 32 + 16 + (lane & 15)][(lane >> 4) * 8 + k0];
#pragma unroll
    for (int j = 0; j < 8; j++) {
      bf16x8v bv = *(const bf16x8v*)&Bs[j * 16 + (lane & 15)][(lane >> 4) * 8 + k0];
      acc[0][j] = __builtin_amdgcn_mfma_f32_16x16x32_bf16(a0, bv, acc[0][j], 0, 0, 0);
      acc[1][j] = __builtin_amdgcn_mfma_f32_16x16x32_bf16(a1, bv, acc[1][j], 0, 0, 0);
    }
  }
  int quad = lane >> 4, cn = lane & 15;
  bf16* Gb = G + (size_t)bc * CHUNKL * CHUNKL;
#pragma unroll
  for (int i = 0; i < 2; i++)
#pragma unroll
    for (int j = 0; j < 8; j++)
#pragma unroll
      for (int r = 0; r < 4; r++) {
        int l = w * 32 + i * 16 + quad * 4 + r;
        int s = j * 16 + cn;
        Gb[l * CHUNKL + s] = f2b(acc[i][j][r]);
      }
}

// ---------------- per-(b,c,h): chunk states only (MFMA, bf16 out) ----------------
__global__ __launch_bounds__(256) void chunk_kernel(
    const bf16* __restrict__ xbc, const float* __restrict__ dt2,
    const float* __restrict__ A_log,
    bf16* __restrict__ states, float* __restrict__ csum) {
  int gid = blockIdx.x;           // (b*32+c)*32 + h
  int h = gid % NHEADS;
  int bc = gid / NHEADS;
  int c = bc % NCHUNK, b = bc / NCHUNK;
  int tid = threadIdx.x;
  int lane = tid & 63;
  int w = tid >> 6;
  __shared__ bf16 BdT[128][136];  // [n][l] = B[l][n]*decay[l]  34 KB
  __shared__ bf16 xdtT[64][136];  // [p][s] = x[s,p]*dt[s]      17 KB
  __shared__ float acs[CHUNKL];
  __shared__ float dtl[CHUNKL];
  __shared__ float decays[CHUNKL];
  if (tid < CHUNKL)
    dtl[tid] = dt2[((size_t)b * L_SEQ + c * CHUNKL + tid) * NHEADS + h];
  __syncthreads();
  if (tid == 0) {
    float Ah = -expf(A_log[h]);
    float s = 0.f;
    for (int l = 0; l < CHUNKL; l++) { s += Ah * dtl[l]; acs[l] = s; }
    csum[gid] = s;
  }
  __syncthreads();
  if (tid < CHUNKL) decays[tid] = expf(acs[CHUNKL - 1] - acs[tid]);
  for (int o = tid; o < CHUNKL * HEADDIM; o += 256) {
    int p = o & 63, s = o >> 6;
    int t = b ? (L_SEQ - 1 - (c * CHUNKL + s)) : (c * CHUNKL + s);
    xdtT[p][s] = f2b(b2f(xbc[(size_t)t * CONVDIM + h * HEADDIM + p]) * dtl[s]);
  }
  __syncthreads();   // decays ready (also xdtT in flight)
  {
    int bofs = b ? 2304 : 2048;
    for (int o = tid; o < CHUNKL * CHUNKL; o += 256) {
      int n = o & 127, l = o >> 7;
      int t = b ? (L_SEQ - 1 - (c * CHUNKL + l)) : (c * CHUNKL + l);
      BdT[n][l] = f2b(b2f(xbc[(size_t)t * CONVDIM + bofs + n]) * decays[l]);
    }
  }
  __syncthreads();
  // states[p][n] = sum_l xdtT[p][l]*BdT[n][l]; wave w -> p rows [16w,16w+16)
  f32x4v accS[8];
#pragma unroll
  for (int j = 0; j < 8; j++) accS[j] = (f32x4v){0.f, 0.f, 0.f, 0.f};
#pragma unroll
  for (int k0 = 0; k0 < 128; k0 += 32) {
    bf16x8v av = *(const bf16x8v*)&xdtT[w * 16 + (lane & 15)][(lane >> 4) * 8 + k0];
#pragma unroll
    for (int j = 0; j < 8; j++) {
      bf16x8v bv = *(const bf16x8v*)&BdT[j * 16 + (lane & 15)][(lane >> 4) * 8 + k0];
      accS[j] = __builtin_amdgcn_mfma_f32_16x16x32_bf16(av, bv, accS[j], 0, 0, 0);
    }
  }
  int quad = lane >> 4, cn = lane & 15;
  bf16* st = states + (size_t)gid * (HEADDIM * DSTATE);
#pragma unroll
  for (int j = 0; j < 8; j++)
#pragma unroll
    for (int r = 0; r < 4; r++) {
      int p = w * 16 + quad * 4 + r;
      int n = j * 16 + cn;
      st[p * DSTATE + n] = f2b(accS[j][r]);
    }
}

// ---------------- inter-chunk scan (in place, bf16; f32 running sum) ----------------
__global__ __launch_bounds__(256) void scan_kernel(
    bf16* __restrict__ states, const float* __restrict__ csum) {
  int idx = blockIdx.x * 256 + threadIdx.x;  // 2*NHEADS*HEADDIM*DSTATE
  int n = idx % DSTATE;
  int p = (idx / DSTATE) % HEADDIM;
  int h = (idx / (DSTATE * HEADDIM)) % NHEADS;
  int b = idx / (DSTATE * HEADDIM * NHEADS);
  float S = 0.f;
  for (int c = 0; c < NCHUNK; c++) {
    int gid = (b * NCHUNK + c) * NHEADS + h;
    size_t off = (size_t)gid * (HEADDIM * DSTATE) + p * DSTATE + n;
    float tmp = b2f(states[off]);
    states[off] = f2b(S);
    S = expf(csum[gid]) * S + tmp;
  }
}

// ---------------- fused Y = Y_diag + Y_off + D*x (MFMA, single bf16 write) ----------------
// Phase 1: W[l][s] = G*exp(acs[l]-acs[s]) (s<=l), SX = xdtT; Y_diag MFMA -> accY.
// Phase 2: WB <- Ce[l][n] = C[l][n]*exp(acs[l]); SX <- St[p][n]; Y_off MFMA += accY.
// Epilogue: Y[l,p] = accY + x*D (bf16, written once, no RMW).
__global__ __launch_bounds__(256) void yoff_kernel(
    const bf16* __restrict__ xbc, const float* __restrict__ dt2,
    const float* __restrict__ A_log, const bf16* __restrict__ G,
    const bf16* __restrict__ states, const float* __restrict__ Dp,
    bf16* __restrict__ Y) {
  int gid = blockIdx.x;
  int h = gid % NHEADS;
  int bc = gid / NHEADS;
  int c = bc % NCHUNK, b = bc / NCHUNK;
  int tid = threadIdx.x;
  int lane = tid & 63;
  int w = tid >> 6;
  __shared__ bf16 WB[128][136];   // 34 KB (W, then Ce)
  __shared__ bf16 SX[64][136];    // 17 KB (xdtT, then St)
  __shared__ float acs[CHUNKL];
  __shared__ float dtl[CHUNKL];
  __shared__ float eAl[CHUNKL];
  if (tid < CHUNKL)
    dtl[tid] = dt2[((size_t)b * L_SEQ + c * CHUNKL + tid) * NHEADS + h];
  __syncthreads();
  if (tid == 0) {
    float Ah = -expf(A_log[h]);
    float s = 0.f;
    for (int l = 0; l < CHUNKL; l++) { s += Ah * dtl[l]; acs[l] = s; }
  }
  __syncthreads();
  if (tid < CHUNKL) eAl[tid] = expf(acs[tid]);   // <= 1
  for (int o = tid; o < CHUNKL * HEADDIM; o += 256) {
    int p = o & 63, s = o >> 6;
    int t = b ? (L_SEQ - 1 - (c * CHUNKL + s)) : (c * CHUNKL + s);
    SX[p][s] = f2b(b2f(xbc[(size_t)t * CONVDIM + h * HEADDIM + p]) * dtl[s]);
  }
  {
    const bf16* Gb = G + (size_t)bc * CHUNKL * CHUNKL;
    for (int o = tid; o < CHUNKL * CHUNKL; o += 256) {
      int s = o & 127, l = o >> 7;
      float wv = (s <= l) ? b2f(Gb[o]) * expf(acs[l] - acs[s]) : 0.f;
      WB[l][s] = f2b(wv);
    }
  }
  __syncthreads();
  f32x4v accY[2][4];
#pragma unroll
  for (int i = 0; i < 2; i++)
#pragma unroll
    for (int j = 0; j < 4; j++) accY[i][j] = (f32x4v){0.f, 0.f, 0.f, 0.f};
  // Y_diag: A=W rows [32w,32w+32), B=xdtT p-tiles, k=s
#pragma unroll
  for (int k0 = 0; k0 < 128; k0 += 32) {
    bf16x8v a0 = *(const bf16x8v*)&WB[w * 32 + (lane & 15)][(lane >> 4) * 8 + k0];
    bf16x8v a1 = *(const bf16x8v*)&WB[w * 32 + 16 + (lane & 15)][(lane >> 4) * 8 + k0];
#pragma unroll
    for (int j = 0; j < 4; j++) {
      bf16x8v bv = *(const bf16x8v*)&SX[j * 16 + (lane & 15)][(lane >> 4) * 8 + k0];
      accY[0][j] = __builtin_amdgcn_mfma_f32_16x16x32_bf16(a0, bv, accY[0][j], 0, 0, 0);
      accY[1][j] = __builtin_amdgcn_mfma_f32_16x16x32_bf16(a1, bv, accY[1][j], 0, 0, 0);
    }
  }
  __syncthreads();   // all phase-1 LDS reads done
  // restage: WB <- Ce, SX <- St
  {
    int cofs = b ? 2432 : 2176;
    for (int o = tid; o < CHUNKL * DSTATE; o += 256) {
      int n = o & 127, l = o >> 7;
      int t = b ? (L_SEQ - 1 - (c * CHUNKL + l)) : (c * CHUNKL + l);
      WB[l][n] = f2b(b2f(xbc[(size_t)t * CONVDIM + cofs + n]) * eAl[l]);
    }
    const bf16* stp = states + (size_t)gid * (HEADDIM * DSTATE);
    for (int o = tid; o < HEADDIM * DSTATE; o += 256) {
      int n = o & 127, p = o >> 7;
      SX[p][n] = stp[o];
    }
  }
  __syncthreads();
  // Y_off: A=Ce rows, B=St p-tiles, k=n; accumulate into same accY
#pragma unroll
  for (int k0 = 0; k0 < 128; k0 += 32) {
    bf16x8v a0 = *(const bf16x8v*)&WB[w * 32 + (lane & 15)][(lane >> 4) * 8 + k0];
    bf16x8v a1 = *(const bf16x8v*)&WB[w * 32 + 16 + (lane & 15)][(lane >> 4) * 8 + k0];
#pragma unroll
    for (int j = 0; j < 4; j++) {
      bf16x8v bv = *(const bf16x8v*)&SX[j * 16 + (lane & 15)][(lane >> 4) * 8 + k0];
      accY[0][j] = __builtin_amdgcn_mfma_f32_16x16x32_bf16(a0, bv, accY[0][j], 0, 0, 0);
      accY[1][j] = __builtin_amdgcn_mfma_f32_16x16x32_bf16(a1, bv, accY[1][j], 0, 0, 0);
    }
  }
  int quad = lane >> 4, cn = lane & 15;
  float Dh = Dp[h];
#pragma unroll
  for (int i = 0; i < 2; i++)
#pragma unroll
    for (int j = 0; j < 4; j++)
#pragma unroll
      for (int r = 0; r < 4; r++) {
        int l = w * 32 + i * 16 + quad * 4 + r;
        int p = j * 16 + cn;
        int t = b ? (L_SEQ - 1 - (c * CHUNKL + l)) : (c * CHUNKL + l);
        float xv = b2f(xbc[(size_t)t * CONVDIM + h * HEADDIM + p]);
        size_t yi = ((size_t)b * L_SEQ + c * CHUNKL + l) * DINNER + h * HEADDIM + p;
        Y[yi] = f2b(accY[i][j][r] + xv * Dh);
      }
}

// ---------------- combine: shift, flip, +x*fd, gate, RMSNorm ----------------
__global__ __launch_bounds__(256) void combine_kernel(
    const bf16* __restrict__ Y, const bf16* __restrict__ xbc,
    const bf16* __restrict__ zx, const float* __restrict__ fd,
    const float* __restrict__ norm_w, bf16* __restrict__ yn) {
  int t = blockIdx.x;
  int tid = threadIdx.x;
  float yg[8];
  float ss = 0.f;
#pragma unroll
  for (int i = 0; i < 8; i++) {
    int j = tid + i * 256;
    float yfw = (t >= 1) ? b2f(Y[(size_t)(t - 1) * DINNER + j]) : 0.f;
    float ybw = (t <= L_SEQ - 2)
                    ? b2f(Y[((size_t)L_SEQ + (L_SEQ - 2 - t)) * DINNER + j]) : 0.f;
    float xog = b2f(xbc[(size_t)t * CONVDIM + j]);
    float fdv = fd[t * NHEADS + (j >> 6)];
    float z = b2f(zx[(size_t)t * DPROJ + j]);
    float y = yfw + ybw + xog * fdv;
    float g = y * (z / (1.f + expf(-z)));
    yg[i] = g;
    ss += g * g;
  }
#pragma unroll
  for (int off = 32; off > 0; off >>= 1) ss += __shfl_down(ss, off);
  __shared__ float red[4];
  if ((tid & 63) == 0) red[tid >> 6] = ss;
  __syncthreads();
  float tot = red[0] + red[1] + red[2] + red[3];
  float scale = rsqrtf(tot / (float)DINNER + 1e-5f);
#pragma unroll
  for (int i = 0; i < 8; i++) {
    int j = tid + i * 256;
    yn[(size_t)t * DINNER + j] = f2b(yg[i] * scale * norm_w[j]);
  }
}

// ---------------- launch ----------------
extern "C" void kernel_launch(void* const* d_in, const int* in_sizes, int n_in,
                              void* d_out, int out_size, void* d_ws, size_t ws_size,
                              hipStream_t stream) {
  const float* u         = (const float*)d_in[0];
  const float* in_proj_w = (const float*)d_in[1];
  const float* conv_w    = (const float*)d_in[2];
  const float* conv_b    = (const float*)d_in[3];
  const float* dt_bias   = (const float*)d_in[4];
  const float* A_log     = (const float*)d_in[5];
  const float* Dp        = (const float*)d_in[6];
  const float* fc_D_w    = (const float*)d_in[7];
  const float* norm_w    = (const float*)d_in[8];
  const float* out_proj_w= (const float*)d_in[9];
  float* out = (float*)d_out;

  // Region sizes unchanged from R6 (aliases stay valid); stored types now bf16
  // for G / Yb / st.
  char* base = (char*)d_ws;
  bf16*  zx  = (bf16*)base;  base += (size_t)L_SEQ * DPROJ * 2;                    // 38.3 MB
  bf16*  xbc = (bf16*)base;  base += (size_t)L_SEQ * CONVDIM * 2;                  // 21.0 MB
  float* dt2 = (float*)base; base += (size_t)2 * L_SEQ * NHEADS * 4;               //  1.0 MB
  bf16*  G   = (bf16*)base;  base += (size_t)2 * NCHUNK * CHUNKL * CHUNKL * 4;     //  4.2 MB region
  bf16*  Yb  = (bf16*)base;  base += (size_t)2 * L_SEQ * DINNER * 4;               // 67.1 MB region
  bf16*  stb = (bf16*)base;  base += (size_t)2 * NCHUNK * NHEADS * HEADDIM * DSTATE * 4; // 67.1 MB region
  float* cs  = (float*)base; base += (size_t)2 * NCHUNK * NHEADS * 4;              //  8 KB
  // aliases into dead regions:
  bf16*  u_bf   = (bf16*)Yb;                          // 8.4 MB   (Yb live only after yoff)
  bf16*  w1p_bf = (bf16*)((char*)Yb + 9437184);       // 9.7 MB   (padded in_proj_w)
  bf16*  w2_bf  = (bf16*)G;                           // 4.2 MB   (G dead after yoff)
  bf16*  yn     = (bf16*)stb;                         // 16.8 MB  (stb dead after yoff)
  float* fd     = (float*)((char*)stb + 33554432);    //  0.5 MB

  // 0. casts for MFMA gemm1
  cast_kernel<<<(L_SEQ * DMODEL + 255) / 256, 256, 0, stream>>>(
      u, u_bf, L_SEQ * DMODEL, L_SEQ * DMODEL);
  cast_kernel<<<(NPAD1 * DMODEL + 255) / 256, 256, 0, stream>>>(
      in_proj_w, w1p_bf, DPROJ * DMODEL, NPAD1 * DMODEL);
  // 1. in_proj: zx = u @ in_proj_w^T  (MFMA)
  gemm_mfma<bf16><<<dim3(NPAD1 / 128, L_SEQ / 128), 256, 0, stream>>>(
      u_bf, DMODEL, w1p_bf, DMODEL, zx, DPROJ, DPROJ, DMODEL);
  // 2. conv + silu
  conv_silu_kernel<<<(L_SEQ * CONVDIM + 255) / 256, 256, 0, stream>>>(
      zx, conv_w, conv_b, xbc);
  // 2b. dt
  dt_kernel<<<(2 * L_SEQ * NHEADS + 255) / 256, 256, 0, stream>>>(
      zx, dt_bias, dt2);
  // 3a. G = C B^T per (b,c)  (MFMA, bf16)
  gmat_kernel<<<2 * NCHUNK, 256, 0, stream>>>(xbc, G);
  // 3b. chunk states (MFMA, bf16)
  chunk_kernel<<<2 * NCHUNK * NHEADS, 256, 0, stream>>>(
      xbc, dt2, A_log, stb, cs);
  // 3c. inter-chunk scan (bf16)
  scan_kernel<<<(2 * NHEADS * HEADDIM * DSTATE) / 256, 256, 0, stream>>>(stb, cs);
  // 3d. fused Y = Y_diag + Y_off + D*x (MFMA, single bf16 write)
  yoff_kernel<<<2 * NCHUNK * NHEADS, 256, 0, stream>>>(
      xbc, dt2, A_log, G, stb, Dp, Yb);
  // 4a. cast out_proj_w (into dead G region)
  cast_kernel<<<(DMODEL * DINNER + 255) / 256, 256, 0, stream>>>(
      out_proj_w, w2_bf, DMODEL * DINNER, DMODEL * DINNER);
  // 4b. fd = x_og @ fc_D_w^T + D
  fc_kernel<<<L_SEQ / 16, 256, 0, stream>>>(xbc, fc_D_w, Dp, fd);
  // 5. combine + gate + RMSNorm
  combine_kernel<<<L_SEQ, 256, 0, stream>>>(Yb, xbc, zx, fd, norm_w, yn);
  // 6. out_proj (MFMA)
  gemm_mfma<float><<<dim3(DMODEL / 128, L_SEQ / 128), 256, 0, stream>>>(
      yn, DINNER, w2_bf, DINNER, out, DMODEL, DMODEL, DINNER);
}

// Round 10
// 444.024 us; speedup vs baseline: 5.5866x; 1.1550x over previous
//
#include <hip/hip_runtime.h>
#include <hip/hip_bf16.h>
#include <math.h>

// ---------------- problem constants ----------------
#define L_SEQ   4096
#define DMODEL  1024
#define DINNER  2048
#define NHEADS  32
#define HEADDIM 64
#define DSTATE  128
#define NCHUNK  32
#define CHUNKL  128
#define CONVDIM 2560
#define DPROJ   4672   // 2*DINNER + 2*(2*DSTATE) + 2*NHEADS
#define NPAD1   4736   // DPROJ padded to multiple of 128 for MFMA gemm

typedef __hip_bfloat16 bf16;
__device__ __forceinline__ float b2f(bf16 x) { return __bfloat162float(x); }
__device__ __forceinline__ bf16 f2b(float x) { return __float2bfloat16(x); }
__device__ __forceinline__ float sh2f(short s) {
  return __uint_as_float(((unsigned int)(unsigned short)s) << 16);
}
__device__ __forceinline__ short f2bs(float x) {
  bf16 t = __float2bfloat16(x);
  return *reinterpret_cast<short*>(&t);
}

typedef __attribute__((ext_vector_type(8))) short bf16x8v;
typedef __attribute__((ext_vector_type(4))) float f32x4v;

__device__ __forceinline__ float dot8(bf16x8v x, float4 w0, float4 w1) {
  return sh2f(x[0]) * w0.x + sh2f(x[1]) * w0.y + sh2f(x[2]) * w0.z + sh2f(x[3]) * w0.w +
         sh2f(x[4]) * w1.x + sh2f(x[5]) * w1.y + sh2f(x[6]) * w1.z + sh2f(x[7]) * w1.w;
}

// zxbcdt column layout: [0,2048) = z ; [2048,4608) = xBC ; [4608,4672) = dt raw
// xBC_conv channel layout: [0,2048) = x ; fw B = [2048,2176) C = [2176,2304)
//                          bw B = [2304,2432) C = [2432,2560)  (bw streams time-flipped)

// ---------------- f32 -> bf16 cast (dst beyond n_src zero-filled) ----------------
__global__ __launch_bounds__(256) void cast_kernel(
    const float* __restrict__ src, bf16* __restrict__ dst, int n_src, int n_tot) {
  int i = blockIdx.x * 256 + threadIdx.x;
  if (i < n_tot) dst[i] = (i < n_src) ? f2b(src[i]) : f2b(0.f);
}

// ---------------- MFMA GEMM: C[m,n] = sum_k A[m,k]*B[n,k], bf16 in, f32 acc ----------------
template <typename TC>
__global__ __launch_bounds__(256) void gemm_mfma(
    const bf16* __restrict__ A, int lda,
    const bf16* __restrict__ B, int ldb,
    TC* __restrict__ C, int ldc,
    int N, int K) {
  __shared__ short As[128][32];
  __shared__ short Bs[128][32];
  int tid = threadIdx.x;
  int lane = tid & 63;
  int w = tid >> 6;            // wave 0..3
  int wr = w >> 1, wc = w & 1; // 2x2 wave grid
  int bm = blockIdx.y * 128;
  int bn = blockIdx.x * 128;
  f32x4v acc[4][4];
#pragma unroll
  for (int i = 0; i < 4; i++)
#pragma unroll
    for (int j = 0; j < 4; j++) acc[i][j] = (f32x4v){0.f, 0.f, 0.f, 0.f};

  const bf16* Ab = A + (size_t)(bm + w * 32 + (lane >> 2)) * lda + (lane & 3) * 8;
  const bf16* Bb = B + (size_t)(bn + w * 32 + (lane >> 2)) * ldb + (lane & 3) * 8;

  for (int k0 = 0; k0 < K; k0 += 32) {
    __builtin_amdgcn_global_load_lds(
        (const __attribute__((address_space(1))) void*)(Ab + k0),
        (__attribute__((address_space(3))) void*)&As[w * 32][0], 16, 0, 0);
    __builtin_amdgcn_global_load_lds(
        (const __attribute__((address_space(1))) void*)(Ab + (size_t)16 * lda + k0),
        (__attribute__((address_space(3))) void*)&As[w * 32 + 16][0], 16, 0, 0);
    __builtin_amdgcn_global_load_lds(
        (const __attribute__((address_space(1))) void*)(Bb + k0),
        (__attribute__((address_space(3))) void*)&Bs[w * 32][0], 16, 0, 0);
    __builtin_amdgcn_global_load_lds(
        (const __attribute__((address_space(1))) void*)(Bb + (size_t)16 * ldb + k0),
        (__attribute__((address_space(3))) void*)&Bs[w * 32 + 16][0], 16, 0, 0);
    __syncthreads();
    bf16x8v af[4], bv[4];
#pragma unroll
    for (int i = 0; i < 4; i++)
      af[i] = *(const bf16x8v*)&As[wr * 64 + i * 16 + (lane & 15)][(lane >> 4) * 8];
#pragma unroll
    for (int j = 0; j < 4; j++)
      bv[j] = *(const bf16x8v*)&Bs[wc * 64 + j * 16 + (lane & 15)][(lane >> 4) * 8];
#pragma unroll
    for (int i = 0; i < 4; i++)
#pragma unroll
      for (int j = 0; j < 4; j++)
        acc[i][j] = __builtin_amdgcn_mfma_f32_16x16x32_bf16(af[i], bv[j], acc[i][j], 0, 0, 0);
    __syncthreads();
  }
  int quad = lane >> 4;
  int cn = lane & 15;
#pragma unroll
  for (int i = 0; i < 4; i++) {
#pragma unroll
    for (int j = 0; j < 4; j++) {
      int col = bn + wc * 64 + j * 16 + cn;
      if (col < N) {
#pragma unroll
        for (int r = 0; r < 4; r++) {
          int row = bm + wr * 64 + i * 16 + quad * 4 + r;
          float v = acc[i][j][r];
          if constexpr (sizeof(TC) == 2) C[(size_t)row * ldc + col] = f2b(v);
          else                           C[(size_t)row * ldc + col] = v;
        }
      }
    }
  }
}

// ---------------- fc_D: fd[t][h] = sum_k x[t,k]*W[h,k] + D[h] ----------------
__global__ __launch_bounds__(256) void fc_kernel(
    const bf16* __restrict__ xbc, const float* __restrict__ Wf,
    const float* __restrict__ Dp, float* __restrict__ fd) {
  int lane = threadIdx.x & 63;
  int w = threadIdx.x >> 6;
  int t0 = (blockIdx.x * 4 + w) * 4;
  int h = lane & 31;
  int g = lane >> 5;                 // k-half
  const float* wr = Wf + (size_t)h * DINNER + g * 1024;
  const bf16* xr = xbc + (size_t)t0 * CONVDIM + g * 1024;
  float a0 = 0.f, a1 = 0.f, a2 = 0.f, a3 = 0.f;
  for (int k = 0; k < 1024; k += 8) {
    float4 w0 = *(const float4*)(wr + k);
    float4 w1 = *(const float4*)(wr + k + 4);
    bf16x8v x0 = *(const bf16x8v*)(xr + k);
    bf16x8v x1 = *(const bf16x8v*)(xr + CONVDIM + k);
    bf16x8v x2 = *(const bf16x8v*)(xr + 2 * CONVDIM + k);
    bf16x8v x3 = *(const bf16x8v*)(xr + 3 * CONVDIM + k);
    a0 += dot8(x0, w0, w1);
    a1 += dot8(x1, w0, w1);
    a2 += dot8(x2, w0, w1);
    a3 += dot8(x3, w0, w1);
  }
  a0 += __shfl_down(a0, 32);
  a1 += __shfl_down(a1, 32);
  a2 += __shfl_down(a2, 32);
  a3 += __shfl_down(a3, 32);
  if (lane < 32) {
    float d = Dp[h];
    fd[(t0 + 0) * NHEADS + h] = a0 + d;
    fd[(t0 + 1) * NHEADS + h] = a1 + d;
    fd[(t0 + 2) * NHEADS + h] = a2 + d;
    fd[(t0 + 3) * NHEADS + h] = a3 + d;
  }
}

// ---------------- conv (depthwise causal, k=4) + SiLU ----------------
__global__ __launch_bounds__(256) void conv_silu_kernel(
    const bf16* __restrict__ zx, const float* __restrict__ conv_w,
    const float* __restrict__ conv_b, bf16* __restrict__ xbc) {
  int idx = blockIdx.x * 256 + threadIdx.x;   // L_SEQ*CONVDIM
  if (idx >= L_SEQ * CONVDIM) return;
  int ch = idx % CONVDIM;
  int t = idx / CONVDIM;
  const bf16* col = zx + DINNER + ch;         // xBC region
  float w0 = conv_w[ch * 4 + 0], w1 = conv_w[ch * 4 + 1];
  float w2 = conv_w[ch * 4 + 2], w3 = conv_w[ch * 4 + 3];
  float acc = conv_b[ch];
  if (t >= 3) acc += w0 * b2f(col[(size_t)(t - 3) * DPROJ]);
  if (t >= 2) acc += w1 * b2f(col[(size_t)(t - 2) * DPROJ]);
  if (t >= 1) acc += w2 * b2f(col[(size_t)(t - 1) * DPROJ]);
  acc += w3 * b2f(col[(size_t)t * DPROJ]);
  xbc[idx] = f2b(acc / (1.f + __expf(-acc)));
}

// ---------------- dt: split fw/bw (bw time-flipped), softplus(dt + bias) ----------------
__global__ __launch_bounds__(256) void dt_kernel(
    const bf16* __restrict__ zx, const float* __restrict__ dt_bias,
    float* __restrict__ dt2) {
  int idx = blockIdx.x * 256 + threadIdx.x;   // 2*L_SEQ*NHEADS
  if (idx >= 2 * L_SEQ * NHEADS) return;
  int h = idx % NHEADS;
  int t = (idx / NHEADS) % L_SEQ;
  int b = idx / (NHEADS * L_SEQ);
  float v;
  if (b == 0) v = b2f(zx[(size_t)t * DPROJ + 4608 + h]);
  else        v = b2f(zx[(size_t)(L_SEQ - 1 - t) * DPROJ + 4608 + NHEADS + h]);
  v += dt_bias[h];
  dt2[idx] = (v > 20.f) ? v : log1pf(expf(v));
}

// ---------------- G[b,c,l,s] = sum_n C[l,n]*B[s,n]  (MFMA, bf16 out) ----------------
__global__ __launch_bounds__(256) void gmat_kernel(
    const bf16* __restrict__ xbc, bf16* __restrict__ G) {
  __shared__ bf16 Cs[128][136];  // C[l][n]  34 KB
  __shared__ bf16 Bs[128][136];  // B[s][n]  34 KB
  int bc = blockIdx.x;            // b*32 + c
  int b = bc / NCHUNK, c = bc % NCHUNK;
  int tid = threadIdx.x;
  int lane = tid & 63;
  int w = tid >> 6;
  int bofs = b ? 2304 : 2048;
  int cofs = b ? 2432 : 2176;
  for (int o = tid; o < CHUNKL * DSTATE / 8; o += 256) {   // 2048 vecs
    int s = o >> 4;
    int n8 = (o & 15) * 8;
    int t = b ? (L_SEQ - 1 - (c * CHUNKL + s)) : (c * CHUNKL + s);
    const bf16* row = xbc + (size_t)t * CONVDIM;
    *(bf16x8v*)&Bs[s][n8] = *(const bf16x8v*)&row[bofs + n8];
    *(bf16x8v*)&Cs[s][n8] = *(const bf16x8v*)&row[cofs + n8];
  }
  __syncthreads();
  f32x4v acc[2][8];
#pragma unroll
  for (int i = 0; i < 2; i++)
#pragma unroll
    for (int j = 0; j < 8; j++) acc[i][j] = (f32x4v){0.f, 0.f, 0.f, 0.f};
#pragma unroll
  for (int k0 = 0; k0 < 128; k0 += 32) {
    bf16x8v a0 = *(const bf16x8v*)&Cs[w * 32 + (lane & 15)][(lane >> 4) * 8 + k0];
    bf16x8v a1 = *(const bf16x8v*)&Cs[w * 32 + 16 + (lane & 15)][(lane >> 4) * 8 + k0];
#pragma unroll
    for (int j = 0; j < 8; j++) {
      bf16x8v bv = *(const bf16x8v*)&Bs[j * 16 + (lane & 15)][(lane >> 4) * 8 + k0];
      acc[0][j] = __builtin_amdgcn_mfma_f32_16x16x32_bf16(a0, bv, acc[0][j], 0, 0, 0);
      acc[1][j] = __builtin_amdgcn_mfma_f32_16x16x32_bf16(a1, bv, acc[1][j], 0, 0, 0);
    }
  }
  int quad = lane >> 4, cn = lane & 15;
  bf16* Gb = G + (size_t)bc * CHUNKL * CHUNKL;
#pragma unroll
  for (int i = 0; i < 2; i++)
#pragma unroll
    for (int j = 0; j < 8; j++)
#pragma unroll
      for (int r = 0; r < 4; r++) {
        int l = w * 32 + i * 16 + quad * 4 + r;
        int s = j * 16 + cn;
        Gb[l * CHUNKL + s] = f2b(acc[i][j][r]);
      }
}

// ---------------- per-(b,c,h): chunk states only (MFMA, bf16 out) ----------------
__global__ __launch_bounds__(256) void chunk_kernel(
    const bf16* __restrict__ xbc, const float* __restrict__ dt2,
    const float* __restrict__ A_log,
    bf16* __restrict__ states, float* __restrict__ csum) {
  int gid = blockIdx.x;           // (b*32+c)*32 + h
  int h = gid % NHEADS;
  int bc = gid / NHEADS;
  int c = bc % NCHUNK, b = bc / NCHUNK;
  int tid = threadIdx.x;
  int lane = tid & 63;
  int w = tid >> 6;
  __shared__ bf16 BdT[128][136];  // [n][l] = B[l][n]*decay[l]  34 KB
  __shared__ bf16 xdtT[64][136];  // [p][s] = x[s,p]*dt[s]      17 KB
  __shared__ float acs[CHUNKL];
  __shared__ float dtl[CHUNKL];
  __shared__ float decays[CHUNKL];
  if (tid < CHUNKL)
    dtl[tid] = dt2[((size_t)b * L_SEQ + c * CHUNKL + tid) * NHEADS + h];
  __syncthreads();
  if (tid == 0) {
    float Ah = -__expf(A_log[h]);
    float s = 0.f;
    for (int l = 0; l < CHUNKL; l++) { s += Ah * dtl[l]; acs[l] = s; }
    csum[gid] = __expf(s);        // stored pre-exponentiated for scan
  }
  __syncthreads();
  if (tid < CHUNKL) decays[tid] = __expf(acs[CHUNKL - 1] - acs[tid]);
  // xdtT[p][s] staging: lane->s (t-strided 16B loads), conflict-free scatter
  for (int o = tid; o < CHUNKL * HEADDIM / 8; o += 256) {   // 1024 vecs
    int s = o & 127;
    int p8 = (o >> 7) * 8;
    int t = b ? (L_SEQ - 1 - (c * CHUNKL + s)) : (c * CHUNKL + s);
    bf16x8v xv = *(const bf16x8v*)&xbc[(size_t)t * CONVDIM + h * HEADDIM + p8];
    float d = dtl[s];
#pragma unroll
    for (int j = 0; j < 8; j++) xdtT[p8 + j][s] = f2b(sh2f(xv[j]) * d);
  }
  __syncthreads();   // decays ready
  // BdT[n][l] staging: lane->l, conflict-free scatter
  for (int o = tid; o < CHUNKL * CHUNKL / 8; o += 256) {    // 2048 vecs
    int l = o & 127;
    int n8 = (o >> 7) * 8;
    int t = b ? (L_SEQ - 1 - (c * CHUNKL + l)) : (c * CHUNKL + l);
    bf16x8v bv = *(const bf16x8v*)&xbc[(size_t)t * CONVDIM + (b ? 2304 : 2048) + n8];
    float d = decays[l];
#pragma unroll
    for (int j = 0; j < 8; j++) BdT[n8 + j][l] = f2b(sh2f(bv[j]) * d);
  }
  __syncthreads();
  // states[p][n] = sum_l xdtT[p][l]*BdT[n][l]; wave w -> p rows [16w,16w+16)
  f32x4v accS[8];
#pragma unroll
  for (int j = 0; j < 8; j++) accS[j] = (f32x4v){0.f, 0.f, 0.f, 0.f};
#pragma unroll
  for (int k0 = 0; k0 < 128; k0 += 32) {
    bf16x8v av = *(const bf16x8v*)&xdtT[w * 16 + (lane & 15)][(lane >> 4) * 8 + k0];
#pragma unroll
    for (int j = 0; j < 8; j++) {
      bf16x8v bv = *(const bf16x8v*)&BdT[j * 16 + (lane & 15)][(lane >> 4) * 8 + k0];
      accS[j] = __builtin_amdgcn_mfma_f32_16x16x32_bf16(av, bv, accS[j], 0, 0, 0);
    }
  }
  int quad = lane >> 4, cn = lane & 15;
  bf16* st = states + (size_t)gid * (HEADDIM * DSTATE);
#pragma unroll
  for (int j = 0; j < 8; j++)
#pragma unroll
    for (int r = 0; r < 4; r++) {
      int p = w * 16 + quad * 4 + r;
      int n = j * 16 + cn;
      st[p * DSTATE + n] = f2b(accS[j][r]);
    }
}

// ---------------- inter-chunk scan (in place, bf16; csum pre-exponentiated) ----------------
__global__ __launch_bounds__(256) void scan_kernel(
    bf16* __restrict__ states, const float* __restrict__ csum) {
  int idx = blockIdx.x * 256 + threadIdx.x;  // 2*NHEADS*HEADDIM*DSTATE
  int n = idx % DSTATE;
  int p = (idx / DSTATE) % HEADDIM;
  int h = (idx / (DSTATE * HEADDIM)) % NHEADS;
  int b = idx / (DSTATE * HEADDIM * NHEADS);
  float S = 0.f;
  for (int c = 0; c < NCHUNK; c++) {
    int gid = (b * NCHUNK + c) * NHEADS + h;
    size_t off = (size_t)gid * (HEADDIM * DSTATE) + p * DSTATE + n;
    float tmp = b2f(states[off]);
    states[off] = f2b(S);
    S = csum[gid] * S + tmp;
  }
}

// ---------------- fused Y = Y_diag + Y_off + D*x (MFMA, single bf16 write) ----------------
__global__ __launch_bounds__(256) void yoff_kernel(
    const bf16* __restrict__ xbc, const float* __restrict__ dt2,
    const float* __restrict__ A_log, const bf16* __restrict__ G,
    const bf16* __restrict__ states, const float* __restrict__ Dp,
    bf16* __restrict__ Y) {
  int gid = blockIdx.x;
  int h = gid % NHEADS;
  int bc = gid / NHEADS;
  int c = bc % NCHUNK, b = bc / NCHUNK;
  int tid = threadIdx.x;
  int lane = tid & 63;
  int w = tid >> 6;
  __shared__ bf16 WB[128][136];   // 34 KB (W, then Ce)
  __shared__ bf16 SX[64][136];    // 17 KB (xdtT, then St)
  __shared__ float acs[CHUNKL];
  __shared__ float dtl[CHUNKL];
  __shared__ float eAl[CHUNKL];
  if (tid < CHUNKL)
    dtl[tid] = dt2[((size_t)b * L_SEQ + c * CHUNKL + tid) * NHEADS + h];
  __syncthreads();
  if (tid == 0) {
    float Ah = -__expf(A_log[h]);
    float s = 0.f;
    for (int l = 0; l < CHUNKL; l++) { s += Ah * dtl[l]; acs[l] = s; }
  }
  __syncthreads();
  if (tid < CHUNKL) eAl[tid] = __expf(acs[tid]);   // <= 1
  // SX <- xdtT[p][s]: lane->s, conflict-free scatter
  for (int o = tid; o < CHUNKL * HEADDIM / 8; o += 256) {   // 1024 vecs
    int s = o & 127;
    int p8 = (o >> 7) * 8;
    int t = b ? (L_SEQ - 1 - (c * CHUNKL + s)) : (c * CHUNKL + s);
    bf16x8v xv = *(const bf16x8v*)&xbc[(size_t)t * CONVDIM + h * HEADDIM + p8];
    float d = dtl[s];
#pragma unroll
    for (int j = 0; j < 8; j++) SX[p8 + j][s] = f2b(sh2f(xv[j]) * d);
  }
  // WB <- W[l][s] = G*exp(acs[l]-acs[s]) (s<=l): vectorized, b128 writes
  {
    const bf16* Gb = G + (size_t)bc * CHUNKL * CHUNKL;
    for (int o = tid; o < CHUNKL * CHUNKL / 8; o += 256) {  // 2048 vecs
      int l = o >> 4;
      int s8 = (o & 15) * 8;
      bf16x8v g = *(const bf16x8v*)&Gb[l * CHUNKL + s8];
      float al = acs[l];
      bf16x8v wv;
#pragma unroll
      for (int j = 0; j < 8; j++) {
        int s = s8 + j;
        float e = (s <= l) ? sh2f(g[j]) * __expf(al - acs[s]) : 0.f;
        wv[j] = f2bs(e);
      }
      *(bf16x8v*)&WB[l][s8] = wv;
    }
  }
  __syncthreads();
  f32x4v accY[2][4];
#pragma unroll
  for (int i = 0; i < 2; i++)
#pragma unroll
    for (int j = 0; j < 4; j++) accY[i][j] = (f32x4v){0.f, 0.f, 0.f, 0.f};
  // Y_diag: A=W rows [32w,32w+32), B=xdtT p-tiles, k=s
#pragma unroll
  for (int k0 = 0; k0 < 128; k0 += 32) {
    bf16x8v a0 = *(const bf16x8v*)&WB[w * 32 + (lane & 15)][(lane >> 4) * 8 + k0];
    bf16x8v a1 = *(const bf16x8v*)&WB[w * 32 + 16 + (lane & 15)][(lane >> 4) * 8 + k0];
#pragma unroll
    for (int j = 0; j < 4; j++) {
      bf16x8v bv = *(const bf16x8v*)&SX[j * 16 + (lane & 15)][(lane >> 4) * 8 + k0];
      accY[0][j] = __builtin_amdgcn_mfma_f32_16x16x32_bf16(a0, bv, accY[0][j], 0, 0, 0);
      accY[1][j] = __builtin_amdgcn_mfma_f32_16x16x32_bf16(a1, bv, accY[1][j], 0, 0, 0);
    }
  }
  __syncthreads();   // all phase-1 LDS reads done
  // restage: WB <- Ce[l][n] (row-contiguous, b128), SX <- St (16B copies)
  {
    int cofs = b ? 2432 : 2176;
    for (int o = tid; o < CHUNKL * DSTATE / 8; o += 256) {  // 2048 vecs
      int l = o >> 4;
      int n8 = (o & 15) * 8;
      int t = b ? (L_SEQ - 1 - (c * CHUNKL + l)) : (c * CHUNKL + l);
      bf16x8v cv = *(const bf16x8v*)&xbc[(size_t)t * CONVDIM + cofs + n8];
      float e = eAl[l];
      bf16x8v ov;
#pragma unroll
      for (int j = 0; j < 8; j++) ov[j] = f2bs(sh2f(cv[j]) * e);
      *(bf16x8v*)&WB[l][n8] = ov;
    }
    const bf16* stp = states + (size_t)gid * (HEADDIM * DSTATE);
    for (int o = tid; o < HEADDIM * DSTATE / 8; o += 256) { // 1024 vecs
      int p = o >> 4;
      int n8 = (o & 15) * 8;
      *(bf16x8v*)&SX[p][n8] = *(const bf16x8v*)&stp[o * 8];
    }
  }
  __syncthreads();
  // Y_off: A=Ce rows, B=St p-tiles, k=n; accumulate into same accY
#pragma unroll
  for (int k0 = 0; k0 < 128; k0 += 32) {
    bf16x8v a0 = *(const bf16x8v*)&WB[w * 32 + (lane & 15)][(lane >> 4) * 8 + k0];
    bf16x8v a1 = *(const bf16x8v*)&WB[w * 32 + 16 + (lane & 15)][(lane >> 4) * 8 + k0];
#pragma unroll
    for (int j = 0; j < 4; j++) {
      bf16x8v bv = *(const bf16x8v*)&SX[j * 16 + (lane & 15)][(lane >> 4) * 8 + k0];
      accY[0][j] = __builtin_amdgcn_mfma_f32_16x16x32_bf16(a0, bv, accY[0][j], 0, 0, 0);
      accY[1][j] = __builtin_amdgcn_mfma_f32_16x16x32_bf16(a1, bv, accY[1][j], 0, 0, 0);
    }
  }
  int quad = lane >> 4, cn = lane & 15;
  float Dh = Dp[h];
#pragma unroll
  for (int i = 0; i < 2; i++)
#pragma unroll
    for (int j = 0; j < 4; j++)
#pragma unroll
      for (int r = 0; r < 4; r++) {
        int l = w * 32 + i * 16 + quad * 4 + r;
        int p = j * 16 + cn;
        int t = b ? (L_SEQ - 1 - (c * CHUNKL + l)) : (c * CHUNKL + l);
        float xv = b2f(xbc[(size_t)t * CONVDIM + h * HEADDIM + p]);
        size_t yi = ((size_t)b * L_SEQ + c * CHUNKL + l) * DINNER + h * HEADDIM + p;
        Y[yi] = f2b(accY[i][j][r] + xv * Dh);
      }
}

// ---------------- combine: shift, flip, +x*fd, gate, RMSNorm (vectorized) ----------------
__global__ __launch_bounds__(256) void combine_kernel(
    const bf16* __restrict__ Y, const bf16* __restrict__ xbc,
    const bf16* __restrict__ zx, const float* __restrict__ fd,
    const float* __restrict__ norm_w, bf16* __restrict__ yn) {
  int t = blockIdx.x;
  int tid = threadIdx.x;
  int j8 = tid * 8;
  float yf[8], yb[8];
#pragma unroll
  for (int j = 0; j < 8; j++) { yf[j] = 0.f; yb[j] = 0.f; }
  if (t >= 1) {
    bf16x8v v = *(const bf16x8v*)&Y[(size_t)(t - 1) * DINNER + j8];
#pragma unroll
    for (int j = 0; j < 8; j++) yf[j] = sh2f(v[j]);
  }
  if (t <= L_SEQ - 2) {
    bf16x8v v = *(const bf16x8v*)&Y[((size_t)L_SEQ + (L_SEQ - 2 - t)) * DINNER + j8];
#pragma unroll
    for (int j = 0; j < 8; j++) yb[j] = sh2f(v[j]);
  }
  bf16x8v xogv = *(const bf16x8v*)&xbc[(size_t)t * CONVDIM + j8];
  bf16x8v zv = *(const bf16x8v*)&zx[(size_t)t * DPROJ + j8];
  float fdv = fd[t * NHEADS + (j8 >> 6)];
  float yg[8];
  float ss = 0.f;
#pragma unroll
  for (int j = 0; j < 8; j++) {
    float y = yf[j] + yb[j] + sh2f(xogv[j]) * fdv;
    float z = sh2f(zv[j]);
    float g = y * (z / (1.f + __expf(-z)));
    yg[j] = g;
    ss += g * g;
  }
#pragma unroll
  for (int off = 32; off > 0; off >>= 1) ss += __shfl_down(ss, off);
  __shared__ float red[4];
  if ((tid & 63) == 0) red[tid >> 6] = ss;
  __syncthreads();
  float tot = red[0] + red[1] + red[2] + red[3];
  float scale = rsqrtf(tot / (float)DINNER + 1e-5f);
  float4 nw0 = *(const float4*)&norm_w[j8];
  float4 nw1 = *(const float4*)&norm_w[j8 + 4];
  bf16x8v ov;
  ov[0] = f2bs(yg[0] * scale * nw0.x);
  ov[1] = f2bs(yg[1] * scale * nw0.y);
  ov[2] = f2bs(yg[2] * scale * nw0.z);
  ov[3] = f2bs(yg[3] * scale * nw0.w);
  ov[4] = f2bs(yg[4] * scale * nw1.x);
  ov[5] = f2bs(yg[5] * scale * nw1.y);
  ov[6] = f2bs(yg[6] * scale * nw1.z);
  ov[7] = f2bs(yg[7] * scale * nw1.w);
  *(bf16x8v*)&yn[(size_t)t * DINNER + j8] = ov;
}

// ---------------- launch ----------------
extern "C" void kernel_launch(void* const* d_in, const int* in_sizes, int n_in,
                              void* d_out, int out_size, void* d_ws, size_t ws_size,
                              hipStream_t stream) {
  const float* u         = (const float*)d_in[0];
  const float* in_proj_w = (const float*)d_in[1];
  const float* conv_w    = (const float*)d_in[2];
  const float* conv_b    = (const float*)d_in[3];
  const float* dt_bias   = (const float*)d_in[4];
  const float* A_log     = (const float*)d_in[5];
  const float* Dp        = (const float*)d_in[6];
  const float* fc_D_w    = (const float*)d_in[7];
  const float* norm_w    = (const float*)d_in[8];
  const float* out_proj_w= (const float*)d_in[9];
  float* out = (float*)d_out;

  char* base = (char*)d_ws;
  bf16*  zx  = (bf16*)base;  base += (size_t)L_SEQ * DPROJ * 2;                    // 38.3 MB
  bf16*  xbc = (bf16*)base;  base += (size_t)L_SEQ * CONVDIM * 2;                  // 21.0 MB
  float* dt2 = (float*)base; base += (size_t)2 * L_SEQ * NHEADS * 4;               //  1.0 MB
  bf16*  G   = (bf16*)base;  base += (size_t)2 * NCHUNK * CHUNKL * CHUNKL * 4;     //  4.2 MB region
  bf16*  Yb  = (bf16*)base;  base += (size_t)2 * L_SEQ * DINNER * 4;               // 67.1 MB region
  bf16*  stb = (bf16*)base;  base += (size_t)2 * NCHUNK * NHEADS * HEADDIM * DSTATE * 4; // 67.1 MB region
  float* cs  = (float*)base; base += (size_t)2 * NCHUNK * NHEADS * 4;              //  8 KB
  // aliases into dead regions:
  bf16*  u_bf   = (bf16*)Yb;                          // 8.4 MB   (Yb live only after yoff)
  bf16*  w1p_bf = (bf16*)((char*)Yb + 9437184);       // 9.7 MB   (padded in_proj_w)
  bf16*  w2_bf  = (bf16*)G;                           // 4.2 MB   (G dead after yoff)
  bf16*  yn     = (bf16*)stb;                         // 16.8 MB  (stb dead after yoff)
  float* fd     = (float*)((char*)stb + 33554432);    //  0.5 MB

  // 0. casts for MFMA gemm1
  cast_kernel<<<(L_SEQ * DMODEL + 255) / 256, 256, 0, stream>>>(
      u, u_bf, L_SEQ * DMODEL, L_SEQ * DMODEL);
  cast_kernel<<<(NPAD1 * DMODEL + 255) / 256, 256, 0, stream>>>(
      in_proj_w, w1p_bf, DPROJ * DMODEL, NPAD1 * DMODEL);
  // 1. in_proj: zx = u @ in_proj_w^T  (MFMA)
  gemm_mfma<bf16><<<dim3(NPAD1 / 128, L_SEQ / 128), 256, 0, stream>>>(
      u_bf, DMODEL, w1p_bf, DMODEL, zx, DPROJ, DPROJ, DMODEL);
  // 2. conv + silu
  conv_silu_kernel<<<(L_SEQ * CONVDIM + 255) / 256, 256, 0, stream>>>(
      zx, conv_w, conv_b, xbc);
  // 2b. dt
  dt_kernel<<<(2 * L_SEQ * NHEADS + 255) / 256, 256, 0, stream>>>(
      zx, dt_bias, dt2);
  // 3a. G = C B^T per (b,c)  (MFMA, bf16)
  gmat_kernel<<<2 * NCHUNK, 256, 0, stream>>>(xbc, G);
  // 3b. chunk states (MFMA, bf16)
  chunk_kernel<<<2 * NCHUNK * NHEADS, 256, 0, stream>>>(
      xbc, dt2, A_log, stb, cs);
  // 3c. inter-chunk scan (bf16, exp-free inner loop)
  scan_kernel<<<(2 * NHEADS * HEADDIM * DSTATE) / 256, 256, 0, stream>>>(stb, cs);
  // 3d. fused Y = Y_diag + Y_off + D*x (MFMA, single bf16 write)
  yoff_kernel<<<2 * NCHUNK * NHEADS, 256, 0, stream>>>(
      xbc, dt2, A_log, G, stb, Dp, Yb);
  // 4a. cast out_proj_w (into dead G region)
  cast_kernel<<<(DMODEL * DINNER + 255) / 256, 256, 0, stream>>>(
      out_proj_w, w2_bf, DMODEL * DINNER, DMODEL * DINNER);
  // 4b. fd = x_og @ fc_D_w^T + D
  fc_kernel<<<L_SEQ / 16, 256, 0, stream>>>(xbc, fc_D_w, Dp, fd);
  // 5. combine + gate + RMSNorm
  combine_kernel<<<L_SEQ, 256, 0, stream>>>(Yb, xbc, zx, fd, norm_w, yn);
  // 6. out_proj (MFMA)
  gemm_mfma<float><<<dim3(DMODEL / 128, L_SEQ / 128), 256, 0, stream>>>(
      yn, DINNER, w2_bf, DINNER, out, DMODEL, DMODEL, DINNER);
}

// Round 11
// 413.468 us; speedup vs baseline: 5.9995x; 1.0739x over previous
//
#include <hip/hip_runtime.h>
#include <hip/hip_bf16.h>
#include <math.h>

// ---------------- problem constants ----------------
#define L_SEQ   4096
#define DMODEL  1024
#define DINNER  2048
#define NHEADS  32
#define HEADDIM 64
#define DSTATE  128
#define NCHUNK  32
#define CHUNKL  128
#define CONVDIM 2560
#define DPROJ   4672   // 2*DINNER + 2*(2*DSTATE) + 2*NHEADS
#define NPAD1   4736   // DPROJ padded to multiple of 128 for MFMA gemm

typedef __hip_bfloat16 bf16;
__device__ __forceinline__ float b2f(bf16 x) { return __bfloat162float(x); }
__device__ __forceinline__ bf16 f2b(float x) { return __float2bfloat16(x); }
__device__ __forceinline__ float sh2f(short s) {
  return __uint_as_float(((unsigned int)(unsigned short)s) << 16);
}
__device__ __forceinline__ short f2bs(float x) {
  bf16 t = __float2bfloat16(x);
  return *reinterpret_cast<short*>(&t);
}

typedef __attribute__((ext_vector_type(8))) short bf16x8v;
typedef __attribute__((ext_vector_type(4))) float f32x4v;

__device__ __forceinline__ float dot8(bf16x8v x, float4 w0, float4 w1) {
  return sh2f(x[0]) * w0.x + sh2f(x[1]) * w0.y + sh2f(x[2]) * w0.z + sh2f(x[3]) * w0.w +
         sh2f(x[4]) * w1.x + sh2f(x[5]) * w1.y + sh2f(x[6]) * w1.z + sh2f(x[7]) * w1.w;
}

// zxbcdt column layout: [0,2048) = z ; [2048,4608) = xBC ; [4608,4672) = dt raw
// xBC_conv channel layout: [0,2048) = x ; fw B = [2048,2176) C = [2176,2304)
//                          bw B = [2304,2432) C = [2432,2560)  (bw streams time-flipped)

// ---------------- f32 -> bf16 cast (dst beyond n_src zero-filled) ----------------
__global__ __launch_bounds__(256) void cast_kernel(
    const float* __restrict__ src, bf16* __restrict__ dst, int n_src, int n_tot) {
  int i = blockIdx.x * 256 + threadIdx.x;
  if (i < n_tot) dst[i] = (i < n_src) ? f2b(src[i]) : f2b(0.f);
}

// ---------------- MFMA GEMM: C[m,n] = sum_k A[m,k]*B[n,k], bf16 in, f32 acc ----------------
// 1-D grid with XCD-aware swizzle: XCD (bid&7, dispatch round-robin) owns m-stripes
// {k, k+8, ...} (A tiles resident in its private L2) and sweeps n. gridM % 8 == 0.
template <typename TC>
__global__ __launch_bounds__(256) void gemm_mfma(
    const bf16* __restrict__ A, int lda,
    const bf16* __restrict__ B, int ldb,
    TC* __restrict__ C, int ldc,
    int N, int K, int gridM) {
  __shared__ short As[128][32];
  __shared__ short Bs[128][32];
  int tid = threadIdx.x;
  int lane = tid & 63;
  int w = tid >> 6;            // wave 0..3
  int wr = w >> 1, wc = w & 1; // 2x2 wave grid
  int bid = blockIdx.x;
  int mst = gridM >> 3;        // m-stripes per XCD
  int xk = bid & 7, q = bid >> 3;
  int bm = (xk + 8 * (q % mst)) * 128;
  int bn = (q / mst) * 128;
  f32x4v acc[4][4];
#pragma unroll
  for (int i = 0; i < 4; i++)
#pragma unroll
    for (int j = 0; j < 4; j++) acc[i][j] = (f32x4v){0.f, 0.f, 0.f, 0.f};

  const bf16* Ab = A + (size_t)(bm + w * 32 + (lane >> 2)) * lda + (lane & 3) * 8;
  const bf16* Bb = B + (size_t)(bn + w * 32 + (lane >> 2)) * ldb + (lane & 3) * 8;

  for (int k0 = 0; k0 < K; k0 += 32) {
    __builtin_amdgcn_global_load_lds(
        (const __attribute__((address_space(1))) void*)(Ab + k0),
        (__attribute__((address_space(3))) void*)&As[w * 32][0], 16, 0, 0);
    __builtin_amdgcn_global_load_lds(
        (const __attribute__((address_space(1))) void*)(Ab + (size_t)16 * lda + k0),
        (__attribute__((address_space(3))) void*)&As[w * 32 + 16][0], 16, 0, 0);
    __builtin_amdgcn_global_load_lds(
        (const __attribute__((address_space(1))) void*)(Bb + k0),
        (__attribute__((address_space(3))) void*)&Bs[w * 32][0], 16, 0, 0);
    __builtin_amdgcn_global_load_lds(
        (const __attribute__((address_space(1))) void*)(Bb + (size_t)16 * ldb + k0),
        (__attribute__((address_space(3))) void*)&Bs[w * 32 + 16][0], 16, 0, 0);
    __syncthreads();
    bf16x8v af[4], bv[4];
#pragma unroll
    for (int i = 0; i < 4; i++)
      af[i] = *(const bf16x8v*)&As[wr * 64 + i * 16 + (lane & 15)][(lane >> 4) * 8];
#pragma unroll
    for (int j = 0; j < 4; j++)
      bv[j] = *(const bf16x8v*)&Bs[wc * 64 + j * 16 + (lane & 15)][(lane >> 4) * 8];
#pragma unroll
    for (int i = 0; i < 4; i++)
#pragma unroll
      for (int j = 0; j < 4; j++)
        acc[i][j] = __builtin_amdgcn_mfma_f32_16x16x32_bf16(af[i], bv[j], acc[i][j], 0, 0, 0);
    __syncthreads();
  }
  int quad = lane >> 4;
  int cn = lane & 15;
#pragma unroll
  for (int i = 0; i < 4; i++) {
#pragma unroll
    for (int j = 0; j < 4; j++) {
      int col = bn + wc * 64 + j * 16 + cn;
      if (col < N) {
#pragma unroll
        for (int r = 0; r < 4; r++) {
          int row = bm + wr * 64 + i * 16 + quad * 4 + r;
          float v = acc[i][j][r];
          if constexpr (sizeof(TC) == 2) C[(size_t)row * ldc + col] = f2b(v);
          else                           C[(size_t)row * ldc + col] = v;
        }
      }
    }
  }
}

// ---------------- fc_D: fd[t][h] = sum_k x[t,k]*W[h,k] + D[h] ----------------
__global__ __launch_bounds__(256) void fc_kernel(
    const bf16* __restrict__ xbc, const float* __restrict__ Wf,
    const float* __restrict__ Dp, float* __restrict__ fd) {
  int lane = threadIdx.x & 63;
  int w = threadIdx.x >> 6;
  int t0 = (blockIdx.x * 4 + w) * 4;
  int h = lane & 31;
  int g = lane >> 5;                 // k-half
  const float* wr = Wf + (size_t)h * DINNER + g * 1024;
  const bf16* xr = xbc + (size_t)t0 * CONVDIM + g * 1024;
  float a0 = 0.f, a1 = 0.f, a2 = 0.f, a3 = 0.f;
  for (int k = 0; k < 1024; k += 8) {
    float4 w0 = *(const float4*)(wr + k);
    float4 w1 = *(const float4*)(wr + k + 4);
    bf16x8v x0 = *(const bf16x8v*)(xr + k);
    bf16x8v x1 = *(const bf16x8v*)(xr + CONVDIM + k);
    bf16x8v x2 = *(const bf16x8v*)(xr + 2 * CONVDIM + k);
    bf16x8v x3 = *(const bf16x8v*)(xr + 3 * CONVDIM + k);
    a0 += dot8(x0, w0, w1);
    a1 += dot8(x1, w0, w1);
    a2 += dot8(x2, w0, w1);
    a3 += dot8(x3, w0, w1);
  }
  a0 += __shfl_down(a0, 32);
  a1 += __shfl_down(a1, 32);
  a2 += __shfl_down(a2, 32);
  a3 += __shfl_down(a3, 32);
  if (lane < 32) {
    float d = Dp[h];
    fd[(t0 + 0) * NHEADS + h] = a0 + d;
    fd[(t0 + 1) * NHEADS + h] = a1 + d;
    fd[(t0 + 2) * NHEADS + h] = a2 + d;
    fd[(t0 + 3) * NHEADS + h] = a3 + d;
  }
}

// ---------------- conv (depthwise causal, k=4) + SiLU: 4 t per thread ----------------
__global__ __launch_bounds__(256) void conv_silu_kernel(
    const bf16* __restrict__ zx, const float* __restrict__ conv_w,
    const float* __restrict__ conv_b, bf16* __restrict__ xbc) {
  int idx = blockIdx.x * 256 + threadIdx.x;   // (L_SEQ/4)*CONVDIM
  if (idx >= (L_SEQ / 4) * CONVDIM) return;
  int ch = idx % CONVDIM;
  int t0 = (idx / CONVDIM) * 4;
  const bf16* col = zx + DINNER + ch;         // xBC region
  float w0 = conv_w[ch * 4 + 0], w1 = conv_w[ch * 4 + 1];
  float w2 = conv_w[ch * 4 + 2], w3 = conv_w[ch * 4 + 3];
  float bsv = conv_b[ch];
  float x[7];
#pragma unroll
  for (int i = 0; i < 7; i++) {
    int t = t0 - 3 + i;
    x[i] = (t >= 0) ? b2f(col[(size_t)t * DPROJ]) : 0.f;
  }
#pragma unroll
  for (int j = 0; j < 4; j++) {
    float acc = bsv + w0 * x[j] + w1 * x[j + 1] + w2 * x[j + 2] + w3 * x[j + 3];
    xbc[(size_t)(t0 + j) * CONVDIM + ch] = f2b(acc / (1.f + __expf(-acc)));
  }
}

// ---------------- dt: split fw/bw (bw time-flipped), softplus(dt + bias) ----------------
__global__ __launch_bounds__(256) void dt_kernel(
    const bf16* __restrict__ zx, const float* __restrict__ dt_bias,
    float* __restrict__ dt2) {
  int idx = blockIdx.x * 256 + threadIdx.x;   // 2*L_SEQ*NHEADS
  if (idx >= 2 * L_SEQ * NHEADS) return;
  int h = idx % NHEADS;
  int t = (idx / NHEADS) % L_SEQ;
  int b = idx / (NHEADS * L_SEQ);
  float v;
  if (b == 0) v = b2f(zx[(size_t)t * DPROJ + 4608 + h]);
  else        v = b2f(zx[(size_t)(L_SEQ - 1 - t) * DPROJ + 4608 + NHEADS + h]);
  v += dt_bias[h];
  dt2[idx] = (v > 20.f) ? v : log1pf(expf(v));
}

// ---------------- G[b,c,l,s] = sum_n C[l,n]*B[s,n]  (MFMA, bf16 out) ----------------
__global__ __launch_bounds__(256) void gmat_kernel(
    const bf16* __restrict__ xbc, bf16* __restrict__ G) {
  __shared__ bf16 Cs[128][136];  // C[l][n]  34 KB
  __shared__ bf16 Bs[128][136];  // B[s][n]  34 KB
  int bc = blockIdx.x;            // b*32 + c
  int b = bc / NCHUNK, c = bc % NCHUNK;
  int tid = threadIdx.x;
  int lane = tid & 63;
  int w = tid >> 6;
  int bofs = b ? 2304 : 2048;
  int cofs = b ? 2432 : 2176;
  for (int o = tid; o < CHUNKL * DSTATE / 8; o += 256) {   // 2048 vecs
    int s = o >> 4;
    int n8 = (o & 15) * 8;
    int t = b ? (L_SEQ - 1 - (c * CHUNKL + s)) : (c * CHUNKL + s);
    const bf16* row = xbc + (size_t)t * CONVDIM;
    *(bf16x8v*)&Bs[s][n8] = *(const bf16x8v*)&row[bofs + n8];
    *(bf16x8v*)&Cs[s][n8] = *(const bf16x8v*)&row[cofs + n8];
  }
  __syncthreads();
  f32x4v acc[2][8];
#pragma unroll
  for (int i = 0; i < 2; i++)
#pragma unroll
    for (int j = 0; j < 8; j++) acc[i][j] = (f32x4v){0.f, 0.f, 0.f, 0.f};
#pragma unroll
  for (int k0 = 0; k0 < 128; k0 += 32) {
    bf16x8v a0 = *(const bf16x8v*)&Cs[w * 32 + (lane & 15)][(lane >> 4) * 8 + k0];
    bf16x8v a1 = *(const bf16x8v*)&Cs[w * 32 + 16 + (lane & 15)][(lane >> 4) * 8 + k0];
#pragma unroll
    for (int j = 0; j < 8; j++) {
      bf16x8v bv = *(const bf16x8v*)&Bs[j * 16 + (lane & 15)][(lane >> 4) * 8 + k0];
      acc[0][j] = __builtin_amdgcn_mfma_f32_16x16x32_bf16(a0, bv, acc[0][j], 0, 0, 0);
      acc[1][j] = __builtin_amdgcn_mfma_f32_16x16x32_bf16(a1, bv, acc[1][j], 0, 0, 0);
    }
  }
  int quad = lane >> 4, cn = lane & 15;
  bf16* Gb = G + (size_t)bc * CHUNKL * CHUNKL;
#pragma unroll
  for (int i = 0; i < 2; i++)
#pragma unroll
    for (int j = 0; j < 8; j++)
#pragma unroll
      for (int r = 0; r < 4; r++) {
        int l = w * 32 + i * 16 + quad * 4 + r;
        int s = j * 16 + cn;
        Gb[l * CHUNKL + s] = f2b(acc[i][j][r]);
      }
}

// ---------------- per-(b,c,h): chunk states only (MFMA, bf16 out) ----------------
__global__ __launch_bounds__(256) void chunk_kernel(
    const bf16* __restrict__ xbc, const float* __restrict__ dt2,
    const float* __restrict__ A_log,
    bf16* __restrict__ states, float* __restrict__ csum) {
  int gid = blockIdx.x;           // (b*32+c)*32 + h
  int h = gid % NHEADS;
  int bc = gid / NHEADS;
  int c = bc % NCHUNK, b = bc / NCHUNK;
  int tid = threadIdx.x;
  int lane = tid & 63;
  int w = tid >> 6;
  __shared__ bf16 BdT[128][136];  // [n][l] = B[l][n]*decay[l]  34 KB
  __shared__ bf16 xdtT[64][136];  // [p][s] = x[s,p]*dt[s]      17 KB
  __shared__ float acs[CHUNKL];
  __shared__ float dtl[CHUNKL];
  __shared__ float decays[CHUNKL];
  if (tid < CHUNKL)
    dtl[tid] = dt2[((size_t)b * L_SEQ + c * CHUNKL + tid) * NHEADS + h];
  __syncthreads();
  if (tid == 0) {
    float Ah = -__expf(A_log[h]);
    float s = 0.f;
    for (int l = 0; l < CHUNKL; l++) { s += Ah * dtl[l]; acs[l] = s; }
    csum[gid] = __expf(s);        // stored pre-exponentiated for scan
  }
  __syncthreads();
  if (tid < CHUNKL) decays[tid] = __expf(acs[CHUNKL - 1] - acs[tid]);
  // xdtT[p][s] staging: lane->s (t-strided 16B loads), conflict-free scatter
  for (int o = tid; o < CHUNKL * HEADDIM / 8; o += 256) {   // 1024 vecs
    int s = o & 127;
    int p8 = (o >> 7) * 8;
    int t = b ? (L_SEQ - 1 - (c * CHUNKL + s)) : (c * CHUNKL + s);
    bf16x8v xv = *(const bf16x8v*)&xbc[(size_t)t * CONVDIM + h * HEADDIM + p8];
    float d = dtl[s];
#pragma unroll
    for (int j = 0; j < 8; j++) xdtT[p8 + j][s] = f2b(sh2f(xv[j]) * d);
  }
  __syncthreads();   // decays ready
  // BdT[n][l] staging: lane->l, conflict-free scatter
  for (int o = tid; o < CHUNKL * CHUNKL / 8; o += 256) {    // 2048 vecs
    int l = o & 127;
    int n8 = (o >> 7) * 8;
    int t = b ? (L_SEQ - 1 - (c * CHUNKL + l)) : (c * CHUNKL + l);
    bf16x8v bv = *(const bf16x8v*)&xbc[(size_t)t * CONVDIM + (b ? 2304 : 2048) + n8];
    float d = decays[l];
#pragma unroll
    for (int j = 0; j < 8; j++) BdT[n8 + j][l] = f2b(sh2f(bv[j]) * d);
  }
  __syncthreads();
  // states[p][n] = sum_l xdtT[p][l]*BdT[n][l]; wave w -> p rows [16w,16w+16)
  f32x4v accS[8];
#pragma unroll
  for (int j = 0; j < 8; j++) accS[j] = (f32x4v){0.f, 0.f, 0.f, 0.f};
#pragma unroll
  for (int k0 = 0; k0 < 128; k0 += 32) {
    bf16x8v av = *(const bf16x8v*)&xdtT[w * 16 + (lane & 15)][(lane >> 4) * 8 + k0];
#pragma unroll
    for (int j = 0; j < 8; j++) {
      bf16x8v bv = *(const bf16x8v*)&BdT[j * 16 + (lane & 15)][(lane >> 4) * 8 + k0];
      accS[j] = __builtin_amdgcn_mfma_f32_16x16x32_bf16(av, bv, accS[j], 0, 0, 0);
    }
  }
  int quad = lane >> 4, cn = lane & 15;
  bf16* st = states + (size_t)gid * (HEADDIM * DSTATE);
#pragma unroll
  for (int j = 0; j < 8; j++)
#pragma unroll
    for (int r = 0; r < 4; r++) {
      int p = w * 16 + quad * 4 + r;
      int n = j * 16 + cn;
      st[p * DSTATE + n] = f2b(accS[j][r]);
    }
}

// ---------------- inter-chunk scan (in place, bf16; csum pre-exponentiated) ----------------
__global__ __launch_bounds__(256) void scan_kernel(
    bf16* __restrict__ states, const float* __restrict__ csum) {
  int idx = blockIdx.x * 256 + threadIdx.x;  // 2*NHEADS*HEADDIM*DSTATE
  int n = idx % DSTATE;
  int p = (idx / DSTATE) % HEADDIM;
  int h = (idx / (DSTATE * HEADDIM)) % NHEADS;
  int b = idx / (DSTATE * HEADDIM * NHEADS);
  float S = 0.f;
  for (int c = 0; c < NCHUNK; c++) {
    int gid = (b * NCHUNK + c) * NHEADS + h;
    size_t off = (size_t)gid * (HEADDIM * DSTATE) + p * DSTATE + n;
    float tmp = b2f(states[off]);
    states[off] = f2b(S);
    S = csum[gid] * S + tmp;
  }
}

// ---------------- fused Y = Y_diag + Y_off + D*x (MFMA, single bf16 write) ----------------
__global__ __launch_bounds__(256) void yoff_kernel(
    const bf16* __restrict__ xbc, const float* __restrict__ dt2,
    const float* __restrict__ A_log, const bf16* __restrict__ G,
    const bf16* __restrict__ states, const float* __restrict__ Dp,
    bf16* __restrict__ Y) {
  int gid = blockIdx.x;
  int h = gid % NHEADS;
  int bc = gid / NHEADS;
  int c = bc % NCHUNK, b = bc / NCHUNK;
  int tid = threadIdx.x;
  int lane = tid & 63;
  int w = tid >> 6;
  __shared__ bf16 WB[128][136];   // 34 KB (W, then Ce)
  __shared__ bf16 SX[64][136];    // 17 KB (xdtT, then St)
  __shared__ float acs[CHUNKL];
  __shared__ float dtl[CHUNKL];
  __shared__ float eAl[CHUNKL];
  if (tid < CHUNKL)
    dtl[tid] = dt2[((size_t)b * L_SEQ + c * CHUNKL + tid) * NHEADS + h];
  __syncthreads();
  if (tid == 0) {
    float Ah = -__expf(A_log[h]);
    float s = 0.f;
    for (int l = 0; l < CHUNKL; l++) { s += Ah * dtl[l]; acs[l] = s; }
  }
  __syncthreads();
  if (tid < CHUNKL) eAl[tid] = __expf(acs[tid]);   // <= 1
  // SX <- xdtT[p][s]: lane->s, conflict-free scatter
  for (int o = tid; o < CHUNKL * HEADDIM / 8; o += 256) {   // 1024 vecs
    int s = o & 127;
    int p8 = (o >> 7) * 8;
    int t = b ? (L_SEQ - 1 - (c * CHUNKL + s)) : (c * CHUNKL + s);
    bf16x8v xv = *(const bf16x8v*)&xbc[(size_t)t * CONVDIM + h * HEADDIM + p8];
    float d = dtl[s];
#pragma unroll
    for (int j = 0; j < 8; j++) SX[p8 + j][s] = f2b(sh2f(xv[j]) * d);
  }
  // WB <- W[l][s] = G*exp(acs[l]-acs[s]) (s<=l): vectorized, b128 writes
  {
    const bf16* Gb = G + (size_t)bc * CHUNKL * CHUNKL;
    for (int o = tid; o < CHUNKL * CHUNKL / 8; o += 256) {  // 2048 vecs
      int l = o >> 4;
      int s8 = (o & 15) * 8;
      bf16x8v g = *(const bf16x8v*)&Gb[l * CHUNKL + s8];
      float al = acs[l];
      bf16x8v wv;
#pragma unroll
      for (int j = 0; j < 8; j++) {
        int s = s8 + j;
        float e = (s <= l) ? sh2f(g[j]) * __expf(al - acs[s]) : 0.f;
        wv[j] = f2bs(e);
      }
      *(bf16x8v*)&WB[l][s8] = wv;
    }
  }
  __syncthreads();
  f32x4v accY[2][4];
#pragma unroll
  for (int i = 0; i < 2; i++)
#pragma unroll
    for (int j = 0; j < 4; j++) accY[i][j] = (f32x4v){0.f, 0.f, 0.f, 0.f};
  // Y_diag: A=W rows [32w,32w+32), B=xdtT p-tiles, k=s
#pragma unroll
  for (int k0 = 0; k0 < 128; k0 += 32) {
    bf16x8v a0 = *(const bf16x8v*)&WB[w * 32 + (lane & 15)][(lane >> 4) * 8 + k0];
    bf16x8v a1 = *(const bf16x8v*)&WB[w * 32 + 16 + (lane & 15)][(lane >> 4) * 8 + k0];
#pragma unroll
    for (int j = 0; j < 4; j++) {
      bf16x8v bv = *(const bf16x8v*)&SX[j * 16 + (lane & 15)][(lane >> 4) * 8 + k0];
      accY[0][j] = __builtin_amdgcn_mfma_f32_16x16x32_bf16(a0, bv, accY[0][j], 0, 0, 0);
      accY[1][j] = __builtin_amdgcn_mfma_f32_16x16x32_bf16(a1, bv, accY[1][j], 0, 0, 0);
    }
  }
  __syncthreads();   // all phase-1 LDS reads done
  // restage: WB <- Ce[l][n] (row-contiguous, b128), SX <- St (16B copies)
  {
    int cofs = b ? 2432 : 2176;
    for (int o = tid; o < CHUNKL * DSTATE / 8; o += 256) {  // 2048 vecs
      int l = o >> 4;
      int n8 = (o & 15) * 8;
      int t = b ? (L_SEQ - 1 - (c * CHUNKL + l)) : (c * CHUNKL + l);
      bf16x8v cv = *(const bf16x8v*)&xbc[(size_t)t * CONVDIM + cofs + n8];
      float e = eAl[l];
      bf16x8v ov;
#pragma unroll
      for (int j = 0; j < 8; j++) ov[j] = f2bs(sh2f(cv[j]) * e);
      *(bf16x8v*)&WB[l][n8] = ov;
    }
    const bf16* stp = states + (size_t)gid * (HEADDIM * DSTATE);
    for (int o = tid; o < HEADDIM * DSTATE / 8; o += 256) { // 1024 vecs
      int p = o >> 4;
      int n8 = (o & 15) * 8;
      *(bf16x8v*)&SX[p][n8] = *(const bf16x8v*)&stp[o * 8];
    }
  }
  __syncthreads();
  // Y_off: A=Ce rows, B=St p-tiles, k=n; accumulate into same accY
#pragma unroll
  for (int k0 = 0; k0 < 128; k0 += 32) {
    bf16x8v a0 = *(const bf16x8v*)&WB[w * 32 + (lane & 15)][(lane >> 4) * 8 + k0];
    bf16x8v a1 = *(const bf16x8v*)&WB[w * 32 + 16 + (lane & 15)][(lane >> 4) * 8 + k0];
#pragma unroll
    for (int j = 0; j < 4; j++) {
      bf16x8v bv = *(const bf16x8v*)&SX[j * 16 + (lane & 15)][(lane >> 4) * 8 + k0];
      accY[0][j] = __builtin_amdgcn_mfma_f32_16x16x32_bf16(a0, bv, accY[0][j], 0, 0, 0);
      accY[1][j] = __builtin_amdgcn_mfma_f32_16x16x32_bf16(a1, bv, accY[1][j], 0, 0, 0);
    }
  }
  int quad = lane >> 4, cn = lane & 15;
  float Dh = Dp[h];
#pragma unroll
  for (int i = 0; i < 2; i++)
#pragma unroll
    for (int j = 0; j < 4; j++)
#pragma unroll
      for (int r = 0; r < 4; r++) {
        int l = w * 32 + i * 16 + quad * 4 + r;
        int p = j * 16 + cn;
        int t = b ? (L_SEQ - 1 - (c * CHUNKL + l)) : (c * CHUNKL + l);
        float xv = b2f(xbc[(size_t)t * CONVDIM + h * HEADDIM + p]);
        size_t yi = ((size_t)b * L_SEQ + c * CHUNKL + l) * DINNER + h * HEADDIM + p;
        Y[yi] = f2b(accY[i][j][r] + xv * Dh);
      }
}

// ---------------- combine: shift, flip, +x*fd, gate, RMSNorm (vectorized) ----------------
__global__ __launch_bounds__(256) void combine_kernel(
    const bf16* __restrict__ Y, const bf16* __restrict__ xbc,
    const bf16* __restrict__ zx, const float* __restrict__ fd,
    const float* __restrict__ norm_w, bf16* __restrict__ yn) {
  int t = blockIdx.x;
  int tid = threadIdx.x;
  int j8 = tid * 8;
  float yf[8], yb[8];
#pragma unroll
  for (int j = 0; j < 8; j++) { yf[j] = 0.f; yb[j] = 0.f; }
  if (t >= 1) {
    bf16x8v v = *(const bf16x8v*)&Y[(size_t)(t - 1) * DINNER + j8];
#pragma unroll
    for (int j = 0; j < 8; j++) yf[j] = sh2f(v[j]);
  }
  if (t <= L_SEQ - 2) {
    bf16x8v v = *(const bf16x8v*)&Y[((size_t)L_SEQ + (L_SEQ - 2 - t)) * DINNER + j8];
#pragma unroll
    for (int j = 0; j < 8; j++) yb[j] = sh2f(v[j]);
  }
  bf16x8v xogv = *(const bf16x8v*)&xbc[(size_t)t * CONVDIM + j8];
  bf16x8v zv = *(const bf16x8v*)&zx[(size_t)t * DPROJ + j8];
  float fdv = fd[t * NHEADS + (j8 >> 6)];
  float yg[8];
  float ss = 0.f;
#pragma unroll
  for (int j = 0; j < 8; j++) {
    float y = yf[j] + yb[j] + sh2f(xogv[j]) * fdv;
    float z = sh2f(zv[j]);
    float g = y * (z / (1.f + __expf(-z)));
    yg[j] = g;
    ss += g * g;
  }
#pragma unroll
  for (int off = 32; off > 0; off >>= 1) ss += __shfl_down(ss, off);
  __shared__ float red[4];
  if ((tid & 63) == 0) red[tid >> 6] = ss;
  __syncthreads();
  float tot = red[0] + red[1] + red[2] + red[3];
  float scale = rsqrtf(tot / (float)DINNER + 1e-5f);
  float4 nw0 = *(const float4*)&norm_w[j8];
  float4 nw1 = *(const float4*)&norm_w[j8 + 4];
  bf16x8v ov;
  ov[0] = f2bs(yg[0] * scale * nw0.x);
  ov[1] = f2bs(yg[1] * scale * nw0.y);
  ov[2] = f2bs(yg[2] * scale * nw0.z);
  ov[3] = f2bs(yg[3] * scale * nw0.w);
  ov[4] = f2bs(yg[4] * scale * nw1.x);
  ov[5] = f2bs(yg[5] * scale * nw1.y);
  ov[6] = f2bs(yg[6] * scale * nw1.z);
  ov[7] = f2bs(yg[7] * scale * nw1.w);
  *(bf16x8v*)&yn[(size_t)t * DINNER + j8] = ov;
}

// ---------------- launch ----------------
extern "C" void kernel_launch(void* const* d_in, const int* in_sizes, int n_in,
                              void* d_out, int out_size, void* d_ws, size_t ws_size,
                              hipStream_t stream) {
  const float* u         = (const float*)d_in[0];
  const float* in_proj_w = (const float*)d_in[1];
  const float* conv_w    = (const float*)d_in[2];
  const float* conv_b    = (const float*)d_in[3];
  const float* dt_bias   = (const float*)d_in[4];
  const float* A_log     = (const float*)d_in[5];
  const float* Dp        = (const float*)d_in[6];
  const float* fc_D_w    = (const float*)d_in[7];
  const float* norm_w    = (const float*)d_in[8];
  const float* out_proj_w= (const float*)d_in[9];
  float* out = (float*)d_out;

  char* base = (char*)d_ws;
  bf16*  zx  = (bf16*)base;  base += (size_t)L_SEQ * DPROJ * 2;                    // 38.3 MB
  bf16*  xbc = (bf16*)base;  base += (size_t)L_SEQ * CONVDIM * 2;                  // 21.0 MB
  float* dt2 = (float*)base; base += (size_t)2 * L_SEQ * NHEADS * 4;               //  1.0 MB
  bf16*  G   = (bf16*)base;  base += (size_t)2 * NCHUNK * CHUNKL * CHUNKL * 4;     //  4.2 MB region
  bf16*  Yb  = (bf16*)base;  base += (size_t)2 * L_SEQ * DINNER * 4;               // 67.1 MB region
  bf16*  stb = (bf16*)base;  base += (size_t)2 * NCHUNK * NHEADS * HEADDIM * DSTATE * 4; // 67.1 MB region
  float* cs  = (float*)base; base += (size_t)2 * NCHUNK * NHEADS * 4;              //  8 KB
  // aliases into dead regions:
  bf16*  u_bf   = (bf16*)Yb;                          // 8.4 MB   (Yb live only after yoff)
  bf16*  w1p_bf = (bf16*)((char*)Yb + 9437184);       // 9.7 MB   (padded in_proj_w)
  bf16*  w2_bf  = (bf16*)G;                           // 4.2 MB   (G dead after yoff)
  bf16*  yn     = (bf16*)stb;                         // 16.8 MB  (stb dead after yoff)
  float* fd     = (float*)((char*)stb + 33554432);    //  0.5 MB

  // 0. casts for MFMA gemm1
  cast_kernel<<<(L_SEQ * DMODEL + 255) / 256, 256, 0, stream>>>(
      u, u_bf, L_SEQ * DMODEL, L_SEQ * DMODEL);
  cast_kernel<<<(NPAD1 * DMODEL + 255) / 256, 256, 0, stream>>>(
      in_proj_w, w1p_bf, DPROJ * DMODEL, NPAD1 * DMODEL);
  // 1. in_proj: zx = u @ in_proj_w^T  (MFMA, XCD-swizzled 1-D grid)
  gemm_mfma<bf16><<<(L_SEQ / 128) * (NPAD1 / 128), 256, 0, stream>>>(
      u_bf, DMODEL, w1p_bf, DMODEL, zx, DPROJ, DPROJ, DMODEL, L_SEQ / 128);
  // 2. conv + silu (4 t per thread)
  conv_silu_kernel<<<((L_SEQ / 4) * CONVDIM + 255) / 256, 256, 0, stream>>>(
      zx, conv_w, conv_b, xbc);
  // 2b. dt
  dt_kernel<<<(2 * L_SEQ * NHEADS + 255) / 256, 256, 0, stream>>>(
      zx, dt_bias, dt2);
  // 3a. G = C B^T per (b,c)  (MFMA, bf16)
  gmat_kernel<<<2 * NCHUNK, 256, 0, stream>>>(xbc, G);
  // 3b. chunk states (MFMA, bf16)
  chunk_kernel<<<2 * NCHUNK * NHEADS, 256, 0, stream>>>(
      xbc, dt2, A_log, stb, cs);
  // 3c. inter-chunk scan (bf16, exp-free inner loop)
  scan_kernel<<<(2 * NHEADS * HEADDIM * DSTATE) / 256, 256, 0, stream>>>(stb, cs);
  // 3d. fused Y = Y_diag + Y_off + D*x (MFMA, single bf16 write)
  yoff_kernel<<<2 * NCHUNK * NHEADS, 256, 0, stream>>>(
      xbc, dt2, A_log, G, stb, Dp, Yb);
  // 4a. cast out_proj_w (into dead G region)
  cast_kernel<<<(DMODEL * DINNER + 255) / 256, 256, 0, stream>>>(
      out_proj_w, w2_bf, DMODEL * DINNER, DMODEL * DINNER);
  // 4b. fd = x_og @ fc_D_w^T + D
  fc_kernel<<<L_SEQ / 16, 256, 0, stream>>>(xbc, fc_D_w, Dp, fd);
  // 5. combine + gate + RMSNorm
  combine_kernel<<<L_SEQ, 256, 0, stream>>>(Yb, xbc, zx, fd, norm_w, yn);
  // 6. out_proj (MFMA, XCD-swizzled 1-D grid)
  gemm_mfma<float><<<(L_SEQ / 128) * (DMODEL / 128), 256, 0, stream>>>(
      yn, DINNER, w2_bf, DINNER, out, DMODEL, DMODEL, DINNER, L_SEQ / 128);
}

// Round 12
// 411.881 us; speedup vs baseline: 6.0226x; 1.0039x over previous
//
#include <hip/hip_runtime.h>
#include <hip/hip_bf16.h>
#include <math.h>

// ---------------- problem constants ----------------
#define L_SEQ   4096
#define DMODEL  1024
#define DINNER  2048
#define NHEADS  32
#define HEADDIM 64
#define DSTATE  128
#define NCHUNK  32
#define CHUNKL  128
#define CONVDIM 2560
#define DPROJ   4672   // 2*DINNER + 2*(2*DSTATE) + 2*NHEADS
#define NPAD1   4736   // DPROJ padded to multiple of 128 for MFMA gemm

typedef __hip_bfloat16 bf16;
__device__ __forceinline__ float b2f(bf16 x) { return __bfloat162float(x); }
__device__ __forceinline__ bf16 f2b(float x) { return __float2bfloat16(x); }
__device__ __forceinline__ float sh2f(short s) {
  return __uint_as_float(((unsigned int)(unsigned short)s) << 16);
}
__device__ __forceinline__ short f2bs(float x) {
  bf16 t = __float2bfloat16(x);
  return *reinterpret_cast<short*>(&t);
}

typedef __attribute__((ext_vector_type(8))) short bf16x8v;
typedef __attribute__((ext_vector_type(4))) float f32x4v;

__device__ __forceinline__ float dot8(bf16x8v x, float4 w0, float4 w1) {
  return sh2f(x[0]) * w0.x + sh2f(x[1]) * w0.y + sh2f(x[2]) * w0.z + sh2f(x[3]) * w0.w +
         sh2f(x[4]) * w1.x + sh2f(x[5]) * w1.y + sh2f(x[6]) * w1.z + sh2f(x[7]) * w1.w;
}

// zxbcdt column layout: [0,2048) = z ; [2048,4608) = xBC ; [4608,4672) = dt raw
// xBC_conv channel layout: [0,2048) = x ; fw B = [2048,2176) C = [2176,2304)
//                          bw B = [2304,2432) C = [2432,2560)  (bw streams time-flipped)

// ---------------- fused casts: u -> bf16 and in_proj_w -> bf16 (zero-padded) ----------------
__global__ __launch_bounds__(256) void cast2_kernel(
    const float* __restrict__ u, const float* __restrict__ w1,
    bf16* __restrict__ u_bf, bf16* __restrict__ w1_bf) {
  const int NU = (L_SEQ * DMODEL) / 256;   // 16384 blocks
  int bid = blockIdx.x;
  if (bid < NU) {
    int i = bid * 256 + threadIdx.x;
    u_bf[i] = f2b(u[i]);
  } else {
    int i = (bid - NU) * 256 + threadIdx.x;
    w1_bf[i] = (i < DPROJ * DMODEL) ? f2b(w1[i]) : f2b(0.f);
  }
}

// ---------------- f32 -> bf16 cast ----------------
__global__ __launch_bounds__(256) void cast_kernel(
    const float* __restrict__ src, bf16* __restrict__ dst, int n_src, int n_tot) {
  int i = blockIdx.x * 256 + threadIdx.x;
  if (i < n_tot) dst[i] = (i < n_src) ? f2b(src[i]) : f2b(0.f);
}

// ---------------- MFMA GEMM: C[m,n] = sum_k A[m,k]*B[n,k], bf16 in, f32 acc ----------------
// swz=1: XCD-aware swizzle (bid&7 = XCD owns m-stripes, sweeps n). swz=0: n-fastest
// plain mapping (R10-measured best for the large in_proj shape).
template <typename TC>
__global__ __launch_bounds__(256) void gemm_mfma(
    const bf16* __restrict__ A, int lda,
    const bf16* __restrict__ B, int ldb,
    TC* __restrict__ C, int ldc,
    int N, int K, int gridM, int gridN, int swz) {
  __shared__ short As[128][32];
  __shared__ short Bs[128][32];
  int tid = threadIdx.x;
  int lane = tid & 63;
  int w = tid >> 6;            // wave 0..3
  int wr = w >> 1, wc = w & 1; // 2x2 wave grid
  int bid = blockIdx.x;
  int bm, bn;
  if (swz) {
    int mst = gridM >> 3;
    int xk = bid & 7, q = bid >> 3;
    bm = (xk + 8 * (q % mst)) * 128;
    bn = (q / mst) * 128;
  } else {
    bm = (bid / gridN) * 128;
    bn = (bid % gridN) * 128;
  }
  f32x4v acc[4][4];
#pragma unroll
  for (int i = 0; i < 4; i++)
#pragma unroll
    for (int j = 0; j < 4; j++) acc[i][j] = (f32x4v){0.f, 0.f, 0.f, 0.f};

  const bf16* Ab = A + (size_t)(bm + w * 32 + (lane >> 2)) * lda + (lane & 3) * 8;
  const bf16* Bb = B + (size_t)(bn + w * 32 + (lane >> 2)) * ldb + (lane & 3) * 8;

  for (int k0 = 0; k0 < K; k0 += 32) {
    __builtin_amdgcn_global_load_lds(
        (const __attribute__((address_space(1))) void*)(Ab + k0),
        (__attribute__((address_space(3))) void*)&As[w * 32][0], 16, 0, 0);
    __builtin_amdgcn_global_load_lds(
        (const __attribute__((address_space(1))) void*)(Ab + (size_t)16 * lda + k0),
        (__attribute__((address_space(3))) void*)&As[w * 32 + 16][0], 16, 0, 0);
    __builtin_amdgcn_global_load_lds(
        (const __attribute__((address_space(1))) void*)(Bb + k0),
        (__attribute__((address_space(3))) void*)&Bs[w * 32][0], 16, 0, 0);
    __builtin_amdgcn_global_load_lds(
        (const __attribute__((address_space(1))) void*)(Bb + (size_t)16 * ldb + k0),
        (__attribute__((address_space(3))) void*)&Bs[w * 32 + 16][0], 16, 0, 0);
    __syncthreads();
    bf16x8v af[4], bv[4];
#pragma unroll
    for (int i = 0; i < 4; i++)
      af[i] = *(const bf16x8v*)&As[wr * 64 + i * 16 + (lane & 15)][(lane >> 4) * 8];
#pragma unroll
    for (int j = 0; j < 4; j++)
      bv[j] = *(const bf16x8v*)&Bs[wc * 64 + j * 16 + (lane & 15)][(lane >> 4) * 8];
#pragma unroll
    for (int i = 0; i < 4; i++)
#pragma unroll
      for (int j = 0; j < 4; j++)
        acc[i][j] = __builtin_amdgcn_mfma_f32_16x16x32_bf16(af[i], bv[j], acc[i][j], 0, 0, 0);
    __syncthreads();
  }
  int quad = lane >> 4;
  int cn = lane & 15;
#pragma unroll
  for (int i = 0; i < 4; i++) {
#pragma unroll
    for (int j = 0; j < 4; j++) {
      int col = bn + wc * 64 + j * 16 + cn;
      if (col < N) {
#pragma unroll
        for (int r = 0; r < 4; r++) {
          int row = bm + wr * 64 + i * 16 + quad * 4 + r;
          float v = acc[i][j][r];
          if constexpr (sizeof(TC) == 2) C[(size_t)row * ldc + col] = f2b(v);
          else                           C[(size_t)row * ldc + col] = v;
        }
      }
    }
  }
}

// ---------------- fc_D: fd[t][h] = sum_k x[t,k]*W[h,k] + D[h] ----------------
__global__ __launch_bounds__(256) void fc_kernel(
    const bf16* __restrict__ xbc, const float* __restrict__ Wf,
    const float* __restrict__ Dp, float* __restrict__ fd) {
  int lane = threadIdx.x & 63;
  int w = threadIdx.x >> 6;
  int t0 = (blockIdx.x * 4 + w) * 4;
  int h = lane & 31;
  int g = lane >> 5;                 // k-half
  const float* wr = Wf + (size_t)h * DINNER + g * 1024;
  const bf16* xr = xbc + (size_t)t0 * CONVDIM + g * 1024;
  float a0 = 0.f, a1 = 0.f, a2 = 0.f, a3 = 0.f;
  for (int k = 0; k < 1024; k += 8) {
    float4 w0 = *(const float4*)(wr + k);
    float4 w1 = *(const float4*)(wr + k + 4);
    bf16x8v x0 = *(const bf16x8v*)(xr + k);
    bf16x8v x1 = *(const bf16x8v*)(xr + CONVDIM + k);
    bf16x8v x2 = *(const bf16x8v*)(xr + 2 * CONVDIM + k);
    bf16x8v x3 = *(const bf16x8v*)(xr + 3 * CONVDIM + k);
    a0 += dot8(x0, w0, w1);
    a1 += dot8(x1, w0, w1);
    a2 += dot8(x2, w0, w1);
    a3 += dot8(x3, w0, w1);
  }
  a0 += __shfl_down(a0, 32);
  a1 += __shfl_down(a1, 32);
  a2 += __shfl_down(a2, 32);
  a3 += __shfl_down(a3, 32);
  if (lane < 32) {
    float d = Dp[h];
    fd[(t0 + 0) * NHEADS + h] = a0 + d;
    fd[(t0 + 1) * NHEADS + h] = a1 + d;
    fd[(t0 + 2) * NHEADS + h] = a2 + d;
    fd[(t0 + 3) * NHEADS + h] = a3 + d;
  }
}

// ---------------- conv (4 t/thread) + SiLU, with dt softplus folded in ----------------
#define CONV_BLOCKS ((L_SEQ / 4) * CONVDIM / 256)   // 10240
__global__ __launch_bounds__(256) void conv_dt_kernel(
    const bf16* __restrict__ zx, const float* __restrict__ conv_w,
    const float* __restrict__ conv_b, bf16* __restrict__ xbc,
    const float* __restrict__ dt_bias, float* __restrict__ dt2) {
  int bid = blockIdx.x;
  if (bid < CONV_BLOCKS) {
    int idx = bid * 256 + threadIdx.x;
    int ch = idx % CONVDIM;
    int t0 = (idx / CONVDIM) * 4;
    const bf16* col = zx + DINNER + ch;
    float w0 = conv_w[ch * 4 + 0], w1 = conv_w[ch * 4 + 1];
    float w2 = conv_w[ch * 4 + 2], w3 = conv_w[ch * 4 + 3];
    float bsv = conv_b[ch];
    float x[7];
#pragma unroll
    for (int i = 0; i < 7; i++) {
      int t = t0 - 3 + i;
      x[i] = (t >= 0) ? b2f(col[(size_t)t * DPROJ]) : 0.f;
    }
#pragma unroll
    for (int j = 0; j < 4; j++) {
      float acc = bsv + w0 * x[j] + w1 * x[j + 1] + w2 * x[j + 2] + w3 * x[j + 3];
      xbc[(size_t)(t0 + j) * CONVDIM + ch] = f2b(acc / (1.f + __expf(-acc)));
    }
  } else {
    int idx = (bid - CONV_BLOCKS) * 256 + threadIdx.x;   // 2*L_SEQ*NHEADS
    int h = idx % NHEADS;
    int t = (idx / NHEADS) % L_SEQ;
    int b = idx / (NHEADS * L_SEQ);
    float v;
    if (b == 0) v = b2f(zx[(size_t)t * DPROJ + 4608 + h]);
    else        v = b2f(zx[(size_t)(L_SEQ - 1 - t) * DPROJ + 4608 + NHEADS + h]);
    v += dt_bias[h];
    dt2[idx] = (v > 20.f) ? v : log1pf(expf(v));
  }
}

// ---------------- G[b,c,l,s] = sum_n C[l,n]*B[s,n]  (MFMA, quarter-split) ----------------
// 4 blocks per (b,c); block handles 32 l-rows. Waves above the diagonal skip compute
// (upper triangle of G is never consumed).
__global__ __launch_bounds__(256) void gmat_kernel(
    const bf16* __restrict__ xbc, bf16* __restrict__ G) {
  __shared__ bf16 Cs[32][136];   // C[l0+l][n]  8.5 KB
  __shared__ bf16 Bs[128][136];  // B[s][n]     34 KB
  int blk = blockIdx.x;          // (b*32+c)*4 + quarter
  int quarter = blk & 3;
  int bc = blk >> 2;
  int b = bc / NCHUNK, c = bc % NCHUNK;
  int l0 = quarter * 32;
  int tid = threadIdx.x;
  int lane = tid & 63;
  int w = tid >> 6;
  int bofs = b ? 2304 : 2048;
  int cofs = b ? 2432 : 2176;
  for (int o = tid; o < CHUNKL * DSTATE / 8; o += 256) {   // 2048 vecs
    int s = o >> 4;
    int n8 = (o & 15) * 8;
    int t = b ? (L_SEQ - 1 - (c * CHUNKL + s)) : (c * CHUNKL + s);
    *(bf16x8v*)&Bs[s][n8] = *(const bf16x8v*)&xbc[(size_t)t * CONVDIM + bofs + n8];
  }
  for (int o = tid; o < 32 * DSTATE / 8; o += 256) {       // 512 vecs
    int l = o >> 4;
    int n8 = (o & 15) * 8;
    int t = b ? (L_SEQ - 1 - (c * CHUNKL + l0 + l)) : (c * CHUNKL + l0 + l);
    *(bf16x8v*)&Cs[l][n8] = *(const bf16x8v*)&xbc[(size_t)t * CONVDIM + cofs + n8];
  }
  __syncthreads();
  if (w > quarter) return;   // s-tiles 2w,2w+1 start at s=32w > l0+31: masked at use
  f32x4v acc[2][2];
#pragma unroll
  for (int i = 0; i < 2; i++)
#pragma unroll
    for (int j = 0; j < 2; j++) acc[i][j] = (f32x4v){0.f, 0.f, 0.f, 0.f};
#pragma unroll
  for (int k0 = 0; k0 < 128; k0 += 32) {
    bf16x8v a0 = *(const bf16x8v*)&Cs[(lane & 15)][(lane >> 4) * 8 + k0];
    bf16x8v a1 = *(const bf16x8v*)&Cs[16 + (lane & 15)][(lane >> 4) * 8 + k0];
#pragma unroll
    for (int j = 0; j < 2; j++) {
      bf16x8v bv = *(const bf16x8v*)&Bs[(2 * w + j) * 16 + (lane & 15)][(lane >> 4) * 8 + k0];
      acc[0][j] = __builtin_amdgcn_mfma_f32_16x16x32_bf16(a0, bv, acc[0][j], 0, 0, 0);
      acc[1][j] = __builtin_amdgcn_mfma_f32_16x16x32_bf16(a1, bv, acc[1][j], 0, 0, 0);
    }
  }
  int quad = lane >> 4, cn = lane & 15;
  bf16* Gb = G + (size_t)bc * CHUNKL * CHUNKL;
#pragma unroll
  for (int i = 0; i < 2; i++)
#pragma unroll
    for (int j = 0; j < 2; j++)
#pragma unroll
      for (int r = 0; r < 4; r++) {
        int l = l0 + i * 16 + quad * 4 + r;
        int s = (2 * w + j) * 16 + cn;
        Gb[l * CHUNKL + s] = f2b(acc[i][j][r]);
      }
}

// ---------------- per-(b,c,h): chunk states only (MFMA, bf16 out) ----------------
__global__ __launch_bounds__(256) void chunk_kernel(
    const bf16* __restrict__ xbc, const float* __restrict__ dt2,
    const float* __restrict__ A_log,
    bf16* __restrict__ states, float* __restrict__ csum) {
  int gid = blockIdx.x;           // (b*32+c)*32 + h
  int h = gid % NHEADS;
  int bc = gid / NHEADS;
  int c = bc % NCHUNK, b = bc / NCHUNK;
  int tid = threadIdx.x;
  int lane = tid & 63;
  int w = tid >> 6;
  __shared__ bf16 BdT[128][136];  // [n][l] = B[l][n]*decay[l]  34 KB
  __shared__ bf16 xdtT[64][136];  // [p][s] = x[s,p]*dt[s]      17 KB
  __shared__ float acs[CHUNKL];
  __shared__ float dtl[CHUNKL];
  __shared__ float decays[CHUNKL];
  if (tid < CHUNKL)
    dtl[tid] = dt2[((size_t)b * L_SEQ + c * CHUNKL + tid) * NHEADS + h];
  __syncthreads();
  if (tid == 0) {
    float Ah = -__expf(A_log[h]);
    float s = 0.f;
    for (int l = 0; l < CHUNKL; l++) { s += Ah * dtl[l]; acs[l] = s; }
    csum[gid] = __expf(s);        // stored pre-exponentiated for scan
  }
  __syncthreads();
  if (tid < CHUNKL) decays[tid] = __expf(acs[CHUNKL - 1] - acs[tid]);
  // xdtT[p][s] staging: lane->s (t-strided 16B loads), conflict-free scatter
  for (int o = tid; o < CHUNKL * HEADDIM / 8; o += 256) {   // 1024 vecs
    int s = o & 127;
    int p8 = (o >> 7) * 8;
    int t = b ? (L_SEQ - 1 - (c * CHUNKL + s)) : (c * CHUNKL + s);
    bf16x8v xv = *(const bf16x8v*)&xbc[(size_t)t * CONVDIM + h * HEADDIM + p8];
    float d = dtl[s];
#pragma unroll
    for (int j = 0; j < 8; j++) xdtT[p8 + j][s] = f2b(sh2f(xv[j]) * d);
  }
  __syncthreads();   // decays ready
  // BdT[n][l] staging: lane->l, conflict-free scatter
  for (int o = tid; o < CHUNKL * CHUNKL / 8; o += 256) {    // 2048 vecs
    int l = o & 127;
    int n8 = (o >> 7) * 8;
    int t = b ? (L_SEQ - 1 - (c * CHUNKL + l)) : (c * CHUNKL + l);
    bf16x8v bv = *(const bf16x8v*)&xbc[(size_t)t * CONVDIM + (b ? 2304 : 2048) + n8];
    float d = decays[l];
#pragma unroll
    for (int j = 0; j < 8; j++) BdT[n8 + j][l] = f2b(sh2f(bv[j]) * d);
  }
  __syncthreads();
  // states[p][n] = sum_l xdtT[p][l]*BdT[n][l]; wave w -> p rows [16w,16w+16)
  f32x4v accS[8];
#pragma unroll
  for (int j = 0; j < 8; j++) accS[j] = (f32x4v){0.f, 0.f, 0.f, 0.f};
#pragma unroll
  for (int k0 = 0; k0 < 128; k0 += 32) {
    bf16x8v av = *(const bf16x8v*)&xdtT[w * 16 + (lane & 15)][(lane >> 4) * 8 + k0];
#pragma unroll
    for (int j = 0; j < 8; j++) {
      bf16x8v bv = *(const bf16x8v*)&BdT[j * 16 + (lane & 15)][(lane >> 4) * 8 + k0];
      accS[j] = __builtin_amdgcn_mfma_f32_16x16x32_bf16(av, bv, accS[j], 0, 0, 0);
    }
  }
  int quad = lane >> 4, cn = lane & 15;
  bf16* st = states + (size_t)gid * (HEADDIM * DSTATE);
#pragma unroll
  for (int j = 0; j < 8; j++)
#pragma unroll
    for (int r = 0; r < 4; r++) {
      int p = w * 16 + quad * 4 + r;
      int n = j * 16 + cn;
      st[p * DSTATE + n] = f2b(accS[j][r]);
    }
}

// ---------------- inter-chunk scan: register-batched (independent loads first) --------
__global__ __launch_bounds__(256) void scan_kernel(
    bf16* __restrict__ states, const float* __restrict__ csum) {
  int idx = blockIdx.x * 256 + threadIdx.x;  // 2*NHEADS*HEADDIM*DSTATE
  int n = idx % DSTATE;
  int p = (idx / DSTATE) % HEADDIM;
  int h = (idx / (DSTATE * HEADDIM)) % NHEADS;
  int b = idx / (DSTATE * HEADDIM * NHEADS);
  size_t base = ((size_t)(b * NCHUNK) * NHEADS + h) * (HEADDIM * DSTATE) + p * DSTATE + n;
  const size_t cstride = (size_t)NHEADS * HEADDIM * DSTATE;
  float tmp[NCHUNK], cv[NCHUNK];
#pragma unroll
  for (int c = 0; c < NCHUNK; c++) tmp[c] = b2f(states[base + c * cstride]);
#pragma unroll
  for (int c = 0; c < NCHUNK; c++) cv[c] = csum[(b * NCHUNK + c) * NHEADS + h];
  float S = 0.f;
#pragma unroll
  for (int c = 0; c < NCHUNK; c++) {
    states[base + c * cstride] = f2b(S);
    S = cv[c] * S + tmp[c];
  }
}

// ---------------- fused Y = Y_diag + Y_off + D*x (MFMA, single bf16 write) ----------------
__global__ __launch_bounds__(256) void yoff_kernel(
    const bf16* __restrict__ xbc, const float* __restrict__ dt2,
    const float* __restrict__ A_log, const bf16* __restrict__ G,
    const bf16* __restrict__ states, const float* __restrict__ Dp,
    bf16* __restrict__ Y) {
  int gid = blockIdx.x;
  int h = gid % NHEADS;
  int bc = gid / NHEADS;
  int c = bc % NCHUNK, b = bc / NCHUNK;
  int tid = threadIdx.x;
  int lane = tid & 63;
  int w = tid >> 6;
  __shared__ bf16 WB[128][136];   // 34 KB (W, then Ce)
  __shared__ bf16 SX[64][136];    // 17 KB (xdtT, then St)
  __shared__ float acs[CHUNKL];
  __shared__ float dtl[CHUNKL];
  __shared__ float eAl[CHUNKL];
  if (tid < CHUNKL)
    dtl[tid] = dt2[((size_t)b * L_SEQ + c * CHUNKL + tid) * NHEADS + h];
  __syncthreads();
  if (tid == 0) {
    float Ah = -__expf(A_log[h]);
    float s = 0.f;
    for (int l = 0; l < CHUNKL; l++) { s += Ah * dtl[l]; acs[l] = s; }
  }
  __syncthreads();
  if (tid < CHUNKL) eAl[tid] = __expf(acs[tid]);   // <= 1
  // SX <- xdtT[p][s]: lane->s, conflict-free scatter
  for (int o = tid; o < CHUNKL * HEADDIM / 8; o += 256) {   // 1024 vecs
    int s = o & 127;
    int p8 = (o >> 7) * 8;
    int t = b ? (L_SEQ - 1 - (c * CHUNKL + s)) : (c * CHUNKL + s);
    bf16x8v xv = *(const bf16x8v*)&xbc[(size_t)t * CONVDIM + h * HEADDIM + p8];
    float d = dtl[s];
#pragma unroll
    for (int j = 0; j < 8; j++) SX[p8 + j][s] = f2b(sh2f(xv[j]) * d);
  }
  // WB <- W[l][s] = G*exp(acs[l]-acs[s]) (s<=l): vectorized, b128 writes
  {
    const bf16* Gb = G + (size_t)bc * CHUNKL * CHUNKL;
    for (int o = tid; o < CHUNKL * CHUNKL / 8; o += 256) {  // 2048 vecs
      int l = o >> 4;
      int s8 = (o & 15) * 8;
      bf16x8v g = *(const bf16x8v*)&Gb[l * CHUNKL + s8];
      float al = acs[l];
      bf16x8v wv;
#pragma unroll
      for (int j = 0; j < 8; j++) {
        int s = s8 + j;
        float e = (s <= l) ? sh2f(g[j]) * __expf(al - acs[s]) : 0.f;
        wv[j] = f2bs(e);
      }
      *(bf16x8v*)&WB[l][s8] = wv;
    }
  }
  __syncthreads();
  f32x4v accY[2][4];
#pragma unroll
  for (int i = 0; i < 2; i++)
#pragma unroll
    for (int j = 0; j < 4; j++) accY[i][j] = (f32x4v){0.f, 0.f, 0.f, 0.f};
  // Y_diag: A=W rows [32w,32w+32), B=xdtT p-tiles, k=s
#pragma unroll
  for (int k0 = 0; k0 < 128; k0 += 32) {
    bf16x8v a0 = *(const bf16x8v*)&WB[w * 32 + (lane & 15)][(lane >> 4) * 8 + k0];
    bf16x8v a1 = *(const bf16x8v*)&WB[w * 32 + 16 + (lane & 15)][(lane >> 4) * 8 + k0];
#pragma unroll
    for (int j = 0; j < 4; j++) {
      bf16x8v bv = *(const bf16x8v*)&SX[j * 16 + (lane & 15)][(lane >> 4) * 8 + k0];
      accY[0][j] = __builtin_amdgcn_mfma_f32_16x16x32_bf16(a0, bv, accY[0][j], 0, 0, 0);
      accY[1][j] = __builtin_amdgcn_mfma_f32_16x16x32_bf16(a1, bv, accY[1][j], 0, 0, 0);
    }
  }
  __syncthreads();   // all phase-1 LDS reads done
  // restage: WB <- Ce[l][n] (row-contiguous, b128), SX <- St (16B copies)
  {
    int cofs = b ? 2432 : 2176;
    for (int o = tid; o < CHUNKL * DSTATE / 8; o += 256) {  // 2048 vecs
      int l = o >> 4;
      int n8 = (o & 15) * 8;
      int t = b ? (L_SEQ - 1 - (c * CHUNKL + l)) : (c * CHUNKL + l);
      bf16x8v cv = *(const bf16x8v*)&xbc[(size_t)t * CONVDIM + cofs + n8];
      float e = eAl[l];
      bf16x8v ov;
#pragma unroll
      for (int j = 0; j < 8; j++) ov[j] = f2bs(sh2f(cv[j]) * e);
      *(bf16x8v*)&WB[l][n8] = ov;
    }
    const bf16* stp = states + (size_t)gid * (HEADDIM * DSTATE);
    for (int o = tid; o < HEADDIM * DSTATE / 8; o += 256) { // 1024 vecs
      int p = o >> 4;
      int n8 = (o & 15) * 8;
      *(bf16x8v*)&SX[p][n8] = *(const bf16x8v*)&stp[o * 8];
    }
  }
  __syncthreads();
  // Y_off: A=Ce rows, B=St p-tiles, k=n; accumulate into same accY
#pragma unroll
  for (int k0 = 0; k0 < 128; k0 += 32) {
    bf16x8v a0 = *(const bf16x8v*)&WB[w * 32 + (lane & 15)][(lane >> 4) * 8 + k0];
    bf16x8v a1 = *(const bf16x8v*)&WB[w * 32 + 16 + (lane & 15)][(lane >> 4) * 8 + k0];
#pragma unroll
    for (int j = 0; j < 4; j++) {
      bf16x8v bv = *(const bf16x8v*)&SX[j * 16 + (lane & 15)][(lane >> 4) * 8 + k0];
      accY[0][j] = __builtin_amdgcn_mfma_f32_16x16x32_bf16(a0, bv, accY[0][j], 0, 0, 0);
      accY[1][j] = __builtin_amdgcn_mfma_f32_16x16x32_bf16(a1, bv, accY[1][j], 0, 0, 0);
    }
  }
  int quad = lane >> 4, cn = lane & 15;
  float Dh = Dp[h];
#pragma unroll
  for (int i = 0; i < 2; i++)
#pragma unroll
    for (int j = 0; j < 4; j++)
#pragma unroll
      for (int r = 0; r < 4; r++) {
        int l = w * 32 + i * 16 + quad * 4 + r;
        int p = j * 16 + cn;
        int t = b ? (L_SEQ - 1 - (c * CHUNKL + l)) : (c * CHUNKL + l);
        float xv = b2f(xbc[(size_t)t * CONVDIM + h * HEADDIM + p]);
        size_t yi = ((size_t)b * L_SEQ + c * CHUNKL + l) * DINNER + h * HEADDIM + p;
        Y[yi] = f2b(accY[i][j][r] + xv * Dh);
      }
}

// ---------------- combine: shift, flip, +x*fd, gate, RMSNorm (vectorized) ----------------
__global__ __launch_bounds__(256) void combine_kernel(
    const bf16* __restrict__ Y, const bf16* __restrict__ xbc,
    const bf16* __restrict__ zx, const float* __restrict__ fd,
    const float* __restrict__ norm_w, bf16* __restrict__ yn) {
  int t = blockIdx.x;
  int tid = threadIdx.x;
  int j8 = tid * 8;
  float yf[8], yb[8];
#pragma unroll
  for (int j = 0; j < 8; j++) { yf[j] = 0.f; yb[j] = 0.f; }
  if (t >= 1) {
    bf16x8v v = *(const bf16x8v*)&Y[(size_t)(t - 1) * DINNER + j8];
#pragma unroll
    for (int j = 0; j < 8; j++) yf[j] = sh2f(v[j]);
  }
  if (t <= L_SEQ - 2) {
    bf16x8v v = *(const bf16x8v*)&Y[((size_t)L_SEQ + (L_SEQ - 2 - t)) * DINNER + j8];
#pragma unroll
    for (int j = 0; j < 8; j++) yb[j] = sh2f(v[j]);
  }
  bf16x8v xogv = *(const bf16x8v*)&xbc[(size_t)t * CONVDIM + j8];
  bf16x8v zv = *(const bf16x8v*)&zx[(size_t)t * DPROJ + j8];
  float fdv = fd[t * NHEADS + (j8 >> 6)];
  float yg[8];
  float ss = 0.f;
#pragma unroll
  for (int j = 0; j < 8; j++) {
    float y = yf[j] + yb[j] + sh2f(xogv[j]) * fdv;
    float z = sh2f(zv[j]);
    float g = y * (z / (1.f + __expf(-z)));
    yg[j] = g;
    ss += g * g;
  }
#pragma unroll
  for (int off = 32; off > 0; off >>= 1) ss += __shfl_down(ss, off);
  __shared__ float red[4];
  if ((tid & 63) == 0) red[tid >> 6] = ss;
  __syncthreads();
  float tot = red[0] + red[1] + red[2] + red[3];
  float scale = rsqrtf(tot / (float)DINNER + 1e-5f);
  float4 nw0 = *(const float4*)&norm_w[j8];
  float4 nw1 = *(const float4*)&norm_w[j8 + 4];
  bf16x8v ov;
  ov[0] = f2bs(yg[0] * scale * nw0.x);
  ov[1] = f2bs(yg[1] * scale * nw0.y);
  ov[2] = f2bs(yg[2] * scale * nw0.z);
  ov[3] = f2bs(yg[3] * scale * nw0.w);
  ov[4] = f2bs(yg[4] * scale * nw1.x);
  ov[5] = f2bs(yg[5] * scale * nw1.y);
  ov[6] = f2bs(yg[6] * scale * nw1.z);
  ov[7] = f2bs(yg[7] * scale * nw1.w);
  *(bf16x8v*)&yn[(size_t)t * DINNER + j8] = ov;
}

// ---------------- launch ----------------
extern "C" void kernel_launch(void* const* d_in, const int* in_sizes, int n_in,
                              void* d_out, int out_size, void* d_ws, size_t ws_size,
                              hipStream_t stream) {
  const float* u         = (const float*)d_in[0];
  const float* in_proj_w = (const float*)d_in[1];
  const float* conv_w    = (const float*)d_in[2];
  const float* conv_b    = (const float*)d_in[3];
  const float* dt_bias   = (const float*)d_in[4];
  const float* A_log     = (const float*)d_in[5];
  const float* Dp        = (const float*)d_in[6];
  const float* fc_D_w    = (const float*)d_in[7];
  const float* norm_w    = (const float*)d_in[8];
  const float* out_proj_w= (const float*)d_in[9];
  float* out = (float*)d_out;

  char* base = (char*)d_ws;
  bf16*  zx  = (bf16*)base;  base += (size_t)L_SEQ * DPROJ * 2;                    // 38.3 MB
  bf16*  xbc = (bf16*)base;  base += (size_t)L_SEQ * CONVDIM * 2;                  // 21.0 MB
  float* dt2 = (float*)base; base += (size_t)2 * L_SEQ * NHEADS * 4;               //  1.0 MB
  bf16*  G   = (bf16*)base;  base += (size_t)2 * NCHUNK * CHUNKL * CHUNKL * 4;     //  4.2 MB region
  bf16*  Yb  = (bf16*)base;  base += (size_t)2 * L_SEQ * DINNER * 4;               // 67.1 MB region
  bf16*  stb = (bf16*)base;  base += (size_t)2 * NCHUNK * NHEADS * HEADDIM * DSTATE * 4; // 67.1 MB region
  float* cs  = (float*)base; base += (size_t)2 * NCHUNK * NHEADS * 4;              //  8 KB
  // aliases into dead regions:
  bf16*  u_bf   = (bf16*)Yb;                          // 8.4 MB   (Yb live only after yoff)
  bf16*  w1p_bf = (bf16*)((char*)Yb + 9437184);       // 9.7 MB   (padded in_proj_w)
  bf16*  w2_bf  = (bf16*)G;                           // 4.2 MB   (G dead after yoff)
  bf16*  yn     = (bf16*)stb;                         // 16.8 MB  (stb dead after yoff)
  float* fd     = (float*)((char*)stb + 33554432);    //  0.5 MB

  // 0. fused casts for MFMA gemm1
  cast2_kernel<<<(L_SEQ * DMODEL + NPAD1 * DMODEL) / 256, 256, 0, stream>>>(
      u, in_proj_w, u_bf, w1p_bf);
  // 1. in_proj: zx = u @ in_proj_w^T  (MFMA, plain n-fastest mapping — R10 best)
  gemm_mfma<bf16><<<(L_SEQ / 128) * (NPAD1 / 128), 256, 0, stream>>>(
      u_bf, DMODEL, w1p_bf, DMODEL, zx, DPROJ, DPROJ, DMODEL,
      L_SEQ / 128, NPAD1 / 128, 0);
  // 2. conv + silu + dt (fused)
  conv_dt_kernel<<<CONV_BLOCKS + (2 * L_SEQ * NHEADS) / 256, 256, 0, stream>>>(
      zx, conv_w, conv_b, xbc, dt_bias, dt2);
  // 3a. G = C B^T per (b,c), quarter-split (MFMA, bf16)
  gmat_kernel<<<2 * NCHUNK * 4, 256, 0, stream>>>(xbc, G);
  // 3b. chunk states (MFMA, bf16)
  chunk_kernel<<<2 * NCHUNK * NHEADS, 256, 0, stream>>>(
      xbc, dt2, A_log, stb, cs);
  // 3c. inter-chunk scan (register-batched)
  scan_kernel<<<(2 * NHEADS * HEADDIM * DSTATE) / 256, 256, 0, stream>>>(stb, cs);
  // 3d. fused Y = Y_diag + Y_off + D*x (MFMA, single bf16 write)
  yoff_kernel<<<2 * NCHUNK * NHEADS, 256, 0, stream>>>(
      xbc, dt2, A_log, G, stb, Dp, Yb);
  // 4a. cast out_proj_w (into dead G region)
  cast_kernel<<<(DMODEL * DINNER + 255) / 256, 256, 0, stream>>>(
      out_proj_w, w2_bf, DMODEL * DINNER, DMODEL * DINNER);
  // 4b. fd = x_og @ fc_D_w^T + D
  fc_kernel<<<L_SEQ / 16, 256, 0, stream>>>(xbc, fc_D_w, Dp, fd);
  // 5. combine + gate + RMSNorm
  combine_kernel<<<L_SEQ, 256, 0, stream>>>(Yb, xbc, zx, fd, norm_w, yn);
  // 6. out_proj (MFMA, XCD-swizzled: 256 blocks = 1/CU, swizzle's home case)
  gemm_mfma<float><<<(L_SEQ / 128) * (DMODEL / 128), 256, 0, stream>>>(
      yn, DINNER, w2_bf, DINNER, out, DMODEL, DMODEL, DINNER,
      L_SEQ / 128, DMODEL / 128, 1);
}